// Round 1
// baseline (6679.241 us; speedup 1.0000x reference)
//
#include <hip/hip_runtime.h>
#include <math.h>

#define HEADS 10
#define D1 780
#define F1 78
#define D2H 780

static __device__ __forceinline__ float lrelu(float x){ return x > 0.f ? x : 0.2f*x; }

// ---------------- CSR build ----------------
__global__ void k_count(const int* __restrict__ dst, int* __restrict__ counts, int Eraw, int N){
  int e = blockIdx.x*blockDim.x + threadIdx.x;
  if (e < Eraw + N){
    int d = (e < Eraw) ? dst[e] : (e - Eraw);
    atomicAdd(&counts[d], 1);
  }
}

__global__ void k_scan(const int* __restrict__ counts, int* __restrict__ row_ptr,
                       int* __restrict__ cursor, int N){
  __shared__ int part[1024];
  int tid = threadIdx.x;
  int chunk = (N + 1023)/1024;
  int beg = tid*chunk, end = min(beg+chunk, N);
  int s = 0;
  for (int i=beg;i<end;++i) s += counts[i];
  part[tid] = s;
  __syncthreads();
  for (int off=1; off<1024; off<<=1){
    int v = (tid >= off) ? part[tid-off] : 0;
    __syncthreads();
    part[tid] += v;
    __syncthreads();
  }
  int excl = (tid>0) ? part[tid-1] : 0;
  for (int i=beg;i<end;++i){ row_ptr[i]=excl; cursor[i]=excl; excl += counts[i]; }
  if (tid == 1023) row_ptr[N] = part[1023];
}

__global__ void k_scatter(const int* __restrict__ src, const int* __restrict__ dst,
                          int* __restrict__ cursor, int* __restrict__ col_src, int Eraw, int N){
  int e = blockIdx.x*blockDim.x + threadIdx.x;
  if (e < Eraw + N){
    int s, d;
    if (e < Eraw){ s = src[e]; d = dst[e]; } else { s = e - Eraw; d = s; }
    int pos = atomicAdd(&cursor[d], 1);
    col_src[pos] = s;
  }
}

// ---------------- generic tiled fp32 GEMM ----------------
// C[M,N] = act(A@B + bias). act: 0=none, 1=relu
__global__ __launch_bounds__(256) void k_gemm(const float* __restrict__ A, const float* __restrict__ Bm,
                       float* __restrict__ C, const float* __restrict__ bias,
                       int M, int Nn, int K, int lda, int ldb, int ldc, int act){
  __shared__ __align__(16) float As[16][68];
  __shared__ __align__(16) float Bs[16][68];
  int tid = threadIdx.x;
  int tx = tid & 15, ty = tid >> 4;
  int row0 = blockIdx.y*64, col0 = blockIdx.x*64;
  float acc[4][4] = {};
  for (int kk=0; kk<K; kk+=16){
    for (int l = tid; l < 64*16; l += 256){
      int m = l >> 4, k = l & 15;
      int gr = row0 + m, gk = kk + k;
      As[k][m] = (gr < M && gk < K) ? A[(size_t)gr*lda + gk] : 0.f;
    }
    for (int l = tid; l < 16*64; l += 256){
      int k = l >> 6, n = l & 63;
      int gk = kk + k, gc = col0 + n;
      Bs[k][n] = (gk < K && gc < Nn) ? Bm[(size_t)gk*ldb + gc] : 0.f;
    }
    __syncthreads();
    #pragma unroll
    for (int k=0;k<16;++k){
      float4 a = *reinterpret_cast<const float4*>(&As[k][ty*4]);
      float4 b = *reinterpret_cast<const float4*>(&Bs[k][tx*4]);
      float av[4] = {a.x,a.y,a.z,a.w};
      float bv[4] = {b.x,b.y,b.z,b.w};
      #pragma unroll
      for (int i=0;i<4;++i)
        #pragma unroll
        for (int j=0;j<4;++j)
          acc[i][j] += av[i]*bv[j];
    }
    __syncthreads();
  }
  #pragma unroll
  for (int i=0;i<4;++i){
    int r = row0 + ty*4 + i;
    if (r >= M) continue;
    #pragma unroll
    for (int j=0;j<4;++j){
      int c = col0 + tx*4 + j;
      if (c >= Nn) continue;
      float v = acc[i][j];
      if (bias) v += bias[c];
      if (act == 1) v = fmaxf(v, 0.f);
      C[(size_t)r*ldc + c] = v;
    }
  }
}

// ---------------- GAT layer 1 ----------------
__global__ void k_scores1(const float* __restrict__ h1, const float* __restrict__ a1s,
                          const float* __restrict__ a1d, float* __restrict__ hs, float* __restrict__ hd){
  __shared__ float ss[HEADS], sd[HEADS];
  int n = blockIdx.x, tid = threadIdx.x;
  if (tid < HEADS){ ss[tid]=0.f; sd[tid]=0.f; }
  __syncthreads();
  const float* hr = h1 + (size_t)n*D1;
  for (int c = tid; c < D1; c += blockDim.x){
    float v = hr[c];
    int h = c / F1;
    atomicAdd(&ss[h], v*a1s[c]);
    atomicAdd(&sd[h], v*a1d[c]);
  }
  __syncthreads();
  if (tid < HEADS){ hs[n*HEADS+tid]=ss[tid]; hd[n*HEADS+tid]=sd[tid]; }
}

#define CH1 32
__global__ __launch_bounds__(256) void k_agg1(const float* __restrict__ h1, const float* __restrict__ hs,
                       const float* __restrict__ hd, const int* __restrict__ row_ptr,
                       const int* __restrict__ col_src, const float* __restrict__ b1,
                       float* __restrict__ g1o){
  __shared__ float m_l[HEADS], s_l[HEADS];
  __shared__ float al[CH1][HEADS];
  __shared__ int src_l[CH1];
  int n = blockIdx.x, tid = threadIdx.x;
  int beg = row_ptr[n], end = row_ptr[n+1];
  if (tid < HEADS){
    float hdv = hd[n*HEADS + tid];
    float m = -1e30f;
    for (int j=beg;j<end;++j){
      float sc = lrelu(hs[col_src[j]*HEADS + tid] + hdv);
      m = fmaxf(m, sc);
    }
    float s = 0.f;
    for (int j=beg;j<end;++j){
      float sc = lrelu(hs[col_src[j]*HEADS + tid] + hdv);
      s += expf(sc - m);
    }
    m_l[tid]=m; s_l[tid]=s;
  }
  __syncthreads();
  float acc[4] = {0.f,0.f,0.f,0.f};
  for (int j0=beg; j0<end; j0+=CH1){
    int cn = min(CH1, end-j0);
    for (int p=tid; p<cn*HEADS; p+=256){
      int j = p/HEADS, h = p - j*HEADS;
      int sidx = col_src[j0+j];
      if (h==0) src_l[j] = sidx;
      float sc = lrelu(hs[sidx*HEADS+h] + hd[n*HEADS+h]);
      al[j][h] = expf(sc - m_l[h]) / s_l[h];
    }
    __syncthreads();
    for (int j=0;j<cn;++j){
      const float* hr = h1 + (size_t)src_l[j]*D1;
      #pragma unroll
      for (int r=0;r<4;++r){
        int c = tid + r*256;
        if (c < D1) acc[r] += al[j][c/F1] * hr[c];
      }
    }
    __syncthreads();
  }
  #pragma unroll
  for (int r=0;r<4;++r){
    int c = tid + r*256;
    if (c < D1){
      float v = acc[r] + b1[c];
      g1o[(size_t)n*D1 + c] = v > 0.f ? v : expm1f(v);
    }
  }
}

// ---------------- GAT layer 2 (per head) ----------------
__global__ void k_scores2(const float* __restrict__ h2, const float* __restrict__ a2s,
                          const float* __restrict__ a2d, float* __restrict__ hs, float* __restrict__ hd){
  __shared__ float rs[256], rd[256];
  int n = blockIdx.x, tid = threadIdx.x;
  const float* hr = h2 + (size_t)n*D2H;
  float ps=0.f, pd=0.f;
  for (int c = tid; c < D2H; c += 256){
    float v = hr[c];
    ps += v*a2s[c]; pd += v*a2d[c];
  }
  rs[tid]=ps; rd[tid]=pd;
  __syncthreads();
  for (int s=128;s>0;s>>=1){
    if (tid<s){ rs[tid]+=rs[tid+s]; rd[tid]+=rd[tid+s]; }
    __syncthreads();
  }
  if (tid==0){ hs[n]=rs[0]; hd[n]=rd[0]; }
}

#define CH2 64
__global__ __launch_bounds__(256) void k_agg2(const float* __restrict__ h2, const float* __restrict__ hs,
                       const float* __restrict__ hd, const int* __restrict__ row_ptr,
                       const int* __restrict__ col_src, float* __restrict__ out2, int first){
  __shared__ float red[256];
  __shared__ float al[CH2];
  __shared__ int src_l[CH2];
  int n = blockIdx.x, tid = threadIdx.x;
  int beg = row_ptr[n], end = row_ptr[n+1];
  float hdv = hd[n];
  float m = -1e30f;
  for (int j=beg+tid; j<end; j+=256) m = fmaxf(m, lrelu(hs[col_src[j]] + hdv));
  red[tid]=m; __syncthreads();
  for (int s=128;s>0;s>>=1){ if(tid<s) red[tid]=fmaxf(red[tid],red[tid+s]); __syncthreads(); }
  m = red[0]; __syncthreads();
  float s_ = 0.f;
  for (int j=beg+tid; j<end; j+=256) s_ += expf(lrelu(hs[col_src[j]] + hdv) - m);
  red[tid]=s_; __syncthreads();
  for (int s=128;s>0;s>>=1){ if(tid<s) red[tid]+=red[tid+s]; __syncthreads(); }
  float denom = red[0];
  __syncthreads();
  float acc[4] = {0.f,0.f,0.f,0.f};
  for (int j0=beg;j0<end;j0+=CH2){
    int cn = min(CH2, end-j0);
    if (tid < cn){
      int sidx = col_src[j0+tid];
      src_l[tid] = sidx;
      al[tid] = expf(lrelu(hs[sidx] + hdv) - m) / denom;
    }
    __syncthreads();
    for (int j=0;j<cn;++j){
      const float* hr = h2 + (size_t)src_l[j]*D2H;
      float a = al[j];
      #pragma unroll
      for (int r=0;r<4;++r){
        int c = tid + r*256;
        if (c < D2H) acc[r] += a * hr[c];
      }
    }
    __syncthreads();
  }
  #pragma unroll
  for (int r=0;r<4;++r){
    int c = tid + r*256;
    if (c < D2H){
      float v = 0.1f*acc[r];
      size_t idx = (size_t)n*D2H + c;
      if (first) out2[idx]=v; else out2[idx]+=v;
    }
  }
}

// ---------------- pooling ----------------
__device__ __forceinline__ int lowb(const int* a, int n, int v){
  int lo=0, hi=n;
  while (lo<hi){ int mid=(lo+hi)>>1; if (a[mid]<v) lo=mid+1; else hi=mid; }
  return lo;
}

__global__ void k_pool(const float* __restrict__ out2, const float* __restrict__ b2,
                       const int* __restrict__ batch, int N, float* __restrict__ gfeat){
  int b = blockIdx.x, tid = threadIdx.x;
  int lo = lowb(batch, N, b), hi = lowb(batch, N, b+1);
  #pragma unroll
  for (int r=0;r<4;++r){
    int c = tid + r*256;
    if (c >= D2H) continue;
    float bb = b2[c];
    float mx = -INFINITY, sm = 0.f;
    for (int n2=lo;n2<hi;++n2){
      float v = out2[(size_t)n2*D2H + c] + bb;
      v = fmaxf(v, 0.f);
      mx = fmaxf(mx, v);
      sm += v;
    }
    int cnt = hi-lo;
    gfeat[(size_t)b*1560 + c] = mx;
    gfeat[(size_t)b*1560 + 780 + c] = sm / fmaxf((float)cnt, 1.f);
  }
}

// ---------------- protein conv ----------------
__global__ __launch_bounds__(128) void k_conv(const int* __restrict__ target, const float* __restrict__ emb,
                       const float* __restrict__ Wc, const float* __restrict__ bc,
                       float* __restrict__ convc){
  __shared__ float emb_l[26*128];
  int b = blockIdx.x, og = blockIdx.y;   // og: 0..3 -> 8 output channels each
  int tid = threadIdx.x;
  for (int i=tid;i<26*128;i+=128) emb_l[i]=emb[i];
  __syncthreads();
  int t = tid;
  float acc[8] = {0.f,0.f,0.f,0.f,0.f,0.f,0.f,0.f};
  const int* tg = target + b*1000;
  const float* wbase = Wc + (size_t)og*8*1000*8;
  for (int i=0;i<1000;++i){
    int idx = tg[i];
    const float* row = emb_l + idx*128;
    float win[8];
    if (t < 121){
      #pragma unroll
      for (int k=0;k<8;++k) win[k] = row[t+k];
      #pragma unroll
      for (int o=0;o<8;++o){
        const float* w = wbase + ((size_t)o*1000 + i)*8;
        float a = 0.f;
        #pragma unroll
        for (int k=0;k<8;++k) a += w[k]*win[k];
        acc[o] += a;
      }
    }
  }
  if (t < 121){
    #pragma unroll
    for (int o=0;o<8;++o)
      convc[(size_t)b*3872 + (size_t)(og*8+o)*121 + t] = acc[o] + bc[og*8+o];
  }
}

// ---------------- launch ----------------
extern "C" void kernel_launch(void* const* d_in, const int* in_sizes, int n_in,
                              void* d_out, int out_size, void* d_ws, size_t ws_size,
                              hipStream_t stream){
  const float* x   = (const float*)d_in[0];
  const int*   ei    = (const int*)d_in[1];
  const int*   batch = (const int*)d_in[2];
  const int*   target= (const int*)d_in[3];
  const float* W1  = (const float*)d_in[4];
  const float* a1s = (const float*)d_in[5];
  const float* a1d = (const float*)d_in[6];
  const float* b1  = (const float*)d_in[7];
  const float* W2  = (const float*)d_in[8];
  const float* a2s = (const float*)d_in[9];
  const float* a2d = (const float*)d_in[10];
  const float* b2  = (const float*)d_in[11];
  const float* Wg1 = (const float*)d_in[12];
  const float* bg1 = (const float*)d_in[13];
  const float* Wg2 = (const float*)d_in[14];
  const float* bg2 = (const float*)d_in[15];
  const float* emb = (const float*)d_in[16];
  const float* Wc  = (const float*)d_in[17];
  const float* bc  = (const float*)d_in[18];
  const float* Wxt = (const float*)d_in[19];
  const float* bxt = (const float*)d_in[20];
  const float* Wf1 = (const float*)d_in[21];
  const float* bf1 = (const float*)d_in[22];
  const float* Wf2 = (const float*)d_in[23];
  const float* bf2 = (const float*)d_in[24];
  const float* Wo  = (const float*)d_in[25];
  const float* bo  = (const float*)d_in[26];

  int N = in_sizes[0] / 78;
  int Eraw = in_sizes[1] / 2;
  int Bb = in_sizes[3] / 1000;
  int Etot = Eraw + N;

  char* wsp = (char*)d_ws;
  size_t off = 0;
  auto alloc = [&](size_t bytes)->void*{ void* p = wsp + off; off += (bytes + 255) & ~(size_t)255; return p; };
  float* bufA   = (float*)alloc((size_t)N*D1*4);   // h1, later out2
  float* bufB   = (float*)alloc((size_t)N*D1*4);   // g1
  float* bufC   = (float*)alloc((size_t)N*D1*4);   // h2 per head
  float* hs1    = (float*)alloc((size_t)N*HEADS*4);
  float* hd1    = (float*)alloc((size_t)N*HEADS*4);
  float* hs2    = (float*)alloc((size_t)N*4);
  float* hd2    = (float*)alloc((size_t)N*4);
  int*   counts = (int*)alloc((size_t)N*4);
  int*   row_ptr= (int*)alloc((size_t)(N+1)*4);
  int*   cursor = (int*)alloc((size_t)N*4);
  int*   col_src= (int*)alloc((size_t)Etot*4);
  float* gfeat  = (float*)alloc((size_t)Bb*1560*4);
  float* fcg1   = (float*)alloc((size_t)Bb*1500*4);
  float* xc     = (float*)alloc((size_t)Bb*256*4);
  float* convc  = (float*)alloc((size_t)Bb*3872*4);
  float* f1     = (float*)alloc((size_t)Bb*1024*4);
  float* f2     = (float*)alloc((size_t)Bb*512*4);
  (void)ws_size; (void)n_in; (void)out_size;

  // CSR by dst (self-loops appended)
  hipMemsetAsync(counts, 0, (size_t)N*4, stream);
  int thr=256, blk=(Etot+thr-1)/thr;
  k_count<<<blk,thr,0,stream>>>(ei+Eraw, counts, Eraw, N);
  k_scan<<<1,1024,0,stream>>>(counts, row_ptr, cursor, N);
  k_scatter<<<blk,thr,0,stream>>>(ei, ei+Eraw, cursor, col_src, Eraw, N);

  // ---- GAT layer 1 ----
  dim3 gL1((D1+63)/64, (N+63)/64);
  k_gemm<<<gL1,256,0,stream>>>(x, W1, bufA, nullptr, N, D1, 78, 78, D1, D1, 0);
  k_scores1<<<N,256,0,stream>>>(bufA, a1s, a1d, hs1, hd1);
  k_agg1<<<N,256,0,stream>>>(bufA, hs1, hd1, row_ptr, col_src, b1, bufB);

  // ---- GAT layer 2, head by head ----
  float* out2 = bufA;
  for (int h=0; h<HEADS; ++h){
    k_gemm<<<gL1,256,0,stream>>>(bufB, W2 + h*D2H, bufC, nullptr, N, D2H, D1, D1, 7800, D2H, 0);
    k_scores2<<<N,256,0,stream>>>(bufC, a2s + h*D2H, a2d + h*D2H, hs2, hd2);
    k_agg2<<<N,256,0,stream>>>(bufC, hs2, hd2, row_ptr, col_src, out2, h==0?1:0);
  }

  // ---- pooling (bias+relu fused) ----
  k_pool<<<Bb,256,0,stream>>>(out2, b2, batch, N, gfeat);

  // ---- graph FCs ----
  dim3 gG1((1500+63)/64, (Bb+63)/64);
  k_gemm<<<gG1,256,0,stream>>>(gfeat, Wg1, fcg1, bg1, Bb, 1500, 1560, 1560, 1500, 1500, 1);
  dim3 gG2((128+63)/64, (Bb+63)/64);
  k_gemm<<<gG2,256,0,stream>>>(fcg1, Wg2, xc, bg2, Bb, 128, 1500, 1500, 128, 256, 1);

  // ---- protein branch ----
  dim3 gcv(Bb, 4);
  k_conv<<<gcv,128,0,stream>>>(target, emb, Wc, bc, convc);
  k_gemm<<<gG2,256,0,stream>>>(convc, Wxt, xc+128, bxt, Bb, 128, 3872, 3872, 128, 256, 0);

  // ---- fusion MLP ----
  dim3 gF1((1024+63)/64, (Bb+63)/64);
  k_gemm<<<gF1,256,0,stream>>>(xc, Wf1, f1, bf1, Bb, 1024, 256, 256, 1024, 1024, 1);
  dim3 gF2((512+63)/64, (Bb+63)/64);
  k_gemm<<<gF2,256,0,stream>>>(f1, Wf2, f2, bf2, Bb, 512, 1024, 1024, 512, 512, 1);
  dim3 gFo(1, (Bb+63)/64);
  k_gemm<<<gFo,256,0,stream>>>(f2, Wo, (float*)d_out, bo, Bb, 1, 512, 512, 1, 1, 0);
}

// Round 2
// 6314.766 us; speedup vs baseline: 1.0577x; 1.0577x over previous
//
#include <hip/hip_runtime.h>
#include <math.h>

#define HEADS 10
#define D1 780
#define F1 78

static __device__ __forceinline__ float lrelu(float x){ return x > 0.f ? x : 0.2f*x; }

// ---------------- CSR build ----------------
__global__ void k_count(const int* __restrict__ dst, int* __restrict__ counts, int Eraw, int N){
  int e = blockIdx.x*blockDim.x + threadIdx.x;
  if (e < Eraw + N){
    int d = (e < Eraw) ? dst[e] : (e - Eraw);
    atomicAdd(&counts[d], 1);
  }
}

__global__ void k_scan(const int* __restrict__ counts, int* __restrict__ row_ptr,
                       int* __restrict__ cursor, int N){
  __shared__ int part[1024];
  int tid = threadIdx.x;
  int chunk = (N + 1023)/1024;
  int beg = tid*chunk, end = min(beg+chunk, N);
  int s = 0;
  for (int i=beg;i<end;++i) s += counts[i];
  part[tid] = s;
  __syncthreads();
  for (int off=1; off<1024; off<<=1){
    int v = (tid >= off) ? part[tid-off] : 0;
    __syncthreads();
    part[tid] += v;
    __syncthreads();
  }
  int excl = (tid>0) ? part[tid-1] : 0;
  for (int i=beg;i<end;++i){ row_ptr[i]=excl; cursor[i]=excl; excl += counts[i]; }
  if (tid == 1023) row_ptr[N] = part[1023];
}

__global__ void k_scatter(const int* __restrict__ src, const int* __restrict__ dst,
                          int* __restrict__ cursor, int* __restrict__ col_src, int Eraw, int N){
  int e = blockIdx.x*blockDim.x + threadIdx.x;
  if (e < Eraw + N){
    int s, d;
    if (e < Eraw){ s = src[e]; d = dst[e]; } else { s = e - Eraw; d = s; }
    int pos = atomicAdd(&cursor[d], 1);
    col_src[pos] = s;
  }
}

// ---------------- 128x128 tiled fp32 GEMM, 8x8 micro-tile ----------------
// C[M,N] = act(A@B + bias) (+C if accum). act: 0=none, 1=relu
__global__ __launch_bounds__(256) void k_gemm128(const float* __restrict__ A, const float* __restrict__ Bm,
                       float* __restrict__ C, const float* __restrict__ bias,
                       int M, int Nn, int K, int lda, int ldb, int ldc, int act, int accum){
  __shared__ __align__(16) float As[16][132];
  __shared__ __align__(16) float Bs[16][132];
  int tid = threadIdx.x;
  int tx = tid & 15, ty = tid >> 4;
  int row0 = blockIdx.y*128, col0 = blockIdx.x*128;
  float acc[8][8] = {};
  for (int kk=0; kk<K; kk+=16){
    for (int l = tid; l < 128*16; l += 256){
      int m = l >> 4, k = l & 15;
      int gr = row0 + m, gk = kk + k;
      As[k][m] = (gr < M && gk < K) ? A[(size_t)gr*lda + gk] : 0.f;
    }
    for (int l = tid; l < 16*128; l += 256){
      int k = l >> 7, n = l & 127;
      int gk = kk + k, gc = col0 + n;
      Bs[k][n] = (gk < K && gc < Nn) ? Bm[(size_t)gk*ldb + gc] : 0.f;
    }
    __syncthreads();
    #pragma unroll
    for (int k=0;k<16;++k){
      float4 a0 = *reinterpret_cast<const float4*>(&As[k][ty*4]);
      float4 a1 = *reinterpret_cast<const float4*>(&As[k][64+ty*4]);
      float4 b0 = *reinterpret_cast<const float4*>(&Bs[k][tx*4]);
      float4 b1 = *reinterpret_cast<const float4*>(&Bs[k][64+tx*4]);
      float av[8] = {a0.x,a0.y,a0.z,a0.w,a1.x,a1.y,a1.z,a1.w};
      float bv[8] = {b0.x,b0.y,b0.z,b0.w,b1.x,b1.y,b1.z,b1.w};
      #pragma unroll
      for (int i=0;i<8;++i)
        #pragma unroll
        for (int j=0;j<8;++j)
          acc[i][j] += av[i]*bv[j];
    }
    __syncthreads();
  }
  #pragma unroll
  for (int i=0;i<8;++i){
    int r = row0 + ((i<4) ? ty*4+i : 64+ty*4+(i-4));
    if (r >= M) continue;
    #pragma unroll
    for (int j=0;j<8;++j){
      int c = col0 + ((j<4) ? tx*4+j : 64+tx*4+(j-4));
      if (c >= Nn) continue;
      float v = acc[i][j];
      if (accum) v += C[(size_t)r*ldc + c];
      if (bias) v += bias[c];
      if (act == 1) v = fmaxf(v, 0.f);
      C[(size_t)r*ldc + c] = v;
    }
  }
}

// ---------------- 64x64 tiled fp32 GEMM (small matrices) ----------------
__global__ __launch_bounds__(256) void k_gemm(const float* __restrict__ A, const float* __restrict__ Bm,
                       float* __restrict__ C, const float* __restrict__ bias,
                       int M, int Nn, int K, int lda, int ldb, int ldc, int act){
  __shared__ __align__(16) float As[16][68];
  __shared__ __align__(16) float Bs[16][68];
  int tid = threadIdx.x;
  int tx = tid & 15, ty = tid >> 4;
  int row0 = blockIdx.y*64, col0 = blockIdx.x*64;
  float acc[4][4] = {};
  for (int kk=0; kk<K; kk+=16){
    for (int l = tid; l < 64*16; l += 256){
      int m = l >> 4, k = l & 15;
      int gr = row0 + m, gk = kk + k;
      As[k][m] = (gr < M && gk < K) ? A[(size_t)gr*lda + gk] : 0.f;
    }
    for (int l = tid; l < 16*64; l += 256){
      int k = l >> 6, n = l & 63;
      int gk = kk + k, gc = col0 + n;
      Bs[k][n] = (gk < K && gc < Nn) ? Bm[(size_t)gk*ldb + gc] : 0.f;
    }
    __syncthreads();
    #pragma unroll
    for (int k=0;k<16;++k){
      float4 a = *reinterpret_cast<const float4*>(&As[k][ty*4]);
      float4 b = *reinterpret_cast<const float4*>(&Bs[k][tx*4]);
      float av[4] = {a.x,a.y,a.z,a.w};
      float bv[4] = {b.x,b.y,b.z,b.w};
      #pragma unroll
      for (int i=0;i<4;++i)
        #pragma unroll
        for (int j=0;j<4;++j)
          acc[i][j] += av[i]*bv[j];
    }
    __syncthreads();
  }
  #pragma unroll
  for (int i=0;i<4;++i){
    int r = row0 + ty*4 + i;
    if (r >= M) continue;
    #pragma unroll
    for (int j=0;j<4;++j){
      int c = col0 + tx*4 + j;
      if (c >= Nn) continue;
      float v = acc[i][j];
      if (bias) v += bias[c];
      if (act == 1) v = fmaxf(v, 0.f);
      C[(size_t)r*ldc + c] = v;
    }
  }
}

// ---------------- GAT layer 1 (unchanged structure) ----------------
__global__ void k_scores1(const float* __restrict__ h1, const float* __restrict__ a1s,
                          const float* __restrict__ a1d, float* __restrict__ hs, float* __restrict__ hd){
  __shared__ float ss[HEADS], sd[HEADS];
  int n = blockIdx.x, tid = threadIdx.x;
  if (tid < HEADS){ ss[tid]=0.f; sd[tid]=0.f; }
  __syncthreads();
  const float* hr = h1 + (size_t)n*D1;
  for (int c = tid; c < D1; c += blockDim.x){
    float v = hr[c];
    int h = c / F1;
    atomicAdd(&ss[h], v*a1s[c]);
    atomicAdd(&sd[h], v*a1d[c]);
  }
  __syncthreads();
  if (tid < HEADS){ hs[n*HEADS+tid]=ss[tid]; hd[n*HEADS+tid]=sd[tid]; }
}

#define CH1 32
__global__ __launch_bounds__(256) void k_agg1(const float* __restrict__ h1, const float* __restrict__ hs,
                       const float* __restrict__ hd, const int* __restrict__ row_ptr,
                       const int* __restrict__ col_src, const float* __restrict__ b1,
                       float* __restrict__ g1o){
  __shared__ float m_l[HEADS], s_l[HEADS];
  __shared__ float al[CH1][HEADS];
  __shared__ int src_l[CH1];
  int n = blockIdx.x, tid = threadIdx.x;
  int beg = row_ptr[n], end = row_ptr[n+1];
  if (tid < HEADS){
    float hdv = hd[n*HEADS + tid];
    float m = -1e30f;
    for (int j=beg;j<end;++j){
      float sc = lrelu(hs[col_src[j]*HEADS + tid] + hdv);
      m = fmaxf(m, sc);
    }
    float s = 0.f;
    for (int j=beg;j<end;++j){
      float sc = lrelu(hs[col_src[j]*HEADS + tid] + hdv);
      s += expf(sc - m);
    }
    m_l[tid]=m; s_l[tid]=s;
  }
  __syncthreads();
  float acc[4] = {0.f,0.f,0.f,0.f};
  for (int j0=beg; j0<end; j0+=CH1){
    int cn = min(CH1, end-j0);
    for (int p=tid; p<cn*HEADS; p+=256){
      int j = p/HEADS, h = p - j*HEADS;
      int sidx = col_src[j0+j];
      if (h==0) src_l[j] = sidx;
      float sc = lrelu(hs[sidx*HEADS+h] + hd[n*HEADS+h]);
      al[j][h] = expf(sc - m_l[h]) / s_l[h];
    }
    __syncthreads();
    for (int j=0;j<cn;++j){
      const float* hr = h1 + (size_t)src_l[j]*D1;
      #pragma unroll
      for (int r=0;r<4;++r){
        int c = tid + r*256;
        if (c < D1) acc[r] += al[j][c/F1] * hr[c];
      }
    }
    __syncthreads();
  }
  #pragma unroll
  for (int r=0;r<4;++r){
    int c = tid + r*256;
    if (c < D1){
      float v = acc[r] + b1[c];
      g1o[(size_t)n*D1 + c] = v > 0.f ? v : expm1f(v);
    }
  }
}

// ---------------- layer-2 score projections: Wsd[c][0..9]=W2_h@a2s, [10..19]=W2_h@a2d ----------------
__global__ void k_makews2(const float* __restrict__ W2, const float* __restrict__ a2s,
                          const float* __restrict__ a2d, float* __restrict__ Wsd){
  __shared__ float out[20];
  int c = blockIdx.x, tid = threadIdx.x;
  if (tid < 20) out[tid] = 0.f;
  __syncthreads();
  const float* row = W2 + (size_t)c*7800;
  for (int j = tid; j < 7800; j += 256){
    float v = row[j];
    int h = j / D1;
    atomicAdd(&out[h],    v * a2s[j]);
    atomicAdd(&out[10+h], v * a2d[j]);
  }
  __syncthreads();
  if (tid < 20) Wsd[c*20 + tid] = out[tid];
}

// ---------------- layer-2 aggregation of g1 with head-h attention (x0.1 folded) ----------------
__global__ __launch_bounds__(256) void k_aggH(const float* __restrict__ g1, const float* __restrict__ hsd,
                       const int* __restrict__ row_ptr, const int* __restrict__ col_src,
                       float* __restrict__ aggG, int h, int N){
  int n = blockIdx.x*4 + (threadIdx.x >> 6);
  if (n >= N) return;
  int lane = threadIdx.x & 63;
  int beg = row_ptr[n], end = row_ptr[n+1];
  float hdv = hsd[n*20 + 10 + h];
  float m = -1e30f;
  for (int j=beg;j<end;++j) m = fmaxf(m, lrelu(hsd[col_src[j]*20 + h] + hdv));
  float denom = 0.f;
  for (int j=beg;j<end;++j) denom += expf(lrelu(hsd[col_src[j]*20 + h] + hdv) - m);
  float acc[13] = {};
  for (int j=beg;j<end;++j){
    int s = col_src[j];
    float a = 0.1f * expf(lrelu(hsd[s*20 + h] + hdv) - m) / denom;
    const float* gr = g1 + (size_t)s*D1;
    #pragma unroll
    for (int r=0;r<12;++r) acc[r] += a * gr[lane + r*64];
    if (lane < 12) acc[12] += a * gr[768 + lane];
  }
  float* og = aggG + (size_t)n*D1;
  #pragma unroll
  for (int r=0;r<12;++r) og[lane + r*64] = acc[r];
  if (lane < 12) og[768 + lane] = acc[12];
}

// ---------------- pooling ----------------
__device__ __forceinline__ int lowb(const int* a, int n, int v){
  int lo=0, hi=n;
  while (lo<hi){ int mid=(lo+hi)>>1; if (a[mid]<v) lo=mid+1; else hi=mid; }
  return lo;
}

__global__ void k_pool(const float* __restrict__ out2, const float* __restrict__ b2,
                       const int* __restrict__ batch, int N, float* __restrict__ gfeat){
  int b = blockIdx.x, tid = threadIdx.x;
  int lo = lowb(batch, N, b), hi = lowb(batch, N, b+1);
  #pragma unroll
  for (int r=0;r<4;++r){
    int c = tid + r*256;
    if (c >= D1) continue;
    float bb = b2[c];
    float mx = -INFINITY, sm = 0.f;
    for (int n2=lo;n2<hi;++n2){
      float v = out2[(size_t)n2*D1 + c] + bb;
      v = fmaxf(v, 0.f);
      mx = fmaxf(mx, v);
      sm += v;
    }
    int cnt = hi-lo;
    gfeat[(size_t)b*1560 + c] = mx;
    gfeat[(size_t)b*1560 + 780 + c] = sm / fmaxf((float)cnt, 1.f);
  }
}

// ---------------- protein conv as GEMM ----------------
// WcT[(o*8+k)][i] = Wc[o][i][k]
__global__ void k_wct(const float* __restrict__ Wc, float* __restrict__ WcT){
  int id = blockIdx.x*256 + threadIdx.x;
  if (id < 256000){
    int i = id % 1000, r = id / 1000;
    int o = r >> 3, k = r & 7;
    WcT[id] = Wc[((size_t)o*1000 + i)*8 + k];
  }
}

// P[b][(o*8+k)][u] = sum_i WcT[(o*8+k)][i] * emb[tg_b[i]][u]   (M=256,N=128,K=1000)
__global__ __launch_bounds__(256) void k_gemmP(const float* __restrict__ WcT, const int* __restrict__ target,
                        const float* __restrict__ emb, float* __restrict__ P){
  __shared__ __align__(16) float emb_l[26*128];
  __shared__ __align__(16) float As[16][132];
  __shared__ int tg_l[16];
  int b = blockIdx.y, mo = blockIdx.x;   // mo: 0..1 (row half)
  int tid = threadIdx.x;
  int tx = tid & 15, ty = tid >> 4;
  for (int i=tid;i<26*128;i+=256) emb_l[i]=emb[i];
  const int* tg = target + b*1000;
  float acc[8][8] = {};
  for (int kk=0; kk<1000; kk+=16){
    __syncthreads();
    if (tid < 16) tg_l[tid] = (kk+tid < 1000) ? tg[kk+tid] : 0;
    for (int l=tid; l<128*16; l+=256){
      int m = l >> 4, k = l & 15;
      int gk = kk + k;
      As[k][m] = (gk < 1000) ? WcT[(size_t)(mo*128 + m)*1000 + gk] : 0.f;
    }
    __syncthreads();
    #pragma unroll
    for (int k=0;k<16;++k){
      float4 a0 = *reinterpret_cast<const float4*>(&As[k][ty*4]);
      float4 a1 = *reinterpret_cast<const float4*>(&As[k][64+ty*4]);
      const float* er = emb_l + tg_l[k]*128;
      float4 b0 = *reinterpret_cast<const float4*>(&er[tx*4]);
      float4 b1 = *reinterpret_cast<const float4*>(&er[64+tx*4]);
      float av[8] = {a0.x,a0.y,a0.z,a0.w,a1.x,a1.y,a1.z,a1.w};
      float bv[8] = {b0.x,b0.y,b0.z,b0.w,b1.x,b1.y,b1.z,b1.w};
      #pragma unroll
      for (int i=0;i<8;++i)
        #pragma unroll
        for (int j=0;j<8;++j)
          acc[i][j] += av[i]*bv[j];
    }
  }
  float* Pb = P + (size_t)b*32768 + (size_t)mo*128*128;
  #pragma unroll
  for (int i=0;i<8;++i){
    int r = (i<4) ? ty*4+i : 64+ty*4+(i-4);
    #pragma unroll
    for (int j=0;j<8;++j){
      int c = (j<4) ? tx*4+j : 64+tx*4+(j-4);
      Pb[(size_t)r*128 + c] = acc[i][j];
    }
  }
}

// convc[b][o][t] = sum_k P[b][(o*8+k)][t+k] + bc[o]
__global__ void k_comb(const float* __restrict__ P, const float* __restrict__ bc,
                       float* __restrict__ convc){
  int id = blockIdx.x*256 + threadIdx.x;
  if (id >= 64*32*121) return;
  int b = id / 3872, rem = id % 3872;
  int o = rem / 121, t = rem % 121;
  const float* Pb = P + (size_t)b*32768;
  float s = 0.f;
  #pragma unroll
  for (int k=0;k<8;++k) s += Pb[(size_t)(o*8+k)*128 + t + k];
  convc[id] = s + bc[o];
}

// ---------------- launch ----------------
extern "C" void kernel_launch(void* const* d_in, const int* in_sizes, int n_in,
                              void* d_out, int out_size, void* d_ws, size_t ws_size,
                              hipStream_t stream){
  const float* x   = (const float*)d_in[0];
  const int*   ei    = (const int*)d_in[1];
  const int*   batch = (const int*)d_in[2];
  const int*   target= (const int*)d_in[3];
  const float* W1  = (const float*)d_in[4];
  const float* a1s = (const float*)d_in[5];
  const float* a1d = (const float*)d_in[6];
  const float* b1  = (const float*)d_in[7];
  const float* W2  = (const float*)d_in[8];
  const float* a2s = (const float*)d_in[9];
  const float* a2d = (const float*)d_in[10];
  const float* b2  = (const float*)d_in[11];
  const float* Wg1 = (const float*)d_in[12];
  const float* bg1 = (const float*)d_in[13];
  const float* Wg2 = (const float*)d_in[14];
  const float* bg2 = (const float*)d_in[15];
  const float* emb = (const float*)d_in[16];
  const float* Wc  = (const float*)d_in[17];
  const float* bc  = (const float*)d_in[18];
  const float* Wxt = (const float*)d_in[19];
  const float* bxt = (const float*)d_in[20];
  const float* Wf1 = (const float*)d_in[21];
  const float* bf1 = (const float*)d_in[22];
  const float* Wf2 = (const float*)d_in[23];
  const float* bf2 = (const float*)d_in[24];
  const float* Wo  = (const float*)d_in[25];
  const float* bo  = (const float*)d_in[26];

  int N = in_sizes[0] / 78;
  int Eraw = in_sizes[1] / 2;
  int Bb = in_sizes[3] / 1000;
  int Etot = Eraw + N;

  char* wsp = (char*)d_ws;
  size_t off = 0;
  auto alloc = [&](size_t bytes)->void*{ void* p = wsp + off; off += (bytes + 255) & ~(size_t)255; return p; };
  float* buf1   = (float*)alloc((size_t)N*D1*4);   // h1, later aggG
  float* buf2   = (float*)alloc((size_t)N*D1*4);   // g1
  float* buf3   = (float*)alloc((size_t)N*D1*4);   // P (conv phase), then out2
  float* hs1    = (float*)alloc((size_t)N*HEADS*4);
  float* hd1    = (float*)alloc((size_t)N*HEADS*4);
  float* hsd2   = (float*)alloc((size_t)N*20*4);
  float* Wsd    = (float*)alloc((size_t)D1*20*4);
  int*   counts = (int*)alloc((size_t)N*4);
  int*   row_ptr= (int*)alloc((size_t)(N+1)*4);
  int*   cursor = (int*)alloc((size_t)N*4);
  int*   col_src= (int*)alloc((size_t)Etot*4);
  float* WcT    = (float*)alloc((size_t)256*1000*4);
  float* convc  = (float*)alloc((size_t)Bb*3872*4);
  float* gfeat  = (float*)alloc((size_t)Bb*1560*4);
  float* fcg1   = (float*)alloc((size_t)Bb*1500*4);
  float* xc     = (float*)alloc((size_t)Bb*256*4);
  float* f1     = (float*)alloc((size_t)Bb*1024*4);
  float* f2     = (float*)alloc((size_t)Bb*512*4);
  (void)ws_size; (void)n_in; (void)out_size;

  // ---- CSR by dst (self-loops appended) ----
  hipMemsetAsync(counts, 0, (size_t)N*4, stream);
  int thr=256, blk=(Etot+thr-1)/thr;
  k_count<<<blk,thr,0,stream>>>(ei+Eraw, counts, Eraw, N);
  k_scan<<<1,1024,0,stream>>>(counts, row_ptr, cursor, N);
  k_scatter<<<blk,thr,0,stream>>>(ei, ei+Eraw, cursor, col_src, Eraw, N);

  // ---- protein branch first (P aliases buf3 before out2 use) ----
  float* P = buf3;
  k_wct<<<(256000+255)/256,256,0,stream>>>(Wc, WcT);
  dim3 gP(2, Bb);
  k_gemmP<<<gP,256,0,stream>>>(WcT, target, emb, P);
  k_comb<<<(Bb*3872+255)/256,256,0,stream>>>(P, bc, convc);
  dim3 gXt((128+63)/64, (Bb+63)/64);
  k_gemm<<<gXt,256,0,stream>>>(convc, Wxt, xc+128, bxt, Bb, 128, 3872, 3872, 128, 256, 0);

  // ---- GAT layer 1 ----
  dim3 gW1((D1+127)/128, (N+127)/128);
  k_gemm128<<<gW1,256,0,stream>>>(x, W1, buf1, nullptr, N, D1, 78, 78, D1, D1, 0, 0);
  k_scores1<<<N,256,0,stream>>>(buf1, a1s, a1d, hs1, hd1);
  k_agg1<<<N,256,0,stream>>>(buf1, hs1, hd1, row_ptr, col_src, b1, buf2);

  // ---- GAT layer 2: scores via projection, per-head agg + GEMM-accumulate ----
  k_makews2<<<D1,256,0,stream>>>(W2, a2s, a2d, Wsd);
  dim3 gHS((20+63)/64, (N+63)/64);
  k_gemm<<<gHS,256,0,stream>>>(buf2, Wsd, hsd2, nullptr, N, 20, D1, D1, 20, 20, 0);
  float* aggG = buf1;
  float* out2 = buf3;
  for (int h=0; h<HEADS; ++h){
    k_aggH<<<(N+3)/4,256,0,stream>>>(buf2, hsd2, row_ptr, col_src, aggG, h, N);
    k_gemm128<<<gW1,256,0,stream>>>(aggG, W2 + h*D1, out2, nullptr, N, D1, D1, D1, 7800, D1, 0, h==0?0:1);
  }

  // ---- pooling (bias+relu fused) ----
  k_pool<<<Bb,256,0,stream>>>(out2, b2, batch, N, gfeat);

  // ---- graph FCs ----
  dim3 gG1((1500+63)/64, (Bb+63)/64);
  k_gemm<<<gG1,256,0,stream>>>(gfeat, Wg1, fcg1, bg1, Bb, 1500, 1560, 1560, 1500, 1500, 1);
  dim3 gG2((128+63)/64, (Bb+63)/64);
  k_gemm<<<gG2,256,0,stream>>>(fcg1, Wg2, xc, bg2, Bb, 128, 1500, 1500, 128, 256, 1);

  // ---- fusion MLP ----
  dim3 gF1((1024+63)/64, (Bb+63)/64);
  k_gemm<<<gF1,256,0,stream>>>(xc, Wf1, f1, bf1, Bb, 1024, 256, 256, 1024, 1024, 1);
  dim3 gF2((512+63)/64, (Bb+63)/64);
  k_gemm<<<gF2,256,0,stream>>>(f1, Wf2, f2, bf2, Bb, 512, 1024, 1024, 512, 512, 1);
  dim3 gFo(1, (Bb+63)/64);
  k_gemm<<<gFo,256,0,stream>>>(f2, Wo, (float*)d_out, bo, Bb, 1, 512, 512, 1, 1, 0);
}

// Round 3
// 2280.996 us; speedup vs baseline: 2.9282x; 2.7684x over previous
//
#include <hip/hip_runtime.h>
#include <math.h>

#define HEADS 10
#define D1 780
#define F1 78

typedef __attribute__((ext_vector_type(8))) short bf16x8;
typedef __attribute__((ext_vector_type(4))) float f32x4;

static __device__ __forceinline__ float lrelu(float x){ return x > 0.f ? x : 0.2f*x; }

static __device__ __forceinline__ unsigned short f2bf(float f){
  unsigned int u = __float_as_uint(f);
  u += 0x7fffu + ((u >> 16) & 1u);   // RNE
  return (unsigned short)(u >> 16);
}

// ---------------- CSR build ----------------
__global__ void k_count(const int* __restrict__ dst, int* __restrict__ counts, int Eraw, int N){
  int e = blockIdx.x*blockDim.x + threadIdx.x;
  if (e < Eraw + N){
    int d = (e < Eraw) ? dst[e] : (e - Eraw);
    atomicAdd(&counts[d], 1);
  }
}

__global__ void k_scan(const int* __restrict__ counts, int* __restrict__ row_ptr,
                       int* __restrict__ cursor, int N){
  __shared__ int part[1024];
  int tid = threadIdx.x;
  int chunk = (N + 1023)/1024;
  int beg = tid*chunk, end = min(beg+chunk, N);
  int s = 0;
  for (int i=beg;i<end;++i) s += counts[i];
  part[tid] = s;
  __syncthreads();
  for (int off=1; off<1024; off<<=1){
    int v = (tid >= off) ? part[tid-off] : 0;
    __syncthreads();
    part[tid] += v;
    __syncthreads();
  }
  int excl = (tid>0) ? part[tid-1] : 0;
  for (int i=beg;i<end;++i){ row_ptr[i]=excl; cursor[i]=excl; excl += counts[i]; }
  if (tid == 1023) row_ptr[N] = part[1023];
}

__global__ void k_scatter(const int* __restrict__ src, const int* __restrict__ dst,
                          int* __restrict__ cursor, int* __restrict__ col_src, int Eraw, int N){
  int e = blockIdx.x*blockDim.x + threadIdx.x;
  if (e < Eraw + N){
    int s, d;
    if (e < Eraw){ s = src[e]; d = dst[e]; } else { s = e - Eraw; d = s; }
    int pos = atomicAdd(&cursor[d], 1);
    col_src[pos] = s;
  }
}

// ---------------- 128x128 tiled fp32 GEMM (W1 only) ----------------
__global__ __launch_bounds__(256) void k_gemm128(const float* __restrict__ A, const float* __restrict__ Bm,
                       float* __restrict__ C, const float* __restrict__ bias,
                       int M, int Nn, int K, int lda, int ldb, int ldc, int act, int accum){
  __shared__ __align__(16) float As[16][132];
  __shared__ __align__(16) float Bs[16][132];
  int tid = threadIdx.x;
  int tx = tid & 15, ty = tid >> 4;
  int row0 = blockIdx.y*128, col0 = blockIdx.x*128;
  float acc[8][8] = {};
  for (int kk=0; kk<K; kk+=16){
    for (int l = tid; l < 128*16; l += 256){
      int m = l >> 4, k = l & 15;
      int gr = row0 + m, gk = kk + k;
      As[k][m] = (gr < M && gk < K) ? A[(size_t)gr*lda + gk] : 0.f;
    }
    for (int l = tid; l < 16*128; l += 256){
      int k = l >> 7, n = l & 127;
      int gk = kk + k, gc = col0 + n;
      Bs[k][n] = (gk < K && gc < Nn) ? Bm[(size_t)gk*ldb + gc] : 0.f;
    }
    __syncthreads();
    #pragma unroll
    for (int k=0;k<16;++k){
      float4 a0 = *reinterpret_cast<const float4*>(&As[k][ty*4]);
      float4 a1 = *reinterpret_cast<const float4*>(&As[k][64+ty*4]);
      float4 b0 = *reinterpret_cast<const float4*>(&Bs[k][tx*4]);
      float4 b1 = *reinterpret_cast<const float4*>(&Bs[k][64+tx*4]);
      float av[8] = {a0.x,a0.y,a0.z,a0.w,a1.x,a1.y,a1.z,a1.w};
      float bv[8] = {b0.x,b0.y,b0.z,b0.w,b1.x,b1.y,b1.z,b1.w};
      #pragma unroll
      for (int i=0;i<8;++i)
        #pragma unroll
        for (int j=0;j<8;++j)
          acc[i][j] += av[i]*bv[j];
    }
    __syncthreads();
  }
  #pragma unroll
  for (int i=0;i<8;++i){
    int r = row0 + ((i<4) ? ty*4+i : 64+ty*4+(i-4));
    if (r >= M) continue;
    #pragma unroll
    for (int j=0;j<8;++j){
      int c = col0 + ((j<4) ? tx*4+j : 64+tx*4+(j-4));
      if (c >= Nn) continue;
      float v = acc[i][j];
      if (accum) v += C[(size_t)r*ldc + c];
      if (bias) v += bias[c];
      if (act == 1) v = fmaxf(v, 0.f);
      C[(size_t)r*ldc + c] = v;
    }
  }
}

// ---------------- 64x64 tiled fp32 GEMM (hsd2 only) ----------------
__global__ __launch_bounds__(256) void k_gemm(const float* __restrict__ A, const float* __restrict__ Bm,
                       float* __restrict__ C, const float* __restrict__ bias,
                       int M, int Nn, int K, int lda, int ldb, int ldc, int act){
  __shared__ __align__(16) float As[16][68];
  __shared__ __align__(16) float Bs[16][68];
  int tid = threadIdx.x;
  int tx = tid & 15, ty = tid >> 4;
  int row0 = blockIdx.y*64, col0 = blockIdx.x*64;
  float acc[4][4] = {};
  for (int kk=0; kk<K; kk+=16){
    for (int l = tid; l < 64*16; l += 256){
      int m = l >> 4, k = l & 15;
      int gr = row0 + m, gk = kk + k;
      As[k][m] = (gr < M && gk < K) ? A[(size_t)gr*lda + gk] : 0.f;
    }
    for (int l = tid; l < 16*64; l += 256){
      int k = l >> 6, n = l & 63;
      int gk = kk + k, gc = col0 + n;
      Bs[k][n] = (gk < K && gc < Nn) ? Bm[(size_t)gk*ldb + gc] : 0.f;
    }
    __syncthreads();
    #pragma unroll
    for (int k=0;k<16;++k){
      float4 a = *reinterpret_cast<const float4*>(&As[k][ty*4]);
      float4 b = *reinterpret_cast<const float4*>(&Bs[k][tx*4]);
      float av[4] = {a.x,a.y,a.z,a.w};
      float bv[4] = {b.x,b.y,b.z,b.w};
      #pragma unroll
      for (int i=0;i<4;++i)
        #pragma unroll
        for (int j=0;j<4;++j)
          acc[i][j] += av[i]*bv[j];
    }
    __syncthreads();
  }
  #pragma unroll
  for (int i=0;i<4;++i){
    int r = row0 + ty*4 + i;
    if (r >= M) continue;
    #pragma unroll
    for (int j=0;j<4;++j){
      int c = col0 + tx*4 + j;
      if (c >= Nn) continue;
      float v = acc[i][j];
      if (bias) v += bias[c];
      if (act == 1) v = fmaxf(v, 0.f);
      C[(size_t)r*ldc + c] = v;
    }
  }
}

// ---------------- MFMA bf16 NT GEMM: C[M,N] (+)= A[M,K] @ BT[N,K]^T ----------------
// A, BT bf16 (as short), K % 32 == 0, 128x128 tile, 4 waves of 64x64.
__global__ __launch_bounds__(256) void k_mfma_nt(const short* __restrict__ A, const short* __restrict__ BT,
                        float* __restrict__ C, int M, int N, int K,
                        int lda, int ldb, int ldc, int accum){
  __shared__ __align__(16) short As[128][40];
  __shared__ __align__(16) short Bs[128][40];
  int tid = threadIdx.x;
  int lane = tid & 63, wave = tid >> 6;
  int wr = (wave >> 1) * 64, wc = (wave & 1) * 64;
  int row0 = blockIdx.y*128, col0 = blockIdx.x*128;
  f32x4 acc[4][4];
  #pragma unroll
  for (int i=0;i<4;++i)
    #pragma unroll
    for (int j=0;j<4;++j) acc[i][j] = (f32x4){0.f,0.f,0.f,0.f};

  for (int k0=0; k0<K; k0+=32){
    #pragma unroll
    for (int it=0; it<2; ++it){
      int s = tid + it*256;
      int r = s >> 2, kp = (s & 3) * 8;
      uint4 va = {0,0,0,0}, vb = {0,0,0,0};
      int gr = row0 + r;
      if (gr < M) va = *reinterpret_cast<const uint4*>(&A[(size_t)gr*lda + k0 + kp]);
      int gc = col0 + r;
      if (gc < N) vb = *reinterpret_cast<const uint4*>(&BT[(size_t)gc*ldb + k0 + kp]);
      *reinterpret_cast<uint4*>(&As[r][kp]) = va;
      *reinterpret_cast<uint4*>(&Bs[r][kp]) = vb;
    }
    __syncthreads();
    bf16x8 af[4], bf[4];
    #pragma unroll
    for (int rb=0;rb<4;++rb)
      af[rb] = *reinterpret_cast<const bf16x8*>(&As[wr + rb*16 + (lane&15)][(lane>>4)*8]);
    #pragma unroll
    for (int cb=0;cb<4;++cb)
      bf[cb] = *reinterpret_cast<const bf16x8*>(&Bs[wc + cb*16 + (lane&15)][(lane>>4)*8]);
    #pragma unroll
    for (int rb=0;rb<4;++rb)
      #pragma unroll
      for (int cb=0;cb<4;++cb)
        acc[rb][cb] = __builtin_amdgcn_mfma_f32_16x16x32_bf16(af[rb], bf[cb], acc[rb][cb], 0, 0, 0);
    __syncthreads();
  }
  // C/D layout: col = lane&15, row = (lane>>4)*4 + j
  #pragma unroll
  for (int rb=0;rb<4;++rb){
    #pragma unroll
    for (int cb=0;cb<4;++cb){
      int c = col0 + wc + cb*16 + (lane & 15);
      if (c >= N) continue;
      #pragma unroll
      for (int j=0;j<4;++j){
        int r = row0 + wr + rb*16 + (lane>>4)*4 + j;
        if (r >= M) continue;
        float v = acc[rb][cb][j];
        if (accum) v += C[(size_t)r*ldc + c];
        C[(size_t)r*ldc + c] = v;
      }
    }
  }
}

// ---------------- W2 repack: W2rT[c][h*800+k] = bf16(W2[k][h*780+c]), zero pad k>=780 ----------------
__global__ void k_w2t(const float* __restrict__ W2, short* __restrict__ W2rT){
  __shared__ float s[32][33];
  int k0 = blockIdx.x*32, c0 = blockIdx.y*32, h = blockIdx.z;
  int tx = threadIdx.x, ty = threadIdx.y;
  #pragma unroll
  for (int i=0;i<32;i+=8){
    int k = k0+ty+i, c = c0+tx;
    s[ty+i][tx] = (k < 780 && c < 780) ? W2[(size_t)k*7800 + h*780 + c] : 0.f;
  }
  __syncthreads();
  #pragma unroll
  for (int i=0;i<32;i+=8){
    int c = c0+ty+i, k = k0+tx;
    if (c < 780 && k < 800)
      W2rT[(size_t)c*8000 + h*800 + k] = (short)f2bf(s[tx][ty+i]);
  }
}

// ---------------- GAT layer 1 ----------------
__global__ void k_scores1(const float* __restrict__ h1, const float* __restrict__ a1s,
                          const float* __restrict__ a1d, float* __restrict__ hs, float* __restrict__ hd){
  __shared__ float ss[HEADS], sd[HEADS];
  int n = blockIdx.x, tid = threadIdx.x;
  if (tid < HEADS){ ss[tid]=0.f; sd[tid]=0.f; }
  __syncthreads();
  const float* hr = h1 + (size_t)n*D1;
  for (int c = tid; c < D1; c += blockDim.x){
    float v = hr[c];
    int h = c / F1;
    atomicAdd(&ss[h], v*a1s[c]);
    atomicAdd(&sd[h], v*a1d[c]);
  }
  __syncthreads();
  if (tid < HEADS){ hs[n*HEADS+tid]=ss[tid]; hd[n*HEADS+tid]=sd[tid]; }
}

#define CH1 32
__global__ __launch_bounds__(256) void k_agg1(const float* __restrict__ h1, const float* __restrict__ hs,
                       const float* __restrict__ hd, const int* __restrict__ row_ptr,
                       const int* __restrict__ col_src, const float* __restrict__ b1,
                       float* __restrict__ g1o){
  __shared__ float m_l[HEADS], s_l[HEADS];
  __shared__ float al[CH1][HEADS];
  __shared__ int src_l[CH1];
  int n = blockIdx.x, tid = threadIdx.x;
  int beg = row_ptr[n], end = row_ptr[n+1];
  if (tid < HEADS){
    float hdv = hd[n*HEADS + tid];
    float m = -1e30f;
    for (int j=beg;j<end;++j){
      float sc = lrelu(hs[col_src[j]*HEADS + tid] + hdv);
      m = fmaxf(m, sc);
    }
    float s = 0.f;
    for (int j=beg;j<end;++j){
      float sc = lrelu(hs[col_src[j]*HEADS + tid] + hdv);
      s += expf(sc - m);
    }
    m_l[tid]=m; s_l[tid]=s;
  }
  __syncthreads();
  float acc[4] = {0.f,0.f,0.f,0.f};
  for (int j0=beg; j0<end; j0+=CH1){
    int cn = min(CH1, end-j0);
    for (int p=tid; p<cn*HEADS; p+=256){
      int j = p/HEADS, h = p - j*HEADS;
      int sidx = col_src[j0+j];
      if (h==0) src_l[j] = sidx;
      float sc = lrelu(hs[sidx*HEADS+h] + hd[n*HEADS+h]);
      al[j][h] = expf(sc - m_l[h]) / s_l[h];
    }
    __syncthreads();
    for (int j=0;j<cn;++j){
      const float* hr = h1 + (size_t)src_l[j]*D1;
      #pragma unroll
      for (int r=0;r<4;++r){
        int c = tid + r*256;
        if (c < D1) acc[r] += al[j][c/F1] * hr[c];
      }
    }
    __syncthreads();
  }
  #pragma unroll
  for (int r=0;r<4;++r){
    int c = tid + r*256;
    if (c < D1){
      float v = acc[r] + b1[c];
      g1o[(size_t)n*D1 + c] = v > 0.f ? v : expm1f(v);
    }
  }
}

// ---------------- layer-2 score projections ----------------
__global__ void k_makews2(const float* __restrict__ W2, const float* __restrict__ a2s,
                          const float* __restrict__ a2d, float* __restrict__ Wsd){
  __shared__ float out[20];
  int c = blockIdx.x, tid = threadIdx.x;
  if (tid < 20) out[tid] = 0.f;
  __syncthreads();
  const float* row = W2 + (size_t)c*7800;
  for (int j = tid; j < 7800; j += 256){
    float v = row[j];
    int h = j / D1;
    atomicAdd(&out[h],    v * a2s[j]);
    atomicAdd(&out[10+h], v * a2d[j]);
  }
  __syncthreads();
  if (tid < 20) Wsd[c*20 + tid] = out[tid];
}

// ---------------- fused all-head aggregation -> aggG10 bf16 [N][10*800] ----------------
__global__ __launch_bounds__(256) void k_aggAll(const float* __restrict__ g1, const float* __restrict__ hsd,
                       const int* __restrict__ row_ptr, const int* __restrict__ col_src,
                       short* __restrict__ aggG10){
  __shared__ float m_l[HEADS], s_l[HEADS];
  __shared__ float al[16][HEADS];
  __shared__ int src_l[16];
  int n = blockIdx.x, tid = threadIdx.x;
  int beg = row_ptr[n], end = row_ptr[n+1];
  if (tid < HEADS){
    float hdv = hsd[n*20 + 10 + tid];
    float m = -1e30f;
    for (int j=beg;j<end;++j) m = fmaxf(m, lrelu(hsd[col_src[j]*20 + tid] + hdv));
    float s = 0.f;
    for (int j=beg;j<end;++j) s += expf(lrelu(hsd[col_src[j]*20 + tid] + hdv) - m);
    m_l[tid]=m; s_l[tid]=s;
  }
  __syncthreads();
  float acc[4][HEADS] = {};
  for (int j0=beg; j0<end; j0+=16){
    int cn = min(16, end-j0);
    for (int p=tid; p<cn*HEADS; p+=256){
      int j = p/HEADS, h = p - j*HEADS;
      int sidx = col_src[j0+j];
      if (h==0) src_l[j] = sidx;
      float hdv = hsd[n*20 + 10 + h];
      al[j][h] = 0.1f * expf(lrelu(hsd[sidx*20 + h] + hdv) - m_l[h]) / s_l[h];
    }
    __syncthreads();
    for (int j=0;j<cn;++j){
      const float* gr = g1 + (size_t)src_l[j]*D1;
      #pragma unroll
      for (int r=0;r<4;++r){
        int c = tid + r*256;
        if (c < D1){
          float v = gr[c];
          #pragma unroll
          for (int h=0;h<HEADS;++h) acc[r][h] += al[j][h]*v;
        }
      }
    }
    __syncthreads();
  }
  short* og = aggG10 + (size_t)n*8000;
  #pragma unroll
  for (int r=0;r<4;++r){
    int c = tid + r*256;
    if (c < D1){
      #pragma unroll
      for (int h=0;h<HEADS;++h) og[h*800 + c] = (short)f2bf(acc[r][h]);
    }
  }
  if (tid < 200){ int h = tid/20, c2 = 780 + tid%20; og[h*800 + c2] = 0; }
}

// ---------------- per-head aggregation fallback -> aggG bf16 [N][800] ----------------
__global__ __launch_bounds__(256) void k_aggH(const float* __restrict__ g1, const float* __restrict__ hsd,
                       const int* __restrict__ row_ptr, const int* __restrict__ col_src,
                       short* __restrict__ aggG, int h, int N){
  int n = blockIdx.x*4 + (threadIdx.x >> 6);
  if (n >= N) return;
  int lane = threadIdx.x & 63;
  int beg = row_ptr[n], end = row_ptr[n+1];
  float hdv = hsd[n*20 + 10 + h];
  float m = -1e30f;
  for (int j=beg;j<end;++j) m = fmaxf(m, lrelu(hsd[col_src[j]*20 + h] + hdv));
  float denom = 0.f;
  for (int j=beg;j<end;++j) denom += expf(lrelu(hsd[col_src[j]*20 + h] + hdv) - m);
  float acc[13] = {};
  for (int j=beg;j<end;++j){
    int s = col_src[j];
    float a = 0.1f * expf(lrelu(hsd[s*20 + h] + hdv) - m) / denom;
    const float* gr = g1 + (size_t)s*D1;
    #pragma unroll
    for (int r=0;r<12;++r) acc[r] += a * gr[lane + r*64];
    if (lane < 12) acc[12] += a * gr[768 + lane];
  }
  short* og = aggG + (size_t)n*800;
  #pragma unroll
  for (int r=0;r<12;++r) og[lane + r*64] = (short)f2bf(acc[r]);
  int c = 768 + lane;
  if (c < 800) og[c] = (c < D1) ? (short)f2bf(acc[12]) : (short)0;
}

// ---------------- pooling ----------------
__device__ __forceinline__ int lowb(const int* a, int n, int v){
  int lo=0, hi=n;
  while (lo<hi){ int mid=(lo+hi)>>1; if (a[mid]<v) lo=mid+1; else hi=mid; }
  return lo;
}

__global__ void k_pool(const float* __restrict__ out2, const float* __restrict__ b2,
                       const int* __restrict__ batch, int N, float* __restrict__ gfeat){
  int b = blockIdx.x, tid = threadIdx.x;
  int lo = lowb(batch, N, b), hi = lowb(batch, N, b+1);
  #pragma unroll
  for (int r=0;r<4;++r){
    int c = tid + r*256;
    if (c >= D1) continue;
    float bb = b2[c];
    float mx = -INFINITY, sm = 0.f;
    for (int n2=lo;n2<hi;++n2){
      float v = out2[(size_t)n2*D1 + c] + bb;
      v = fmaxf(v, 0.f);
      mx = fmaxf(mx, v);
      sm += v;
    }
    int cnt = hi-lo;
    gfeat[(size_t)b*1560 + c] = mx;
    gfeat[(size_t)b*1560 + 780 + c] = sm / fmaxf((float)cnt, 1.f);
  }
}

// ---------------- protein conv as GEMM ----------------
__global__ void k_wct(const float* __restrict__ Wc, float* __restrict__ WcT){
  int id = blockIdx.x*256 + threadIdx.x;
  if (id < 256000){
    int i = id % 1000, r = id / 1000;
    int o = r >> 3, k = r & 7;
    WcT[id] = Wc[((size_t)o*1000 + i)*8 + k];
  }
}

__global__ __launch_bounds__(256) void k_gemmP(const float* __restrict__ WcT, const int* __restrict__ target,
                        const float* __restrict__ emb, float* __restrict__ P){
  __shared__ __align__(16) float emb_l[26*128];
  __shared__ __align__(16) float As[16][132];
  __shared__ int tg_l[16];
  int b = blockIdx.y, mo = blockIdx.x;
  int tid = threadIdx.x;
  int tx = tid & 15, ty = tid >> 4;
  for (int i=tid;i<26*128;i+=256) emb_l[i]=emb[i];
  const int* tg = target + b*1000;
  float acc[8][8] = {};
  for (int kk=0; kk<1000; kk+=16){
    __syncthreads();
    if (tid < 16) tg_l[tid] = (kk+tid < 1000) ? tg[kk+tid] : 0;
    for (int l=tid; l<128*16; l+=256){
      int m = l >> 4, k = l & 15;
      int gk = kk + k;
      As[k][m] = (gk < 1000) ? WcT[(size_t)(mo*128 + m)*1000 + gk] : 0.f;
    }
    __syncthreads();
    #pragma unroll
    for (int k=0;k<16;++k){
      float4 a0 = *reinterpret_cast<const float4*>(&As[k][ty*4]);
      float4 a1 = *reinterpret_cast<const float4*>(&As[k][64+ty*4]);
      const float* er = emb_l + tg_l[k]*128;
      float4 b0 = *reinterpret_cast<const float4*>(&er[tx*4]);
      float4 b1 = *reinterpret_cast<const float4*>(&er[64+tx*4]);
      float av[8] = {a0.x,a0.y,a0.z,a0.w,a1.x,a1.y,a1.z,a1.w};
      float bv[8] = {b0.x,b0.y,b0.z,b0.w,b1.x,b1.y,b1.z,b1.w};
      #pragma unroll
      for (int i=0;i<8;++i)
        #pragma unroll
        for (int j=0;j<8;++j)
          acc[i][j] += av[i]*bv[j];
    }
  }
  float* Pb = P + (size_t)b*32768 + (size_t)mo*128*128;
  #pragma unroll
  for (int i=0;i<8;++i){
    int r = (i<4) ? ty*4+i : 64+ty*4+(i-4);
    #pragma unroll
    for (int j=0;j<8;++j){
      int c = (j<4) ? tx*4+j : 64+tx*4+(j-4);
      Pb[(size_t)r*128 + c] = acc[i][j];
    }
  }
}

__global__ void k_comb(const float* __restrict__ P, const float* __restrict__ bc,
                       float* __restrict__ convc){
  int id = blockIdx.x*256 + threadIdx.x;
  if (id >= 64*32*121) return;
  int b = id / 3872, rem = id % 3872;
  int o = rem / 121, t = rem % 121;
  const float* Pb = P + (size_t)b*32768;
  float s = 0.f;
  #pragma unroll
  for (int k=0;k<8;++k) s += Pb[(size_t)(o*8+k)*128 + t + k];
  convc[id] = s + bc[o];
}

// ---------------- split-K skinny GEMM (M<=64): atomicAdd partials into zeroed C ----------------
__global__ __launch_bounds__(256) void k_skinny(const float* __restrict__ A, const float* __restrict__ B,
                        float* __restrict__ C, int M, int N, int K, int ldb, int ldc, int kc){
  int col0 = blockIdx.x*64;
  int k0 = blockIdx.y*kc, k1 = min(K, k0+kc);
  int tx = threadIdx.x & 63, ty = threadIdx.x >> 6;
  int col = col0 + tx;
  if (col >= N) return;
  float acc[16] = {};
  for (int k=k0; k<k1; ++k){
    float b = B[(size_t)k*ldb + col];
    const float* Ak = A + (size_t)(ty*16)*K + k;
    #pragma unroll
    for (int i=0;i<16;++i) acc[i] += Ak[(size_t)i*K] * b;
  }
  #pragma unroll
  for (int i=0;i<16;++i){
    int r = ty*16 + i;
    if (r < M) atomicAdd(&C[(size_t)r*ldc + col], acc[i]);
  }
}

__global__ void k_biasact(float* __restrict__ C, const float* __restrict__ bias,
                          int M, int N, int ldc, int act){
  int id = blockIdx.x*256 + threadIdx.x;
  if (id >= M*N) return;
  int r = id / N, c = id % N;
  float v = C[(size_t)r*ldc + c] + bias[c];
  if (act == 1) v = fmaxf(v, 0.f);
  C[(size_t)r*ldc + c] = v;
}

// ---------------- final Wo dot ----------------
__global__ void k_wo(const float* __restrict__ f2, const float* __restrict__ Wo,
                     const float* __restrict__ bo, float* __restrict__ out, int M){
  __shared__ float red[256];
  int tid = threadIdx.x;
  int r = tid & 63, kg = tid >> 6;
  float p = 0.f;
  for (int k = kg*128; k < kg*128 + 128; ++k) p += f2[(size_t)r*512 + k] * Wo[k];
  red[tid] = p;
  __syncthreads();
  if (tid < 64 && tid < M) out[tid] = red[tid] + red[tid+64] + red[tid+128] + red[tid+192] + bo[0];
}

// ---------------- launch ----------------
extern "C" void kernel_launch(void* const* d_in, const int* in_sizes, int n_in,
                              void* d_out, int out_size, void* d_ws, size_t ws_size,
                              hipStream_t stream){
  const float* x   = (const float*)d_in[0];
  const int*   ei    = (const int*)d_in[1];
  const int*   batch = (const int*)d_in[2];
  const int*   target= (const int*)d_in[3];
  const float* W1  = (const float*)d_in[4];
  const float* a1s = (const float*)d_in[5];
  const float* a1d = (const float*)d_in[6];
  const float* b1  = (const float*)d_in[7];
  const float* W2  = (const float*)d_in[8];
  const float* a2s = (const float*)d_in[9];
  const float* a2d = (const float*)d_in[10];
  const float* b2  = (const float*)d_in[11];
  const float* Wg1 = (const float*)d_in[12];
  const float* bg1 = (const float*)d_in[13];
  const float* Wg2 = (const float*)d_in[14];
  const float* bg2 = (const float*)d_in[15];
  const float* emb = (const float*)d_in[16];
  const float* Wc  = (const float*)d_in[17];
  const float* bc  = (const float*)d_in[18];
  const float* Wxt = (const float*)d_in[19];
  const float* bxt = (const float*)d_in[20];
  const float* Wf1 = (const float*)d_in[21];
  const float* bf1 = (const float*)d_in[22];
  const float* Wf2 = (const float*)d_in[23];
  const float* bf2 = (const float*)d_in[24];
  const float* Wo  = (const float*)d_in[25];
  const float* bo  = (const float*)d_in[26];

  int N = in_sizes[0] / 78;
  int Eraw = in_sizes[1] / 2;
  int Bb = in_sizes[3] / 1000;
  int Etot = Eraw + N;

  char* wsp = (char*)d_ws;
  size_t off = 0;
  auto alloc = [&](size_t bytes)->void*{ void* p = wsp + off; off += (bytes + 255) & ~(size_t)255; return p; };
  float* buf1   = (float*)alloc((size_t)N*D1*4);   // h1
  float* buf2   = (float*)alloc((size_t)N*D1*4);   // g1
  float* buf3   = (float*)alloc((size_t)N*D1*4);   // P (conv), then out2
  float* hs1    = (float*)alloc((size_t)N*HEADS*4);
  float* hd1    = (float*)alloc((size_t)N*HEADS*4);
  float* hsd2   = (float*)alloc((size_t)N*20*4);
  float* Wsd    = (float*)alloc((size_t)D1*20*4);
  int*   counts = (int*)alloc((size_t)N*4);
  int*   row_ptr= (int*)alloc((size_t)(N+1)*4);
  int*   cursor = (int*)alloc((size_t)N*4);
  int*   col_src= (int*)alloc((size_t)Etot*4);
  float* WcT    = (float*)alloc((size_t)256*1000*4);
  float* convc  = (float*)alloc((size_t)Bb*3872*4);
  float* gfeat  = (float*)alloc((size_t)Bb*1560*4);
  float* fcg1   = (float*)alloc((size_t)Bb*1500*4);
  float* xc     = (float*)alloc((size_t)Bb*256*4);
  float* f1     = (float*)alloc((size_t)Bb*1024*4);
  float* f2     = (float*)alloc((size_t)Bb*512*4);
  short* W2rT   = (short*)alloc((size_t)D1*8000*2);  // [c][h*800+k] bf16
  // fused path needs N*8000*2 bytes for aggG10; fallback needs N*800*2
  size_t fused_bytes = (size_t)N*8000*2;
  int fused = (ws_size > off + fused_bytes + (1u<<20)) ? 1 : 0;
  short* aggB = (short*)alloc(fused ? fused_bytes : (size_t)N*800*2);
  (void)n_in; (void)out_size;

  // ---- CSR by dst (self-loops appended) ----
  hipMemsetAsync(counts, 0, (size_t)N*4, stream);
  int thr=256, blk=(Etot+thr-1)/thr;
  k_count<<<blk,thr,0,stream>>>(ei+Eraw, counts, Eraw, N);
  k_scan<<<1,1024,0,stream>>>(counts, row_ptr, cursor, N);
  k_scatter<<<blk,thr,0,stream>>>(ei, ei+Eraw, cursor, col_src, Eraw, N);

  // ---- zero atomic-target buffers ----
  hipMemsetAsync(fcg1, 0, (size_t)Bb*1500*4, stream);
  hipMemsetAsync(xc,   0, (size_t)Bb*256*4,  stream);
  hipMemsetAsync(f1,   0, (size_t)Bb*1024*4, stream);
  hipMemsetAsync(f2,   0, (size_t)Bb*512*4,  stream);

  // ---- protein branch (P aliases buf3 before out2 use) ----
  float* P = buf3;
  k_wct<<<(256000+255)/256,256,0,stream>>>(Wc, WcT);
  dim3 gP(2, Bb);
  k_gemmP<<<gP,256,0,stream>>>(WcT, target, emb, P);
  k_comb<<<(Bb*3872+255)/256,256,0,stream>>>(P, bc, convc);
  { dim3 g((128+63)/64, (3872+127)/128);
    k_skinny<<<g,256,0,stream>>>(convc, Wxt, xc+128, Bb, 128, 3872, 128, 256, 128);
    k_biasact<<<(Bb*128+255)/256,256,0,stream>>>(xc+128, bxt, Bb, 128, 256, 0); }

  // ---- GAT layer 1 ----
  dim3 gW1((D1+127)/128, (N+127)/128);
  k_gemm128<<<gW1,256,0,stream>>>(x, W1, buf1, nullptr, N, D1, 78, 78, D1, D1, 0, 0);
  k_scores1<<<N,256,0,stream>>>(buf1, a1s, a1d, hs1, hd1);
  k_agg1<<<N,256,0,stream>>>(buf1, hs1, hd1, row_ptr, col_src, b1, buf2);

  // ---- GAT layer 2 ----
  k_makews2<<<D1,256,0,stream>>>(W2, a2s, a2d, Wsd);
  dim3 gHS(1, (N+63)/64);
  k_gemm<<<gHS,256,0,stream>>>(buf2, Wsd, hsd2, nullptr, N, 20, D1, D1, 20, 20, 0);
  { dim3 g(25, 25, 10); dim3 b(32, 8);
    k_w2t<<<g,b,0,stream>>>(W2, W2rT); }

  float* out2 = buf3;
  dim3 gMM((D1+127)/128, (N+127)/128);
  if (fused){
    k_aggAll<<<N,256,0,stream>>>(buf2, hsd2, row_ptr, col_src, aggB);
    k_mfma_nt<<<gMM,256,0,stream>>>(aggB, W2rT, out2, N, D1, 8000, 8000, 8000, D1, 0);
  } else {
    for (int h=0; h<HEADS; ++h){
      k_aggH<<<(N+3)/4,256,0,stream>>>(buf2, hsd2, row_ptr, col_src, aggB, h, N);
      k_mfma_nt<<<gMM,256,0,stream>>>(aggB, W2rT + h*800, out2, N, D1, 800, 800, 8000, D1, h==0?0:1);
    }
  }

  // ---- pooling (bias+relu fused) ----
  k_pool<<<Bb,256,0,stream>>>(out2, b2, batch, N, gfeat);

  // ---- graph FCs (split-K skinny) ----
  { dim3 g((1500+63)/64, (1560+127)/128);
    k_skinny<<<g,256,0,stream>>>(gfeat, Wg1, fcg1, Bb, 1500, 1560, 1500, 1500, 128);
    k_biasact<<<(Bb*1500+255)/256,256,0,stream>>>(fcg1, bg1, Bb, 1500, 1500, 1); }
  { dim3 g((128+63)/64, (1500+127)/128);
    k_skinny<<<g,256,0,stream>>>(fcg1, Wg2, xc, Bb, 128, 1500, 128, 256, 128);
    k_biasact<<<(Bb*128+255)/256,256,0,stream>>>(xc, bg2, Bb, 128, 256, 1); }

  // ---- fusion MLP ----
  { dim3 g((1024+63)/64, (256+127)/128);
    k_skinny<<<g,256,0,stream>>>(xc, Wf1, f1, Bb, 1024, 256, 1024, 1024, 128);
    k_biasact<<<(Bb*1024+255)/256,256,0,stream>>>(f1, bf1, Bb, 1024, 1024, 1); }
  { dim3 g((512+63)/64, (1024+127)/128);
    k_skinny<<<g,256,0,stream>>>(f1, Wf2, f2, Bb, 512, 1024, 512, 512, 128);
    k_biasact<<<(Bb*512+255)/256,256,0,stream>>>(f2, bf2, Bb, 512, 512, 1); }
  k_wo<<<1,256,0,stream>>>(f2, Wo, bo, (float*)d_out, Bb);
}

// Round 4
// 2005.051 us; speedup vs baseline: 3.3312x; 1.1376x over previous
//
#include <hip/hip_runtime.h>
#include <math.h>

#define HEADS 10
#define D1 780
#define F1 78

typedef __attribute__((ext_vector_type(8))) short bf16x8;
typedef __attribute__((ext_vector_type(4))) float f32x4;

static __device__ __forceinline__ float lrelu(float x){ return x > 0.f ? x : 0.2f*x; }

static __device__ __forceinline__ unsigned short f2bf(float f){
  unsigned int u = __float_as_uint(f);
  u += 0x7fffu + ((u >> 16) & 1u);   // RNE
  return (unsigned short)(u >> 16);
}

// ---------------- CSR build ----------------
__global__ void k_count(const int* __restrict__ dst, int* __restrict__ counts, int Eraw, int N){
  int e = blockIdx.x*blockDim.x + threadIdx.x;
  if (e < Eraw + N){
    int d = (e < Eraw) ? dst[e] : (e - Eraw);
    atomicAdd(&counts[d], 1);
  }
}

__global__ void k_scan(const int* __restrict__ counts, int* __restrict__ row_ptr,
                       int* __restrict__ cursor, int N){
  __shared__ int part[1024];
  int tid = threadIdx.x;
  int chunk = (N + 1023)/1024;
  int beg = tid*chunk, end = min(beg+chunk, N);
  int s = 0;
  for (int i=beg;i<end;++i) s += counts[i];
  part[tid] = s;
  __syncthreads();
  for (int off=1; off<1024; off<<=1){
    int v = (tid >= off) ? part[tid-off] : 0;
    __syncthreads();
    part[tid] += v;
    __syncthreads();
  }
  int excl = (tid>0) ? part[tid-1] : 0;
  for (int i=beg;i<end;++i){ row_ptr[i]=excl; cursor[i]=excl; excl += counts[i]; }
  if (tid == 1023) row_ptr[N] = part[1023];
}

__global__ void k_scatter(const int* __restrict__ src, const int* __restrict__ dst,
                          int* __restrict__ cursor, int* __restrict__ col_src, int Eraw, int N){
  int e = blockIdx.x*blockDim.x + threadIdx.x;
  if (e < Eraw + N){
    int s, d;
    if (e < Eraw){ s = src[e]; d = dst[e]; } else { s = e - Eraw; d = s; }
    int pos = atomicAdd(&cursor[d], 1);
    col_src[pos] = s;
  }
}

// ---------------- 128x128 tiled fp32 GEMM (W1 only) ----------------
__global__ __launch_bounds__(256) void k_gemm128(const float* __restrict__ A, const float* __restrict__ Bm,
                       float* __restrict__ C, const float* __restrict__ bias,
                       int M, int Nn, int K, int lda, int ldb, int ldc, int act, int accum){
  __shared__ __align__(16) float As[16][132];
  __shared__ __align__(16) float Bs[16][132];
  int tid = threadIdx.x;
  int tx = tid & 15, ty = tid >> 4;
  int row0 = blockIdx.y*128, col0 = blockIdx.x*128;
  float acc[8][8] = {};
  for (int kk=0; kk<K; kk+=16){
    for (int l = tid; l < 128*16; l += 256){
      int m = l >> 4, k = l & 15;
      int gr = row0 + m, gk = kk + k;
      As[k][m] = (gr < M && gk < K) ? A[(size_t)gr*lda + gk] : 0.f;
    }
    for (int l = tid; l < 16*128; l += 256){
      int k = l >> 7, n = l & 127;
      int gk = kk + k, gc = col0 + n;
      Bs[k][n] = (gk < K && gc < Nn) ? Bm[(size_t)gk*ldb + gc] : 0.f;
    }
    __syncthreads();
    #pragma unroll
    for (int k=0;k<16;++k){
      float4 a0 = *reinterpret_cast<const float4*>(&As[k][ty*4]);
      float4 a1 = *reinterpret_cast<const float4*>(&As[k][64+ty*4]);
      float4 b0 = *reinterpret_cast<const float4*>(&Bs[k][tx*4]);
      float4 b1 = *reinterpret_cast<const float4*>(&Bs[k][64+tx*4]);
      float av[8] = {a0.x,a0.y,a0.z,a0.w,a1.x,a1.y,a1.z,a1.w};
      float bv[8] = {b0.x,b0.y,b0.z,b0.w,b1.x,b1.y,b1.z,b1.w};
      #pragma unroll
      for (int i=0;i<8;++i)
        #pragma unroll
        for (int j=0;j<8;++j)
          acc[i][j] += av[i]*bv[j];
    }
    __syncthreads();
  }
  #pragma unroll
  for (int i=0;i<8;++i){
    int r = row0 + ((i<4) ? ty*4+i : 64+ty*4+(i-4));
    if (r >= M) continue;
    #pragma unroll
    for (int j=0;j<8;++j){
      int c = col0 + ((j<4) ? tx*4+j : 64+tx*4+(j-4));
      if (c >= Nn) continue;
      float v = acc[i][j];
      if (accum) v += C[(size_t)r*ldc + c];
      if (bias) v += bias[c];
      if (act == 1) v = fmaxf(v, 0.f);
      C[(size_t)r*ldc + c] = v;
    }
  }
}

// ---------------- 64x64 tiled fp32 GEMM (hsd2 only) ----------------
__global__ __launch_bounds__(256) void k_gemm(const float* __restrict__ A, const float* __restrict__ Bm,
                       float* __restrict__ C, const float* __restrict__ bias,
                       int M, int Nn, int K, int lda, int ldb, int ldc, int act){
  __shared__ __align__(16) float As[16][68];
  __shared__ __align__(16) float Bs[16][68];
  int tid = threadIdx.x;
  int tx = tid & 15, ty = tid >> 4;
  int row0 = blockIdx.y*64, col0 = blockIdx.x*64;
  float acc[4][4] = {};
  for (int kk=0; kk<K; kk+=16){
    for (int l = tid; l < 64*16; l += 256){
      int m = l >> 4, k = l & 15;
      int gr = row0 + m, gk = kk + k;
      As[k][m] = (gr < M && gk < K) ? A[(size_t)gr*lda + gk] : 0.f;
    }
    for (int l = tid; l < 16*64; l += 256){
      int k = l >> 6, n = l & 63;
      int gk = kk + k, gc = col0 + n;
      Bs[k][n] = (gk < K && gc < Nn) ? Bm[(size_t)gk*ldb + gc] : 0.f;
    }
    __syncthreads();
    #pragma unroll
    for (int k=0;k<16;++k){
      float4 a = *reinterpret_cast<const float4*>(&As[k][ty*4]);
      float4 b = *reinterpret_cast<const float4*>(&Bs[k][tx*4]);
      float av[4] = {a.x,a.y,a.z,a.w};
      float bv[4] = {b.x,b.y,b.z,b.w};
      #pragma unroll
      for (int i=0;i<4;++i)
        #pragma unroll
        for (int j=0;j<4;++j)
          acc[i][j] += av[i]*bv[j];
    }
    __syncthreads();
  }
  #pragma unroll
  for (int i=0;i<4;++i){
    int r = row0 + ty*4 + i;
    if (r >= M) continue;
    #pragma unroll
    for (int j=0;j<4;++j){
      int c = col0 + tx*4 + j;
      if (c >= Nn) continue;
      float v = acc[i][j];
      if (bias) v += bias[c];
      if (act == 1) v = fmaxf(v, 0.f);
      C[(size_t)r*ldc + c] = v;
    }
  }
}

// ---------------- MFMA bf16 NT GEMM with global_load_lds staging ----------------
// C[M,N] (+)= A[M,K] @ BT[N,K]^T. A,BT bf16 (as short), K%32==0, lda/ldb rows 16B-aligned.
// 128x128 tile, 4 waves of 64x64. Linear LDS [128][32] shorts (m97 structure).
__global__ __launch_bounds__(256) void k_mfma_nt(const short* __restrict__ A, const short* __restrict__ BT,
                        float* __restrict__ C, int M, int N, int K,
                        int lda, int ldb, int ldc, int accum){
  __shared__ __align__(16) short As[128*32];
  __shared__ __align__(16) short Bs[128*32];
  int tid = threadIdx.x;
  int lane = tid & 63, wave = tid >> 6;
  int wr = (wave >> 1) * 64, wc = (wave & 1) * 64;
  int row0 = blockIdx.y*128, col0 = blockIdx.x*128;

  // staging addresses: wave covers 32 rows via 2 issues of 16 rows (64 lanes x 16B = 16 rows x 64B)
  int rA0 = min(row0 + wave*32 + (lane>>2), M-1);
  int rA1 = min(row0 + wave*32 + 16 + (lane>>2), M-1);
  int rB0 = min(col0 + wave*32 + (lane>>2), N-1);
  int rB1 = min(col0 + wave*32 + 16 + (lane>>2), N-1);
  int kp = (lane & 3) * 8;
  const short* pa0 = A  + (size_t)rA0*lda + kp;
  const short* pa1 = A  + (size_t)rA1*lda + kp;
  const short* pb0 = BT + (size_t)rB0*ldb + kp;
  const short* pb1 = BT + (size_t)rB1*ldb + kp;
  short* la0 = As + (wave*32 + 0)*32;
  short* la1 = As + (wave*32 + 16)*32;
  short* lb0 = Bs + (wave*32 + 0)*32;
  short* lb1 = Bs + (wave*32 + 16)*32;

  f32x4 acc[4][4];
  #pragma unroll
  for (int i=0;i<4;++i)
    #pragma unroll
    for (int j=0;j<4;++j) acc[i][j] = (f32x4){0.f,0.f,0.f,0.f};

  for (int k0=0; k0<K; k0+=32){
    __builtin_amdgcn_global_load_lds((const __attribute__((address_space(1))) unsigned int*)pa0,
                                     (__attribute__((address_space(3))) unsigned int*)la0, 16, 0, 0);
    __builtin_amdgcn_global_load_lds((const __attribute__((address_space(1))) unsigned int*)pa1,
                                     (__attribute__((address_space(3))) unsigned int*)la1, 16, 0, 0);
    __builtin_amdgcn_global_load_lds((const __attribute__((address_space(1))) unsigned int*)pb0,
                                     (__attribute__((address_space(3))) unsigned int*)lb0, 16, 0, 0);
    __builtin_amdgcn_global_load_lds((const __attribute__((address_space(1))) unsigned int*)pb1,
                                     (__attribute__((address_space(3))) unsigned int*)lb1, 16, 0, 0);
    pa0 += 32; pa1 += 32; pb0 += 32; pb1 += 32;
    __syncthreads();
    bf16x8 af[4], bf[4];
    #pragma unroll
    for (int rb=0;rb<4;++rb)
      af[rb] = *reinterpret_cast<const bf16x8*>(&As[(wr + rb*16 + (lane&15))*32 + (lane>>4)*8]);
    #pragma unroll
    for (int cb=0;cb<4;++cb)
      bf[cb] = *reinterpret_cast<const bf16x8*>(&Bs[(wc + cb*16 + (lane&15))*32 + (lane>>4)*8]);
    #pragma unroll
    for (int rb=0;rb<4;++rb)
      #pragma unroll
      for (int cb=0;cb<4;++cb)
        acc[rb][cb] = __builtin_amdgcn_mfma_f32_16x16x32_bf16(af[rb], bf[cb], acc[rb][cb], 0, 0, 0);
    __syncthreads();
  }
  // C/D layout: col = lane&15, row = (lane>>4)*4 + j
  #pragma unroll
  for (int rb=0;rb<4;++rb){
    #pragma unroll
    for (int cb=0;cb<4;++cb){
      int c = col0 + wc + cb*16 + (lane & 15);
      if (c >= N) continue;
      #pragma unroll
      for (int j=0;j<4;++j){
        int r = row0 + wr + rb*16 + (lane>>4)*4 + j;
        if (r >= M) continue;
        float v = acc[rb][cb][j];
        if (accum) v += C[(size_t)r*ldc + c];
        C[(size_t)r*ldc + c] = v;
      }
    }
  }
}

// ---------------- W2 repack: W2rT[c][h*800+k] = bf16(W2[k][h*780+c]), zero pad k>=780 ----------------
__global__ void k_w2t(const float* __restrict__ W2, short* __restrict__ W2rT){
  __shared__ float s[32][33];
  int k0 = blockIdx.x*32, c0 = blockIdx.y*32, h = blockIdx.z;
  int tx = threadIdx.x, ty = threadIdx.y;
  #pragma unroll
  for (int i=0;i<32;i+=8){
    int k = k0+ty+i, c = c0+tx;
    s[ty+i][tx] = (k < 780 && c < 780) ? W2[(size_t)k*7800 + h*780 + c] : 0.f;
  }
  __syncthreads();
  #pragma unroll
  for (int i=0;i<32;i+=8){
    int c = c0+ty+i, k = k0+tx;
    if (c < 780 && k < 800)
      W2rT[(size_t)c*8000 + h*800 + k] = (short)f2bf(s[tx][ty+i]);
  }
}

// ---------------- GAT layer 1 ----------------
__global__ void k_scores1(const float* __restrict__ h1, const float* __restrict__ a1s,
                          const float* __restrict__ a1d, float* __restrict__ hs, float* __restrict__ hd){
  __shared__ float ss[HEADS], sd[HEADS];
  int n = blockIdx.x, tid = threadIdx.x;
  if (tid < HEADS){ ss[tid]=0.f; sd[tid]=0.f; }
  __syncthreads();
  const float* hr = h1 + (size_t)n*D1;
  for (int c = tid; c < D1; c += blockDim.x){
    float v = hr[c];
    int h = c / F1;
    atomicAdd(&ss[h], v*a1s[c]);
    atomicAdd(&sd[h], v*a1d[c]);
  }
  __syncthreads();
  if (tid < HEADS){ hs[n*HEADS+tid]=ss[tid]; hd[n*HEADS+tid]=sd[tid]; }
}

#define CH1 32
__global__ __launch_bounds__(256) void k_agg1(const float* __restrict__ h1, const float* __restrict__ hs,
                       const float* __restrict__ hd, const int* __restrict__ row_ptr,
                       const int* __restrict__ col_src, const float* __restrict__ b1,
                       float* __restrict__ g1o){
  __shared__ float m_l[HEADS], s_l[HEADS];
  __shared__ float al[CH1][HEADS];
  __shared__ int src_l[CH1];
  int n = blockIdx.x, tid = threadIdx.x;
  int beg = row_ptr[n], end = row_ptr[n+1];
  if (tid < HEADS){
    float hdv = hd[n*HEADS + tid];
    float m = -1e30f;
    for (int j=beg;j<end;++j){
      float sc = lrelu(hs[col_src[j]*HEADS + tid] + hdv);
      m = fmaxf(m, sc);
    }
    float s = 0.f;
    for (int j=beg;j<end;++j){
      float sc = lrelu(hs[col_src[j]*HEADS + tid] + hdv);
      s += expf(sc - m);
    }
    m_l[tid]=m; s_l[tid]=s;
  }
  __syncthreads();
  float acc[4] = {0.f,0.f,0.f,0.f};
  for (int j0=beg; j0<end; j0+=CH1){
    int cn = min(CH1, end-j0);
    for (int p=tid; p<cn*HEADS; p+=256){
      int j = p/HEADS, h = p - j*HEADS;
      int sidx = col_src[j0+j];
      if (h==0) src_l[j] = sidx;
      float sc = lrelu(hs[sidx*HEADS+h] + hd[n*HEADS+h]);
      al[j][h] = expf(sc - m_l[h]) / s_l[h];
    }
    __syncthreads();
    for (int j=0;j<cn;++j){
      const float* hr = h1 + (size_t)src_l[j]*D1;
      #pragma unroll
      for (int r=0;r<4;++r){
        int c = tid + r*256;
        if (c < D1) acc[r] += al[j][c/F1] * hr[c];
      }
    }
    __syncthreads();
  }
  #pragma unroll
  for (int r=0;r<4;++r){
    int c = tid + r*256;
    if (c < D1){
      float v = acc[r] + b1[c];
      g1o[(size_t)n*D1 + c] = v > 0.f ? v : expm1f(v);
    }
  }
}

// ---------------- layer-2 score projections ----------------
__global__ void k_makews2(const float* __restrict__ W2, const float* __restrict__ a2s,
                          const float* __restrict__ a2d, float* __restrict__ Wsd){
  __shared__ float out[20];
  int c = blockIdx.x, tid = threadIdx.x;
  if (tid < 20) out[tid] = 0.f;
  __syncthreads();
  const float* row = W2 + (size_t)c*7800;
  for (int j = tid; j < 7800; j += 256){
    float v = row[j];
    int h = j / D1;
    atomicAdd(&out[h],    v * a2s[j]);
    atomicAdd(&out[10+h], v * a2d[j]);
  }
  __syncthreads();
  if (tid < 20) Wsd[c*20 + tid] = out[tid];
}

// ---------------- fused all-head aggregation -> aggG10 bf16 [N][10*800] ----------------
__global__ __launch_bounds__(256) void k_aggAll(const float* __restrict__ g1, const float* __restrict__ hsd,
                       const int* __restrict__ row_ptr, const int* __restrict__ col_src,
                       short* __restrict__ aggG10){
  __shared__ float m_l[HEADS], s_l[HEADS];
  __shared__ float al[16][HEADS];
  __shared__ int src_l[16];
  int n = blockIdx.x, tid = threadIdx.x;
  int beg = row_ptr[n], end = row_ptr[n+1];
  if (tid < HEADS){
    float hdv = hsd[n*20 + 10 + tid];
    float m = -1e30f;
    for (int j=beg;j<end;++j) m = fmaxf(m, lrelu(hsd[col_src[j]*20 + tid] + hdv));
    float s = 0.f;
    for (int j=beg;j<end;++j) s += expf(lrelu(hsd[col_src[j]*20 + tid] + hdv) - m);
    m_l[tid]=m; s_l[tid]=s;
  }
  __syncthreads();
  float acc[4][HEADS] = {};
  for (int j0=beg; j0<end; j0+=16){
    int cn = min(16, end-j0);
    for (int p=tid; p<cn*HEADS; p+=256){
      int j = p/HEADS, h = p - j*HEADS;
      int sidx = col_src[j0+j];
      if (h==0) src_l[j] = sidx;
      float hdv = hsd[n*20 + 10 + h];
      al[j][h] = 0.1f * expf(lrelu(hsd[sidx*20 + h] + hdv) - m_l[h]) / s_l[h];
    }
    __syncthreads();
    for (int j=0;j<cn;++j){
      const float* gr = g1 + (size_t)src_l[j]*D1;
      #pragma unroll
      for (int r=0;r<4;++r){
        int c = tid + r*256;
        if (c < D1){
          float v = gr[c];
          #pragma unroll
          for (int h=0;h<HEADS;++h) acc[r][h] += al[j][h]*v;
        }
      }
    }
    __syncthreads();
  }
  short* og = aggG10 + (size_t)n*8000;
  #pragma unroll
  for (int r=0;r<4;++r){
    int c = tid + r*256;
    if (c < D1){
      #pragma unroll
      for (int h=0;h<HEADS;++h) og[h*800 + c] = (short)f2bf(acc[r][h]);
    }
  }
  if (tid < 200){ int h = tid/20, c2 = 780 + tid%20; og[h*800 + c2] = 0; }
}

// ---------------- per-head aggregation fallback -> aggG bf16 [N][800] ----------------
__global__ __launch_bounds__(256) void k_aggH(const float* __restrict__ g1, const float* __restrict__ hsd,
                       const int* __restrict__ row_ptr, const int* __restrict__ col_src,
                       short* __restrict__ aggG, int h, int N){
  int n = blockIdx.x*4 + (threadIdx.x >> 6);
  if (n >= N) return;
  int lane = threadIdx.x & 63;
  int beg = row_ptr[n], end = row_ptr[n+1];
  float hdv = hsd[n*20 + 10 + h];
  float m = -1e30f;
  for (int j=beg;j<end;++j) m = fmaxf(m, lrelu(hsd[col_src[j]*20 + h] + hdv));
  float denom = 0.f;
  for (int j=beg;j<end;++j) denom += expf(lrelu(hsd[col_src[j]*20 + h] + hdv) - m);
  float acc[13] = {};
  for (int j=beg;j<end;++j){
    int s = col_src[j];
    float a = 0.1f * expf(lrelu(hsd[s*20 + h] + hdv) - m) / denom;
    const float* gr = g1 + (size_t)s*D1;
    #pragma unroll
    for (int r=0;r<12;++r) acc[r] += a * gr[lane + r*64];
    if (lane < 12) acc[12] += a * gr[768 + lane];
  }
  short* og = aggG + (size_t)n*800;
  #pragma unroll
  for (int r=0;r<12;++r) og[lane + r*64] = (short)f2bf(acc[r]);
  int c = 768 + lane;
  if (c < 800) og[c] = (c < D1) ? (short)f2bf(acc[12]) : (short)0;
}

// ---------------- pooling (col-split) ----------------
__device__ __forceinline__ int lowb(const int* a, int n, int v){
  int lo=0, hi=n;
  while (lo<hi){ int mid=(lo+hi)>>1; if (a[mid]<v) lo=mid+1; else hi=mid; }
  return lo;
}

__global__ void k_pool(const float* __restrict__ out2, const float* __restrict__ b2,
                       const int* __restrict__ batch, int N, float* __restrict__ gfeat){
  int b = blockIdx.x;
  int c = blockIdx.y*256 + threadIdx.x;
  if (c >= D1) return;
  int lo = lowb(batch, N, b), hi = lowb(batch, N, b+1);
  float bb = b2[c];
  float mx = -INFINITY, sm = 0.f;
  for (int n2=lo;n2<hi;++n2){
    float v = fmaxf(out2[(size_t)n2*D1 + c] + bb, 0.f);
    mx = fmaxf(mx, v);
    sm += v;
  }
  int cnt = hi-lo;
  gfeat[(size_t)b*1560 + c] = mx;
  gfeat[(size_t)b*1560 + 780 + c] = sm / fmaxf((float)cnt, 1.f);
}

// ---------------- protein conv: rank-26 factorization ----------------
// WcF[i][r] = Wc[o][i][k], r=o*8+k   (coalesced per-i rows)
__global__ void k_wcf(const float* __restrict__ Wc, float* __restrict__ WcF){
  int id = blockIdx.x*256 + threadIdx.x;
  if (id < 256000){
    int i = id >> 8, r = id & 255;
    WcF[id] = Wc[(size_t)(r>>3)*8000 + i*8 + (r&7)];
  }
}

// per-b: Q[r][v] = sum_i WcF[i][r]*[tg[i]==v]; convc[o][t] = sum_v sum_k Q[o*8+k][v]*emb[v][t+k] + bc[o]
__global__ __launch_bounds__(256) void k_prot(const int* __restrict__ target, const float* __restrict__ WcF,
                       const float* __restrict__ emb, const float* __restrict__ bc,
                       float* __restrict__ convc){
  __shared__ float Q[256*27];       // pad 27: bank-conflict-free RMW
  __shared__ float emb_l[26*128];
  __shared__ int tg_l[1000];
  int b = blockIdx.x, tid = threadIdx.x;
  for (int i=tid;i<26*128;i+=256) emb_l[i]=emb[i];
  for (int i=tid;i<1000;i+=256) tg_l[i]=target[b*1000+i];
  for (int i=tid;i<256*27;i+=256) Q[i]=0.f;
  __syncthreads();
  float* q = Q + tid*27;
  for (int i=0;i<1000;++i){
    float w = WcF[i*256 + tid];
    q[tg_l[i]] += w;
  }
  __syncthreads();
  for (int p=tid; p<32*121; p+=256){
    int o = p/121, t = p%121;
    float acc = bc[o];
    const float* qb = Q + (o*8)*27;
    for (int v=0; v<26; ++v){
      const float* ev = emb_l + v*128 + t;
      #pragma unroll
      for (int k=0;k<8;++k) acc += qb[k*27 + v] * ev[k];
    }
    convc[(size_t)b*3872 + p] = acc;
  }
}

// ---------------- split-K skinny GEMM (M<=64): atomicAdd partials into zeroed C ----------------
__global__ __launch_bounds__(256) void k_skinny(const float* __restrict__ A, const float* __restrict__ B,
                        float* __restrict__ C, int M, int N, int K, int ldb, int ldc, int kc){
  int col0 = blockIdx.x*64;
  int k0 = blockIdx.y*kc, k1 = min(K, k0+kc);
  int tx = threadIdx.x & 63, ty = threadIdx.x >> 6;
  int col = col0 + tx;
  if (col >= N) return;
  float acc[16] = {};
  for (int k=k0; k<k1; ++k){
    float b = B[(size_t)k*ldb + col];
    const float* Ak = A + (size_t)(ty*16)*K + k;
    #pragma unroll
    for (int i=0;i<16;++i) acc[i] += Ak[(size_t)i*K] * b;
  }
  #pragma unroll
  for (int i=0;i<16;++i){
    int r = ty*16 + i;
    if (r < M) atomicAdd(&C[(size_t)r*ldc + col], acc[i]);
  }
}

__global__ void k_biasact(float* __restrict__ C, const float* __restrict__ bias,
                          int M, int N, int ldc, int act){
  int id = blockIdx.x*256 + threadIdx.x;
  if (id >= M*N) return;
  int r = id / N, c = id % N;
  float v = C[(size_t)r*ldc + c] + bias[c];
  if (act == 1) v = fmaxf(v, 0.f);
  C[(size_t)r*ldc + c] = v;
}

// ---------------- final Wo dot ----------------
__global__ void k_wo(const float* __restrict__ f2, const float* __restrict__ Wo,
                     const float* __restrict__ bo, float* __restrict__ out, int M){
  __shared__ float red[256];
  int tid = threadIdx.x;
  int r = tid & 63, kg = tid >> 6;
  float p = 0.f;
  for (int k = kg*128; k < kg*128 + 128; ++k) p += f2[(size_t)r*512 + k] * Wo[k];
  red[tid] = p;
  __syncthreads();
  if (tid < 64 && tid < M) out[tid] = red[tid] + red[tid+64] + red[tid+128] + red[tid+192] + bo[0];
}

// ---------------- launch ----------------
extern "C" void kernel_launch(void* const* d_in, const int* in_sizes, int n_in,
                              void* d_out, int out_size, void* d_ws, size_t ws_size,
                              hipStream_t stream){
  const float* x   = (const float*)d_in[0];
  const int*   ei    = (const int*)d_in[1];
  const int*   batch = (const int*)d_in[2];
  const int*   target= (const int*)d_in[3];
  const float* W1  = (const float*)d_in[4];
  const float* a1s = (const float*)d_in[5];
  const float* a1d = (const float*)d_in[6];
  const float* b1  = (const float*)d_in[7];
  const float* W2  = (const float*)d_in[8];
  const float* a2s = (const float*)d_in[9];
  const float* a2d = (const float*)d_in[10];
  const float* b2  = (const float*)d_in[11];
  const float* Wg1 = (const float*)d_in[12];
  const float* bg1 = (const float*)d_in[13];
  const float* Wg2 = (const float*)d_in[14];
  const float* bg2 = (const float*)d_in[15];
  const float* emb = (const float*)d_in[16];
  const float* Wc  = (const float*)d_in[17];
  const float* bc  = (const float*)d_in[18];
  const float* Wxt = (const float*)d_in[19];
  const float* bxt = (const float*)d_in[20];
  const float* Wf1 = (const float*)d_in[21];
  const float* bf1 = (const float*)d_in[22];
  const float* Wf2 = (const float*)d_in[23];
  const float* bf2 = (const float*)d_in[24];
  const float* Wo  = (const float*)d_in[25];
  const float* bo  = (const float*)d_in[26];

  int N = in_sizes[0] / 78;
  int Eraw = in_sizes[1] / 2;
  int Bb = in_sizes[3] / 1000;
  int Etot = Eraw + N;

  char* wsp = (char*)d_ws;
  size_t off = 0;
  auto alloc = [&](size_t bytes)->void*{ void* p = wsp + off; off += (bytes + 255) & ~(size_t)255; return p; };
  float* buf1   = (float*)alloc((size_t)N*D1*4);   // h1
  float* buf2   = (float*)alloc((size_t)N*D1*4);   // g1
  float* buf3   = (float*)alloc((size_t)N*D1*4);   // out2
  float* hs1    = (float*)alloc((size_t)N*HEADS*4);
  float* hd1    = (float*)alloc((size_t)N*HEADS*4);
  float* hsd2   = (float*)alloc((size_t)N*20*4);
  float* Wsd    = (float*)alloc((size_t)D1*20*4);
  int*   counts = (int*)alloc((size_t)N*4);
  int*   row_ptr= (int*)alloc((size_t)(N+1)*4);
  int*   cursor = (int*)alloc((size_t)N*4);
  int*   col_src= (int*)alloc((size_t)Etot*4);
  float* WcF    = (float*)alloc((size_t)1000*256*4);
  float* convc  = (float*)alloc((size_t)Bb*3872*4);
  float* gfeat  = (float*)alloc((size_t)Bb*1560*4);
  float* fcg1   = (float*)alloc((size_t)Bb*1500*4);
  float* xc     = (float*)alloc((size_t)Bb*256*4);
  float* f1     = (float*)alloc((size_t)Bb*1024*4);
  float* f2     = (float*)alloc((size_t)Bb*512*4);
  short* W2rT   = (short*)alloc((size_t)D1*8000*2);  // [c][h*800+k] bf16
  size_t fused_bytes = (size_t)N*8000*2;
  int fused = (ws_size > off + fused_bytes + (1u<<20)) ? 1 : 0;
  short* aggB = (short*)alloc(fused ? fused_bytes : (size_t)N*800*2);
  (void)n_in; (void)out_size;

  // ---- CSR by dst (self-loops appended) ----
  hipMemsetAsync(counts, 0, (size_t)N*4, stream);
  int thr=256, blk=(Etot+thr-1)/thr;
  k_count<<<blk,thr,0,stream>>>(ei+Eraw, counts, Eraw, N);
  k_scan<<<1,1024,0,stream>>>(counts, row_ptr, cursor, N);
  k_scatter<<<blk,thr,0,stream>>>(ei, ei+Eraw, cursor, col_src, Eraw, N);

  // ---- zero atomic-target buffers ----
  hipMemsetAsync(fcg1, 0, (size_t)Bb*1500*4, stream);
  hipMemsetAsync(xc,   0, (size_t)Bb*256*4,  stream);
  hipMemsetAsync(f1,   0, (size_t)Bb*1024*4, stream);
  hipMemsetAsync(f2,   0, (size_t)Bb*512*4,  stream);

  // ---- protein branch: rank-26 factorization ----
  k_wcf<<<(256000+255)/256,256,0,stream>>>(Wc, WcF);
  k_prot<<<Bb,256,0,stream>>>(target, WcF, emb, bc, convc);
  { dim3 g((128+63)/64, (3872+127)/128);
    k_skinny<<<g,256,0,stream>>>(convc, Wxt, xc+128, Bb, 128, 3872, 128, 256, 128);
    k_biasact<<<(Bb*128+255)/256,256,0,stream>>>(xc+128, bxt, Bb, 128, 256, 0); }

  // ---- GAT layer 1 ----
  dim3 gW1((D1+127)/128, (N+127)/128);
  k_gemm128<<<gW1,256,0,stream>>>(x, W1, buf1, nullptr, N, D1, 78, 78, D1, D1, 0, 0);
  k_scores1<<<N,256,0,stream>>>(buf1, a1s, a1d, hs1, hd1);
  k_agg1<<<N,256,0,stream>>>(buf1, hs1, hd1, row_ptr, col_src, b1, buf2);

  // ---- GAT layer 2 ----
  k_makews2<<<D1,256,0,stream>>>(W2, a2s, a2d, Wsd);
  dim3 gHS(1, (N+63)/64);
  k_gemm<<<gHS,256,0,stream>>>(buf2, Wsd, hsd2, nullptr, N, 20, D1, D1, 20, 20, 0);
  { dim3 g(25, 25, 10); dim3 b(32, 8);
    k_w2t<<<g,b,0,stream>>>(W2, W2rT); }

  float* out2 = buf3;
  dim3 gMM((D1+127)/128, (N+127)/128);
  if (fused){
    k_aggAll<<<N,256,0,stream>>>(buf2, hsd2, row_ptr, col_src, aggB);
    k_mfma_nt<<<gMM,256,0,stream>>>(aggB, W2rT, out2, N, D1, 8000, 8000, 8000, D1, 0);
  } else {
    for (int h=0; h<HEADS; ++h){
      k_aggH<<<(N+3)/4,256,0,stream>>>(buf2, hsd2, row_ptr, col_src, aggB, h, N);
      k_mfma_nt<<<gMM,256,0,stream>>>(aggB, W2rT + h*800, out2, N, D1, 800, 800, 8000, D1, h==0?0:1);
    }
  }

  // ---- pooling (bias+relu fused, col-split) ----
  { dim3 gp(Bb, 4);
    k_pool<<<gp,256,0,stream>>>(out2, b2, batch, N, gfeat); }

  // ---- graph FCs (split-K skinny) ----
  { dim3 g((1500+63)/64, (1560+127)/128);
    k_skinny<<<g,256,0,stream>>>(gfeat, Wg1, fcg1, Bb, 1500, 1560, 1500, 1500, 128);
    k_biasact<<<(Bb*1500+255)/256,256,0,stream>>>(fcg1, bg1, Bb, 1500, 1500, 1); }
  { dim3 g((128+63)/64, (1500+127)/128);
    k_skinny<<<g,256,0,stream>>>(fcg1, Wg2, xc, Bb, 128, 1500, 128, 256, 128);
    k_biasact<<<(Bb*128+255)/256,256,0,stream>>>(xc, bg2, Bb, 128, 256, 1); }

  // ---- fusion MLP ----
  { dim3 g((1024+63)/64, (256+127)/128);
    k_skinny<<<g,256,0,stream>>>(xc, Wf1, f1, Bb, 1024, 256, 1024, 1024, 128);
    k_biasact<<<(Bb*1024+255)/256,256,0,stream>>>(f1, bf1, Bb, 1024, 1024, 1); }
  { dim3 g((512+63)/64, (1024+127)/128);
    k_skinny<<<g,256,0,stream>>>(f1, Wf2, f2, Bb, 512, 1024, 512, 512, 128);
    k_biasact<<<(Bb*512+255)/256,256,0,stream>>>(f2, bf2, Bb, 512, 512, 1); }
  k_wo<<<1,256,0,stream>>>(f2, Wo, bo, (float*)d_out, Bb);
}

// Round 6
// 1435.557 us; speedup vs baseline: 4.6527x; 1.3967x over previous
//
#include <hip/hip_runtime.h>
#include <math.h>

#define HEADS 10
#define D1 780
#define F1 78

typedef __attribute__((ext_vector_type(8))) short bf16x8;
typedef __attribute__((ext_vector_type(4))) float f32x4;

static __device__ __forceinline__ float lrelu(float x){ return x > 0.f ? x : 0.2f*x; }

static __device__ __forceinline__ unsigned short f2bf(float f){
  unsigned int u = __float_as_uint(f);
  u += 0x7fffu + ((u >> 16) & 1u);   // RNE
  return (unsigned short)(u >> 16);
}

// ---------------- CSR build ----------------
__global__ void k_count(const int* __restrict__ dst, int* __restrict__ counts, int Eraw, int N){
  int e = blockIdx.x*blockDim.x + threadIdx.x;
  if (e < Eraw + N){
    int d = (e < Eraw) ? dst[e] : (e - Eraw);
    atomicAdd(&counts[d], 1);
  }
}

__global__ void k_scan(const int* __restrict__ counts, int* __restrict__ row_ptr,
                       int* __restrict__ cursor, int N){
  __shared__ int part[1024];
  int tid = threadIdx.x;
  int chunk = (N + 1023)/1024;
  int beg = tid*chunk, end = min(beg+chunk, N);
  int s = 0;
  for (int i=beg;i<end;++i) s += counts[i];
  part[tid] = s;
  __syncthreads();
  for (int off=1; off<1024; off<<=1){
    int v = (tid >= off) ? part[tid-off] : 0;
    __syncthreads();
    part[tid] += v;
    __syncthreads();
  }
  int excl = (tid>0) ? part[tid-1] : 0;
  for (int i=beg;i<end;++i){ row_ptr[i]=excl; cursor[i]=excl; excl += counts[i]; }
  if (tid == 1023) row_ptr[N] = part[1023];
}

__global__ void k_scatter(const int* __restrict__ src, const int* __restrict__ dst,
                          int* __restrict__ cursor, int* __restrict__ col_src, int Eraw, int N){
  int e = blockIdx.x*blockDim.x + threadIdx.x;
  if (e < Eraw + N){
    int s, d;
    if (e < Eraw){ s = src[e]; d = dst[e]; } else { s = e - Eraw; d = s; }
    int pos = atomicAdd(&cursor[d], 1);
    col_src[pos] = s;
  }
}

// ---------------- 128x128 tiled fp32 GEMM (W1 only) ----------------
__global__ __launch_bounds__(256) void k_gemm128(const float* __restrict__ A, const float* __restrict__ Bm,
                       float* __restrict__ C, const float* __restrict__ bias,
                       int M, int Nn, int K, int lda, int ldb, int ldc, int act, int accum){
  __shared__ __align__(16) float As[16][132];
  __shared__ __align__(16) float Bs[16][132];
  int tid = threadIdx.x;
  int tx = tid & 15, ty = tid >> 4;
  int row0 = blockIdx.y*128, col0 = blockIdx.x*128;
  float acc[8][8] = {};
  for (int kk=0; kk<K; kk+=16){
    for (int l = tid; l < 128*16; l += 256){
      int m = l >> 4, k = l & 15;
      int gr = row0 + m, gk = kk + k;
      As[k][m] = (gr < M && gk < K) ? A[(size_t)gr*lda + gk] : 0.f;
    }
    for (int l = tid; l < 16*128; l += 256){
      int k = l >> 7, n = l & 127;
      int gk = kk + k, gc = col0 + n;
      Bs[k][n] = (gk < K && gc < Nn) ? Bm[(size_t)gk*ldb + gc] : 0.f;
    }
    __syncthreads();
    #pragma unroll
    for (int k=0;k<16;++k){
      float4 a0 = *reinterpret_cast<const float4*>(&As[k][ty*4]);
      float4 a1 = *reinterpret_cast<const float4*>(&As[k][64+ty*4]);
      float4 b0 = *reinterpret_cast<const float4*>(&Bs[k][tx*4]);
      float4 b1 = *reinterpret_cast<const float4*>(&Bs[k][64+tx*4]);
      float av[8] = {a0.x,a0.y,a0.z,a0.w,a1.x,a1.y,a1.z,a1.w};
      float bv[8] = {b0.x,b0.y,b0.z,b0.w,b1.x,b1.y,b1.z,b1.w};
      #pragma unroll
      for (int i=0;i<8;++i)
        #pragma unroll
        for (int j=0;j<8;++j)
          acc[i][j] += av[i]*bv[j];
    }
    __syncthreads();
  }
  #pragma unroll
  for (int i=0;i<8;++i){
    int r = row0 + ((i<4) ? ty*4+i : 64+ty*4+(i-4));
    if (r >= M) continue;
    #pragma unroll
    for (int j=0;j<8;++j){
      int c = col0 + ((j<4) ? tx*4+j : 64+tx*4+(j-4));
      if (c >= Nn) continue;
      float v = acc[i][j];
      if (accum) v += C[(size_t)r*ldc + c];
      if (bias) v += bias[c];
      if (act == 1) v = fmaxf(v, 0.f);
      C[(size_t)r*ldc + c] = v;
    }
  }
}

// ---------------- MFMA bf16 NT GEMM with global_load_lds staging ----------------
// C[M,N] (+)= A[M,K] @ BT[N,K]^T. A,BT bf16 (as short), K%32==0, rows 16B-aligned.
__global__ __launch_bounds__(256) void k_mfma_nt(const short* __restrict__ A, const short* __restrict__ BT,
                        float* __restrict__ C, int M, int N, int K,
                        int lda, int ldb, int ldc, int accum){
  __shared__ __align__(16) short As[128*32];
  __shared__ __align__(16) short Bs[128*32];
  int tid = threadIdx.x;
  int lane = tid & 63, wave = tid >> 6;
  int wr = (wave >> 1) * 64, wc = (wave & 1) * 64;
  int row0 = blockIdx.y*128, col0 = blockIdx.x*128;

  int rA0 = min(row0 + wave*32 + (lane>>2), M-1);
  int rA1 = min(row0 + wave*32 + 16 + (lane>>2), M-1);
  int rB0 = min(col0 + wave*32 + (lane>>2), N-1);
  int rB1 = min(col0 + wave*32 + 16 + (lane>>2), N-1);
  int kp = (lane & 3) * 8;
  const short* pa0 = A  + (size_t)rA0*lda + kp;
  const short* pa1 = A  + (size_t)rA1*lda + kp;
  const short* pb0 = BT + (size_t)rB0*ldb + kp;
  const short* pb1 = BT + (size_t)rB1*ldb + kp;
  short* la0 = As + (wave*32 + 0)*32;
  short* la1 = As + (wave*32 + 16)*32;
  short* lb0 = Bs + (wave*32 + 0)*32;
  short* lb1 = Bs + (wave*32 + 16)*32;

  f32x4 acc[4][4];
  #pragma unroll
  for (int i=0;i<4;++i)
    #pragma unroll
    for (int j=0;j<4;++j) acc[i][j] = (f32x4){0.f,0.f,0.f,0.f};

  for (int k0=0; k0<K; k0+=32){
    __builtin_amdgcn_global_load_lds((const __attribute__((address_space(1))) unsigned int*)pa0,
                                     (__attribute__((address_space(3))) unsigned int*)la0, 16, 0, 0);
    __builtin_amdgcn_global_load_lds((const __attribute__((address_space(1))) unsigned int*)pa1,
                                     (__attribute__((address_space(3))) unsigned int*)la1, 16, 0, 0);
    __builtin_amdgcn_global_load_lds((const __attribute__((address_space(1))) unsigned int*)pb0,
                                     (__attribute__((address_space(3))) unsigned int*)lb0, 16, 0, 0);
    __builtin_amdgcn_global_load_lds((const __attribute__((address_space(1))) unsigned int*)pb1,
                                     (__attribute__((address_space(3))) unsigned int*)lb1, 16, 0, 0);
    pa0 += 32; pa1 += 32; pb0 += 32; pb1 += 32;
    __syncthreads();
    bf16x8 af[4], bf[4];
    #pragma unroll
    for (int rb=0;rb<4;++rb)
      af[rb] = *reinterpret_cast<const bf16x8*>(&As[(wr + rb*16 + (lane&15))*32 + (lane>>4)*8]);
    #pragma unroll
    for (int cb=0;cb<4;++cb)
      bf[cb] = *reinterpret_cast<const bf16x8*>(&Bs[(wc + cb*16 + (lane&15))*32 + (lane>>4)*8]);
    #pragma unroll
    for (int rb=0;rb<4;++rb)
      #pragma unroll
      for (int cb=0;cb<4;++cb)
        acc[rb][cb] = __builtin_amdgcn_mfma_f32_16x16x32_bf16(af[rb], bf[cb], acc[rb][cb], 0, 0, 0);
    __syncthreads();
  }
  #pragma unroll
  for (int rb=0;rb<4;++rb){
    #pragma unroll
    for (int cb=0;cb<4;++cb){
      int c = col0 + wc + cb*16 + (lane & 15);
      if (c >= N) continue;
      #pragma unroll
      for (int j=0;j<4;++j){
        int r = row0 + wr + rb*16 + (lane>>4)*4 + j;
        if (r >= M) continue;
        float v = acc[rb][cb][j];
        if (accum) v += C[(size_t)r*ldc + c];
        C[(size_t)r*ldc + c] = v;
      }
    }
  }
}

// ---------------- W2 repack: W2rT[c][h*800+k] = bf16(W2[k][h*780+c]) ----------------
__global__ void k_w2t(const float* __restrict__ W2, short* __restrict__ W2rT){
  __shared__ float s[32][33];
  int k0 = blockIdx.x*32, c0 = blockIdx.y*32, h = blockIdx.z;
  int tx = threadIdx.x, ty = threadIdx.y;
  #pragma unroll
  for (int i=0;i<32;i+=8){
    int k = k0+ty+i, c = c0+tx;
    s[ty+i][tx] = (k < 780 && c < 780) ? W2[(size_t)k*7800 + h*780 + c] : 0.f;
  }
  __syncthreads();
  #pragma unroll
  for (int i=0;i<32;i+=8){
    int c = c0+ty+i, k = k0+tx;
    if (c < 780 && k < 800)
      W2rT[(size_t)c*8000 + h*800 + k] = (short)f2bf(s[tx][ty+i]);
  }
}

// ---------------- Wsd1T build: [20][780] block-diagonal from a1s/a1d ----------------
__global__ void k_mkwsd1(const float* __restrict__ a1s, const float* __restrict__ a1d,
                         float* __restrict__ WsdT){
  int id = blockIdx.x*256 + threadIdx.x;
  if (id >= 20*780) return;
  int j = id / 780, c = id % 780;
  int h = (j < 10) ? j : j - 10;
  float v = 0.f;
  if (c / F1 == h) v = (j < 10) ? a1s[h*F1 + c%F1] : a1d[h*F1 + c%F1];
  WsdT[id] = v;
}

// ---------------- layer-2 score projections -> WsdT2[j][c], j<10: W2_h@a2s, j>=10: @a2d ----------------
__global__ void k_makews2(const float* __restrict__ W2, const float* __restrict__ a2s,
                          const float* __restrict__ a2d, float* __restrict__ WsdT){
  __shared__ float out[20];
  int c = blockIdx.x, tid = threadIdx.x;
  if (tid < 20) out[tid] = 0.f;
  __syncthreads();
  const float* row = W2 + (size_t)c*7800;
  for (int j = tid; j < 7800; j += 256){
    float v = row[j];
    int h = j / D1;
    atomicAdd(&out[h],    v * a2s[j]);
    atomicAdd(&out[10+h], v * a2d[j]);
  }
  __syncthreads();
  if (tid < 20) WsdT[(size_t)tid*780 + c] = out[tid];
}

// ---------------- tall-skinny projection: out[n][j] = sum_c A[n][c]*WT[j][c], j<20 ----------------
__global__ __launch_bounds__(256) void k_proj20(const float* __restrict__ A, const float* __restrict__ WT,
                        float* __restrict__ out, int N){
  int n = blockIdx.x*4 + (threadIdx.x >> 6);
  if (n >= N) return;
  int lane = threadIdx.x & 63;
  const float* row = A + (size_t)n*D1;
  float acc[20] = {};
  #pragma unroll
  for (int r=0;r<12;++r){
    int c = lane + r*64;
    float v = row[c];
    #pragma unroll
    for (int j=0;j<20;++j) acc[j] += v * WT[j*780 + c];
  }
  { int c = 768 + lane;
    if (c < D1){
      float v = row[c];
      #pragma unroll
      for (int j=0;j<20;++j) acc[j] += v * WT[j*780 + c];
    } }
  #pragma unroll
  for (int j=0;j<20;++j){
    #pragma unroll
    for (int off=32; off; off>>=1) acc[j] += __shfl_xor(acc[j], off);
  }
  #pragma unroll
  for (int j=0;j<20;++j) if (lane == j) out[(size_t)n*20 + j] = acc[j];
}

// ---------------- GAT layer 1 aggregation (hsd1 layout [n][20]) ----------------
#define CH1 32
__global__ __launch_bounds__(256) void k_agg1(const float* __restrict__ h1, const float* __restrict__ hsd,
                       const int* __restrict__ row_ptr, const int* __restrict__ col_src,
                       const float* __restrict__ b1, float* __restrict__ g1o){
  __shared__ float m_l[HEADS], s_l[HEADS];
  __shared__ float al[CH1][HEADS];
  __shared__ int src_l[CH1];
  int n = blockIdx.x, tid = threadIdx.x;
  int beg = row_ptr[n], end = row_ptr[n+1];
  if (tid < HEADS){
    float hdv = hsd[(size_t)n*20 + 10 + tid];
    float m = -1e30f;
    for (int j=beg;j<end;++j) m = fmaxf(m, lrelu(hsd[(size_t)col_src[j]*20 + tid] + hdv));
    float s = 0.f;
    for (int j=beg;j<end;++j) s += expf(lrelu(hsd[(size_t)col_src[j]*20 + tid] + hdv) - m);
    m_l[tid]=m; s_l[tid]=s;
  }
  __syncthreads();
  float acc[4] = {0.f,0.f,0.f,0.f};
  for (int j0=beg; j0<end; j0+=CH1){
    int cn = min(CH1, end-j0);
    for (int p=tid; p<cn*HEADS; p+=256){
      int j = p/HEADS, h = p - j*HEADS;
      int sidx = col_src[j0+j];
      if (h==0) src_l[j] = sidx;
      float sc = lrelu(hsd[(size_t)sidx*20 + h] + hsd[(size_t)n*20 + 10 + h]);
      al[j][h] = expf(sc - m_l[h]) / s_l[h];
    }
    __syncthreads();
    for (int j=0;j<cn;++j){
      const float* hr = h1 + (size_t)src_l[j]*D1;
      #pragma unroll
      for (int r=0;r<4;++r){
        int c = tid + r*256;
        if (c < D1) acc[r] += al[j][c/F1] * hr[c];
      }
    }
    __syncthreads();
  }
  #pragma unroll
  for (int r=0;r<4;++r){
    int c = tid + r*256;
    if (c < D1){
      float v = acc[r] + b1[c];
      g1o[(size_t)n*D1 + c] = v > 0.f ? v : expm1f(v);
    }
  }
}

// ---------------- layer-2 aggregation for head group [h0,h0+G) -> aggB bf16 [N][G*800] ----------------
template<int G>
__global__ __launch_bounds__(256) void k_aggG(const float* __restrict__ g1, const float* __restrict__ hsd,
                       const int* __restrict__ row_ptr, const int* __restrict__ col_src,
                       short* __restrict__ aggB, int h0){
  __shared__ float m_l[G], s_l[G];
  __shared__ float al[16][G];
  __shared__ int src_l[16];
  int n = blockIdx.x, tid = threadIdx.x;
  int beg = row_ptr[n], end = row_ptr[n+1];
  if (tid < G){
    int h = h0 + tid;
    float hdv = hsd[(size_t)n*20 + 10 + h];
    float m = -1e30f;
    for (int j=beg;j<end;++j) m = fmaxf(m, lrelu(hsd[(size_t)col_src[j]*20 + h] + hdv));
    float s = 0.f;
    for (int j=beg;j<end;++j) s += expf(lrelu(hsd[(size_t)col_src[j]*20 + h] + hdv) - m);
    m_l[tid]=m; s_l[tid]=s;
  }
  __syncthreads();
  float acc[4][G] = {};
  for (int j0=beg; j0<end; j0+=16){
    int cn = min(16, end-j0);
    for (int p=tid; p<cn*G; p+=256){
      int j = p/G, g = p - j*G;
      int h = h0 + g;
      int sidx = col_src[j0+j];
      if (g==0) src_l[j] = sidx;
      float hdv = hsd[(size_t)n*20 + 10 + h];
      al[j][g] = 0.1f * expf(lrelu(hsd[(size_t)sidx*20 + h] + hdv) - m_l[g]) / s_l[g];
    }
    if (G == 1) for (int p=tid; p<cn; p+=256) src_l[p] = col_src[j0+p];
    __syncthreads();
    for (int j=0;j<cn;++j){
      const float* gr = g1 + (size_t)src_l[j]*D1;
      #pragma unroll
      for (int r=0;r<4;++r){
        int c = tid + r*256;
        if (c < D1){
          float v = gr[c];
          #pragma unroll
          for (int g=0;g<G;++g) acc[r][g] += al[j][g]*v;
        }
      }
    }
    __syncthreads();
  }
  short* og = aggB + (size_t)n*G*800;
  #pragma unroll
  for (int r=0;r<4;++r){
    int c = tid + r*256;
    if (c < D1){
      #pragma unroll
      for (int g=0;g<G;++g) og[g*800 + c] = (short)f2bf(acc[r][g]);
    }
  }
  for (int p=tid; p<G*20; p+=256){ int g=p/20, c2=780+p%20; og[g*800 + c2] = 0; }
}

// ---------------- pooling (col-split) ----------------
__device__ __forceinline__ int lowb(const int* a, int n, int v){
  int lo=0, hi=n;
  while (lo<hi){ int mid=(lo+hi)>>1; if (a[mid]<v) lo=mid+1; else hi=mid; }
  return lo;
}

__global__ void k_pool(const float* __restrict__ out2, const float* __restrict__ b2,
                       const int* __restrict__ batch, int N, float* __restrict__ gfeat){
  int b = blockIdx.x;
  int c = blockIdx.y*256 + threadIdx.x;
  if (c >= D1) return;
  int lo = lowb(batch, N, b), hi = lowb(batch, N, b+1);
  float bb = b2[c];
  float mx = -INFINITY, sm = 0.f;
  for (int n2=lo;n2<hi;++n2){
    float v = fmaxf(out2[(size_t)n2*D1 + c] + bb, 0.f);
    mx = fmaxf(mx, v);
    sm += v;
  }
  int cnt = hi-lo;
  gfeat[(size_t)b*1560 + c] = mx;
  gfeat[(size_t)b*1560 + 780 + c] = sm / fmaxf((float)cnt, 1.f);
}

// ---------------- protein conv: rank-26 factorization ----------------
__global__ void k_wcf(const float* __restrict__ Wc, float* __restrict__ WcF){
  int id = blockIdx.x*256 + threadIdx.x;
  if (id < 256000){
    int i = id >> 8, r = id & 255;
    WcF[id] = Wc[(size_t)(r>>3)*8000 + i*8 + (r&7)];
  }
}

__global__ __launch_bounds__(256) void k_prot(const int* __restrict__ target, const float* __restrict__ WcF,
                       const float* __restrict__ emb, const float* __restrict__ bc,
                       float* __restrict__ convc){
  __shared__ float Q[256*27];
  __shared__ float emb_l[26*128];
  __shared__ int tg_l[1000];
  int b = blockIdx.x, tid = threadIdx.x;
  for (int i=tid;i<26*128;i+=256) emb_l[i]=emb[i];
  for (int i=tid;i<1000;i+=256) tg_l[i]=target[b*1000+i];
  for (int i=tid;i<256*27;i+=256) Q[i]=0.f;
  __syncthreads();
  float* q = Q + tid*27;
  for (int i=0;i<1000;++i){
    float w = WcF[i*256 + tid];
    q[tg_l[i]] += w;
  }
  __syncthreads();
  for (int p=tid; p<32*121; p+=256){
    int o = p/121, t = p%121;
    float acc = bc[o];
    const float* qb = Q + (o*8)*27;
    for (int v=0; v<26; ++v){
      const float* ev = emb_l + v*128 + t;
      #pragma unroll
      for (int k=0;k<8;++k) acc += qb[k*27 + v] * ev[k];
    }
    convc[(size_t)b*3872 + p] = acc;
  }
}

// ---------------- split-K skinny GEMM (M<=64) ----------------
__global__ __launch_bounds__(256) void k_skinny(const float* __restrict__ A, const float* __restrict__ B,
                        float* __restrict__ C, int M, int N, int K, int ldb, int ldc, int kc){
  int col0 = blockIdx.x*64;
  int k0 = blockIdx.y*kc, k1 = min(K, k0+kc);
  int tx = threadIdx.x & 63, ty = threadIdx.x >> 6;
  int col = col0 + tx;
  if (col >= N) return;
  float acc[16] = {};
  for (int k=k0; k<k1; ++k){
    float b = B[(size_t)k*ldb + col];
    const float* Ak = A + (size_t)(ty*16)*K + k;
    #pragma unroll
    for (int i=0;i<16;++i) acc[i] += Ak[(size_t)i*K] * b;
  }
  #pragma unroll
  for (int i=0;i<16;++i){
    int r = ty*16 + i;
    if (r < M) atomicAdd(&C[(size_t)r*ldc + col], acc[i]);
  }
}

__global__ void k_biasact(float* __restrict__ C, const float* __restrict__ bias,
                          int M, int N, int ldc, int act){
  int id = blockIdx.x*256 + threadIdx.x;
  if (id >= M*N) return;
  int r = id / N, c = id % N;
  float v = C[(size_t)r*ldc + c] + bias[c];
  if (act == 1) v = fmaxf(v, 0.f);
  C[(size_t)r*ldc + c] = v;
}

// ---------------- final Wo dot ----------------
__global__ void k_wo(const float* __restrict__ f2, const float* __restrict__ Wo,
                     const float* __restrict__ bo, float* __restrict__ out, int M){
  __shared__ float red[256];
  int tid = threadIdx.x;
  int r = tid & 63, kg = tid >> 6;
  float p = 0.f;
  for (int k = kg*128; k < kg*128 + 128; ++k) p += f2[(size_t)r*512 + k] * Wo[k];
  red[tid] = p;
  __syncthreads();
  if (tid < 64 && tid < M) out[tid] = red[tid] + red[tid+64] + red[tid+128] + red[tid+192] + bo[0];
}

// ---------------- launch ----------------
extern "C" void kernel_launch(void* const* d_in, const int* in_sizes, int n_in,
                              void* d_out, int out_size, void* d_ws, size_t ws_size,
                              hipStream_t stream){
  const float* x   = (const float*)d_in[0];
  const int*   ei    = (const int*)d_in[1];
  const int*   batch = (const int*)d_in[2];
  const int*   target= (const int*)d_in[3];
  const float* W1  = (const float*)d_in[4];
  const float* a1s = (const float*)d_in[5];
  const float* a1d = (const float*)d_in[6];
  const float* b1  = (const float*)d_in[7];
  const float* W2  = (const float*)d_in[8];
  const float* a2s = (const float*)d_in[9];
  const float* a2d = (const float*)d_in[10];
  const float* b2  = (const float*)d_in[11];
  const float* Wg1 = (const float*)d_in[12];
  const float* bg1 = (const float*)d_in[13];
  const float* Wg2 = (const float*)d_in[14];
  const float* bg2 = (const float*)d_in[15];
  const float* emb = (const float*)d_in[16];
  const float* Wc  = (const float*)d_in[17];
  const float* bc  = (const float*)d_in[18];
  const float* Wxt = (const float*)d_in[19];
  const float* bxt = (const float*)d_in[20];
  const float* Wf1 = (const float*)d_in[21];
  const float* bf1 = (const float*)d_in[22];
  const float* Wf2 = (const float*)d_in[23];
  const float* bf2 = (const float*)d_in[24];
  const float* Wo  = (const float*)d_in[25];
  const float* bo  = (const float*)d_in[26];

  int N = in_sizes[0] / 78;
  int Eraw = in_sizes[1] / 2;
  int Bb = in_sizes[3] / 1000;
  int Etot = Eraw + N;

  char* wsp = (char*)d_ws;
  size_t off = 0;
  auto alloc = [&](size_t bytes)->void*{ void* p = wsp + off; off += (bytes + 255) & ~(size_t)255; return p; };
  float* buf1   = (float*)alloc((size_t)N*D1*4);   // h1
  float* buf2   = (float*)alloc((size_t)N*D1*4);   // g1
  float* buf3   = (float*)alloc((size_t)N*D1*4);   // out2
  float* hsd1   = (float*)alloc((size_t)N*20*4);
  float* hsd2   = (float*)alloc((size_t)N*20*4);
  float* WsdT1  = (float*)alloc((size_t)20*D1*4);
  float* WsdT2  = (float*)alloc((size_t)20*D1*4);
  int*   counts = (int*)alloc((size_t)N*4);
  int*   row_ptr= (int*)alloc((size_t)(N+1)*4);
  int*   cursor = (int*)alloc((size_t)N*4);
  int*   col_src= (int*)alloc((size_t)Etot*4);
  float* WcF    = (float*)alloc((size_t)1000*256*4);
  float* convc  = (float*)alloc((size_t)Bb*3872*4);
  float* gfeat  = (float*)alloc((size_t)Bb*1560*4);
  float* fcg1   = (float*)alloc((size_t)Bb*1500*4);
  float* xc     = (float*)alloc((size_t)Bb*256*4);
  float* f1     = (float*)alloc((size_t)Bb*1024*4);
  float* f2     = (float*)alloc((size_t)Bb*512*4);
  short* W2rT   = (short*)alloc((size_t)D1*8000*2);  // [c][h*800+k] bf16
  // choose largest head-group G whose aggB fits
  int G = 10;
  { size_t avail = (ws_size > off + (1u<<20)) ? ws_size - off - (1u<<20) : 0;
    if      (avail >= (size_t)N*10*800*2) G = 10;
    else if (avail >= (size_t)N*5*800*2)  G = 5;
    else if (avail >= (size_t)N*2*800*2)  G = 2;
    else                                   G = 1; }
  short* aggB = (short*)alloc((size_t)N*G*800*2);
  (void)n_in; (void)out_size;

  // ---- CSR by dst (self-loops appended) ----
  hipMemsetAsync(counts, 0, (size_t)N*4, stream);
  int thr=256, blk=(Etot+thr-1)/thr;
  k_count<<<blk,thr,0,stream>>>(ei+Eraw, counts, Eraw, N);
  k_scan<<<1,1024,0,stream>>>(counts, row_ptr, cursor, N);
  k_scatter<<<blk,thr,0,stream>>>(ei, ei+Eraw, cursor, col_src, Eraw, N);

  // ---- zero atomic-target buffers ----
  hipMemsetAsync(fcg1, 0, (size_t)Bb*1500*4, stream);
  hipMemsetAsync(xc,   0, (size_t)Bb*256*4,  stream);
  hipMemsetAsync(f1,   0, (size_t)Bb*1024*4, stream);
  hipMemsetAsync(f2,   0, (size_t)Bb*512*4,  stream);

  // ---- protein branch: rank-26 factorization ----
  k_wcf<<<(256000+255)/256,256,0,stream>>>(Wc, WcF);
  k_prot<<<Bb,256,0,stream>>>(target, WcF, emb, bc, convc);
  { dim3 g((128+63)/64, (3872+127)/128);
    k_skinny<<<g,256,0,stream>>>(convc, Wxt, xc+128, Bb, 128, 3872, 128, 256, 128);
    k_biasact<<<(Bb*128+255)/256,256,0,stream>>>(xc+128, bxt, Bb, 128, 256, 0); }

  // ---- GAT layer 1 ----
  dim3 gW1((D1+127)/128, (N+127)/128);
  k_gemm128<<<gW1,256,0,stream>>>(x, W1, buf1, nullptr, N, D1, 78, 78, D1, D1, 0, 0);
  k_mkwsd1<<<(20*D1+255)/256,256,0,stream>>>(a1s, a1d, WsdT1);
  k_proj20<<<(N+3)/4,256,0,stream>>>(buf1, WsdT1, hsd1, N);
  k_agg1<<<N,256,0,stream>>>(buf1, hsd1, row_ptr, col_src, b1, buf2);

  // ---- GAT layer 2 ----
  k_makews2<<<D1,256,0,stream>>>(W2, a2s, a2d, WsdT2);
  k_proj20<<<(N+3)/4,256,0,stream>>>(buf2, WsdT2, hsd2, N);
  { dim3 g(25, 25, 10); dim3 b(32, 8);
    k_w2t<<<g,b,0,stream>>>(W2, W2rT); }

  float* out2 = buf3;
  dim3 gMM((D1+127)/128, (N+127)/128);
  for (int h0=0; h0<HEADS; h0+=G){
    switch (G){
      case 10: k_aggG<10><<<N,256,0,stream>>>(buf2, hsd2, row_ptr, col_src, aggB, h0); break;
      case 5:  k_aggG<5> <<<N,256,0,stream>>>(buf2, hsd2, row_ptr, col_src, aggB, h0); break;
      case 2:  k_aggG<2> <<<N,256,0,stream>>>(buf2, hsd2, row_ptr, col_src, aggB, h0); break;
      default: k_aggG<1> <<<N,256,0,stream>>>(buf2, hsd2, row_ptr, col_src, aggB, h0); break;
    }
    k_mfma_nt<<<gMM,256,0,stream>>>(aggB, W2rT + h0*800, out2, N, D1, G*800, G*800, 8000, D1, h0?1:0);
  }

  // ---- pooling (bias+relu fused, col-split) ----
  { dim3 gp(Bb, 4);
    k_pool<<<gp,256,0,stream>>>(out2, b2, batch, N, gfeat); }

  // ---- graph FCs (split-K skinny) ----
  { dim3 g((1500+63)/64, (1560+127)/128);
    k_skinny<<<g,256,0,stream>>>(gfeat, Wg1, fcg1, Bb, 1500, 1560, 1500, 1500, 128);
    k_biasact<<<(Bb*1500+255)/256,256,0,stream>>>(fcg1, bg1, Bb, 1500, 1500, 1); }
  { dim3 g((128+63)/64, (1500+127)/128);
    k_skinny<<<g,256,0,stream>>>(fcg1, Wg2, xc, Bb, 128, 1500, 128, 256, 128);
    k_biasact<<<(Bb*128+255)/256,256,0,stream>>>(xc, bg2, Bb, 128, 256, 1); }

  // ---- fusion MLP ----
  { dim3 g((1024+63)/64, (256+127)/128);
    k_skinny<<<g,256,0,stream>>>(xc, Wf1, f1, Bb, 1024, 256, 1024, 1024, 128);
    k_biasact<<<(Bb*1024+255)/256,256,0,stream>>>(f1, bf1, Bb, 1024, 1024, 1); }
  { dim3 g((512+63)/64, (1024+127)/128);
    k_skinny<<<g,256,0,stream>>>(f1, Wf2, f2, Bb, 512, 1024, 512, 512, 128);
    k_biasact<<<(Bb*512+255)/256,256,0,stream>>>(f2, bf2, Bb, 512, 512, 1); }
  k_wo<<<1,256,0,stream>>>(f2, Wo, bo, (float*)d_out, Bb);
}

// Round 7
// 1354.110 us; speedup vs baseline: 4.9326x; 1.0601x over previous
//
#include <hip/hip_runtime.h>
#include <math.h>

#define HEADS 10
#define D1 780
#define F1 78

typedef __attribute__((ext_vector_type(8))) short bf16x8;
typedef __attribute__((ext_vector_type(4))) float f32x4;

static __device__ __forceinline__ float lrelu(float x){ return x > 0.f ? x : 0.2f*x; }

static __device__ __forceinline__ unsigned short f2bf(float f){
  unsigned int u = __float_as_uint(f);
  u += 0x7fffu + ((u >> 16) & 1u);   // RNE
  return (unsigned short)(u >> 16);
}

// ---------------- CSR build ----------------
__global__ void k_count(const int* __restrict__ dst, int* __restrict__ counts, int Eraw, int N){
  int e = blockIdx.x*blockDim.x + threadIdx.x;
  if (e < Eraw + N){
    int d = (e < Eraw) ? dst[e] : (e - Eraw);
    atomicAdd(&counts[d], 1);
  }
}

__global__ void k_scan(const int* __restrict__ counts, int* __restrict__ row_ptr,
                       int* __restrict__ cursor, int N){
  __shared__ int part[1024];
  int tid = threadIdx.x;
  int chunk = (N + 1023)/1024;
  int beg = tid*chunk, end = min(beg+chunk, N);
  int s = 0;
  for (int i=beg;i<end;++i) s += counts[i];
  part[tid] = s;
  __syncthreads();
  for (int off=1; off<1024; off<<=1){
    int v = (tid >= off) ? part[tid-off] : 0;
    __syncthreads();
    part[tid] += v;
    __syncthreads();
  }
  int excl = (tid>0) ? part[tid-1] : 0;
  for (int i=beg;i<end;++i){ row_ptr[i]=excl; cursor[i]=excl; excl += counts[i]; }
  if (tid == 1023) row_ptr[N] = part[1023];
}

__global__ void k_scatter(const int* __restrict__ src, const int* __restrict__ dst,
                          int* __restrict__ cursor, int* __restrict__ col_src, int Eraw, int N){
  int e = blockIdx.x*blockDim.x + threadIdx.x;
  if (e < Eraw + N){
    int s, d;
    if (e < Eraw){ s = src[e]; d = dst[e]; } else { s = e - Eraw; d = s; }
    int pos = atomicAdd(&cursor[d], 1);
    col_src[pos] = s;
  }
}

// ---------------- 128x128 tiled fp32 GEMM (W1 only) ----------------
__global__ __launch_bounds__(256) void k_gemm128(const float* __restrict__ A, const float* __restrict__ Bm,
                       float* __restrict__ C, const float* __restrict__ bias,
                       int M, int Nn, int K, int lda, int ldb, int ldc, int act, int accum){
  __shared__ __align__(16) float As[16][132];
  __shared__ __align__(16) float Bs[16][132];
  int tid = threadIdx.x;
  int tx = tid & 15, ty = tid >> 4;
  int row0 = blockIdx.y*128, col0 = blockIdx.x*128;
  float acc[8][8] = {};
  for (int kk=0; kk<K; kk+=16){
    for (int l = tid; l < 128*16; l += 256){
      int m = l >> 4, k = l & 15;
      int gr = row0 + m, gk = kk + k;
      As[k][m] = (gr < M && gk < K) ? A[(size_t)gr*lda + gk] : 0.f;
    }
    for (int l = tid; l < 16*128; l += 256){
      int k = l >> 7, n = l & 127;
      int gk = kk + k, gc = col0 + n;
      Bs[k][n] = (gk < K && gc < Nn) ? Bm[(size_t)gk*ldb + gc] : 0.f;
    }
    __syncthreads();
    #pragma unroll
    for (int k=0;k<16;++k){
      float4 a0 = *reinterpret_cast<const float4*>(&As[k][ty*4]);
      float4 a1 = *reinterpret_cast<const float4*>(&As[k][64+ty*4]);
      float4 b0 = *reinterpret_cast<const float4*>(&Bs[k][tx*4]);
      float4 b1 = *reinterpret_cast<const float4*>(&Bs[k][64+tx*4]);
      float av[8] = {a0.x,a0.y,a0.z,a0.w,a1.x,a1.y,a1.z,a1.w};
      float bv[8] = {b0.x,b0.y,b0.z,b0.w,b1.x,b1.y,b1.z,b1.w};
      #pragma unroll
      for (int i=0;i<8;++i)
        #pragma unroll
        for (int j=0;j<8;++j)
          acc[i][j] += av[i]*bv[j];
    }
    __syncthreads();
  }
  #pragma unroll
  for (int i=0;i<8;++i){
    int r = row0 + ((i<4) ? ty*4+i : 64+ty*4+(i-4));
    if (r >= M) continue;
    #pragma unroll
    for (int j=0;j<8;++j){
      int c = col0 + ((j<4) ? tx*4+j : 64+tx*4+(j-4));
      if (c >= Nn) continue;
      float v = acc[i][j];
      if (accum) v += C[(size_t)r*ldc + c];
      if (bias) v += bias[c];
      if (act == 1) v = fmaxf(v, 0.f);
      C[(size_t)r*ldc + c] = v;
    }
  }
}

// ---------------- MFMA bf16 NT GEMM, global_load_lds + both-sides swizzle + XCD chunking ----------------
// C[M,N] (+)= A[M,K] @ BT[N,K]^T. A,BT bf16 (as short), K%32==0, rows 16B-aligned.
// LDS tile [128 rows][32 shorts]; slot' = slot ^ ((row>>1)&3) (2-way banks, free).
__global__ __launch_bounds__(256) void k_mfma_nt(const short* __restrict__ A, const short* __restrict__ BT,
                        float* __restrict__ C, int M, int N, int K,
                        int lda, int ldb, int ldc, int accum, int nbx){
  __shared__ __align__(16) short As[128*32];
  __shared__ __align__(16) short Bs[128*32];
  int tid = threadIdx.x;
  int lane = tid & 63, wave = tid >> 6;
  int wr = (wave >> 1) * 64, wc = (wave & 1) * 64;

  // bijective XCD-chunked swizzle (m204): same-row blocks share one XCD's L2
  int nwg = gridDim.x;
  int q = nwg >> 3, rr = nwg & 7;
  int xcd = blockIdx.x & 7, rank = blockIdx.x >> 3;
  int l = xcd*q + min(xcd, rr) + rank;
  int row0 = (l / nbx) * 128, col0 = (l % nbx) * 128;

  // staging: lane covers row (lane>>2), linear slot (lane&3); global source slot inverse-swizzled
  int kp = ((lane & 3) ^ ((lane >> 3) & 3)) * 8;
  int rA0 = min(row0 + wave*32 + (lane>>2), M-1);
  int rA1 = min(row0 + wave*32 + 16 + (lane>>2), M-1);
  int rB0 = min(col0 + wave*32 + (lane>>2), N-1);
  int rB1 = min(col0 + wave*32 + 16 + (lane>>2), N-1);
  const short* pa0 = A  + (size_t)rA0*lda + kp;
  const short* pa1 = A  + (size_t)rA1*lda + kp;
  const short* pb0 = BT + (size_t)rB0*ldb + kp;
  const short* pb1 = BT + (size_t)rB1*ldb + kp;
  short* la0 = As + (wave*32 + 0)*32;
  short* la1 = As + (wave*32 + 16)*32;
  short* lb0 = Bs + (wave*32 + 0)*32;
  short* lb1 = Bs + (wave*32 + 16)*32;

  // swizzled fragment-read slot (same for all rb/cb: row bits from rb*16 vanish in (row>>1)&3)
  int so = ((lane>>4) ^ (((lane&15)>>1)&3)) * 8;

  f32x4 acc[4][4];
  #pragma unroll
  for (int i=0;i<4;++i)
    #pragma unroll
    for (int j=0;j<4;++j) acc[i][j] = (f32x4){0.f,0.f,0.f,0.f};

  for (int k0=0; k0<K; k0+=32){
    __builtin_amdgcn_global_load_lds((const __attribute__((address_space(1))) unsigned int*)pa0,
                                     (__attribute__((address_space(3))) unsigned int*)la0, 16, 0, 0);
    __builtin_amdgcn_global_load_lds((const __attribute__((address_space(1))) unsigned int*)pa1,
                                     (__attribute__((address_space(3))) unsigned int*)la1, 16, 0, 0);
    __builtin_amdgcn_global_load_lds((const __attribute__((address_space(1))) unsigned int*)pb0,
                                     (__attribute__((address_space(3))) unsigned int*)lb0, 16, 0, 0);
    __builtin_amdgcn_global_load_lds((const __attribute__((address_space(1))) unsigned int*)pb1,
                                     (__attribute__((address_space(3))) unsigned int*)lb1, 16, 0, 0);
    pa0 += 32; pa1 += 32; pb0 += 32; pb1 += 32;
    __syncthreads();
    bf16x8 af[4], bf[4];
    #pragma unroll
    for (int rb=0;rb<4;++rb)
      af[rb] = *reinterpret_cast<const bf16x8*>(&As[(wr + rb*16 + (lane&15))*32 + so]);
    #pragma unroll
    for (int cb=0;cb<4;++cb)
      bf[cb] = *reinterpret_cast<const bf16x8*>(&Bs[(wc + cb*16 + (lane&15))*32 + so]);
    #pragma unroll
    for (int rb=0;rb<4;++rb)
      #pragma unroll
      for (int cb=0;cb<4;++cb)
        acc[rb][cb] = __builtin_amdgcn_mfma_f32_16x16x32_bf16(af[rb], bf[cb], acc[rb][cb], 0, 0, 0);
    __syncthreads();
  }
  #pragma unroll
  for (int rb=0;rb<4;++rb){
    #pragma unroll
    for (int cb=0;cb<4;++cb){
      int c = col0 + wc + cb*16 + (lane & 15);
      if (c >= N) continue;
      #pragma unroll
      for (int j=0;j<4;++j){
        int r = row0 + wr + rb*16 + (lane>>4)*4 + j;
        if (r >= M) continue;
        float v = acc[rb][cb][j];
        if (accum) v += C[(size_t)r*ldc + c];
        C[(size_t)r*ldc + c] = v;
      }
    }
  }
}

// ---------------- W2 repack: W2rT[c][h*800+k] = bf16(W2[k][h*780+c]) ----------------
__global__ void k_w2t(const float* __restrict__ W2, short* __restrict__ W2rT){
  __shared__ float s[32][33];
  int k0 = blockIdx.x*32, c0 = blockIdx.y*32, h = blockIdx.z;
  int tx = threadIdx.x, ty = threadIdx.y;
  #pragma unroll
  for (int i=0;i<32;i+=8){
    int k = k0+ty+i, c = c0+tx;
    s[ty+i][tx] = (k < 780 && c < 780) ? W2[(size_t)k*7800 + h*780 + c] : 0.f;
  }
  __syncthreads();
  #pragma unroll
  for (int i=0;i<32;i+=8){
    int c = c0+ty+i, k = k0+tx;
    if (c < 780 && k < 800)
      W2rT[(size_t)c*8000 + h*800 + k] = (short)f2bf(s[tx][ty+i]);
  }
}

// ---------------- Wsd1T build: [20][780] block-diagonal from a1s/a1d ----------------
__global__ void k_mkwsd1(const float* __restrict__ a1s, const float* __restrict__ a1d,
                         float* __restrict__ WsdT){
  int id = blockIdx.x*256 + threadIdx.x;
  if (id >= 20*780) return;
  int j = id / 780, c = id % 780;
  int h = (j < 10) ? j : j - 10;
  float v = 0.f;
  if (c / F1 == h) v = (j < 10) ? a1s[h*F1 + c%F1] : a1d[h*F1 + c%F1];
  WsdT[id] = v;
}

// ---------------- layer-2 score projections -> WsdT2[j][c] ----------------
__global__ void k_makews2(const float* __restrict__ W2, const float* __restrict__ a2s,
                          const float* __restrict__ a2d, float* __restrict__ WsdT){
  __shared__ float out[20];
  int c = blockIdx.x, tid = threadIdx.x;
  if (tid < 20) out[tid] = 0.f;
  __syncthreads();
  const float* row = W2 + (size_t)c*7800;
  for (int j = tid; j < 7800; j += 256){
    float v = row[j];
    int h = j / D1;
    atomicAdd(&out[h],    v * a2s[j]);
    atomicAdd(&out[10+h], v * a2d[j]);
  }
  __syncthreads();
  if (tid < 20) WsdT[(size_t)tid*780 + c] = out[tid];
}

// ---------------- tall-skinny projection: out[n][j] = sum_c A[n][c]*WT[j][c], j<20 ----------------
__global__ __launch_bounds__(256) void k_proj20(const float* __restrict__ A, const float* __restrict__ WT,
                        float* __restrict__ out, int N){
  int n = blockIdx.x*4 + (threadIdx.x >> 6);
  if (n >= N) return;
  int lane = threadIdx.x & 63;
  const float* row = A + (size_t)n*D1;
  float acc[20] = {};
  #pragma unroll
  for (int r=0;r<12;++r){
    int c = lane + r*64;
    float v = row[c];
    #pragma unroll
    for (int j=0;j<20;++j) acc[j] += v * WT[j*780 + c];
  }
  { int c = 768 + lane;
    if (c < D1){
      float v = row[c];
      #pragma unroll
      for (int j=0;j<20;++j) acc[j] += v * WT[j*780 + c];
    } }
  #pragma unroll
  for (int j=0;j<20;++j){
    #pragma unroll
    for (int off=32; off; off>>=1) acc[j] += __shfl_xor(acc[j], off);
  }
  #pragma unroll
  for (int j=0;j<20;++j) if (lane == j) out[(size_t)n*20 + j] = acc[j];
}

// ---------------- GAT layer 1 aggregation (float4 gather) ----------------
#define CH1 32
__global__ __launch_bounds__(256) void k_agg1(const float* __restrict__ h1, const float* __restrict__ hsd,
                       const int* __restrict__ row_ptr, const int* __restrict__ col_src,
                       const float* __restrict__ b1, float* __restrict__ g1o){
  __shared__ float m_l[HEADS], s_l[HEADS];
  __shared__ float al[CH1][HEADS];
  __shared__ int src_l[CH1];
  int n = blockIdx.x, tid = threadIdx.x;
  int beg = row_ptr[n], end = row_ptr[n+1];
  if (tid < HEADS){
    float hdv = hsd[(size_t)n*20 + 10 + tid];
    float m = -1e30f;
    for (int j=beg;j<end;++j) m = fmaxf(m, lrelu(hsd[(size_t)col_src[j]*20 + tid] + hdv));
    float s = 0.f;
    for (int j=beg;j<end;++j) s += expf(lrelu(hsd[(size_t)col_src[j]*20 + tid] + hdv) - m);
    m_l[tid]=m; s_l[tid]=s;
  }
  __syncthreads();
  float4 a4 = {0.f,0.f,0.f,0.f};
  int c0 = tid*4;
  int h0 = c0/F1, h1i = (c0+1)/F1, h2 = (c0+2)/F1, h3 = (c0+3)/F1;
  for (int j0=beg; j0<end; j0+=CH1){
    int cn = min(CH1, end-j0);
    for (int p=tid; p<cn*HEADS; p+=256){
      int j = p/HEADS, h = p - j*HEADS;
      int sidx = col_src[j0+j];
      if (h==0) src_l[j] = sidx;
      float sc = lrelu(hsd[(size_t)sidx*20 + h] + hsd[(size_t)n*20 + 10 + h]);
      al[j][h] = expf(sc - m_l[h]) / s_l[h];
    }
    __syncthreads();
    if (tid < 195){
      for (int j=0;j<cn;++j){
        const float4* hr4 = reinterpret_cast<const float4*>(h1 + (size_t)src_l[j]*D1);
        float4 v = hr4[tid];
        a4.x += al[j][h0]*v.x;
        a4.y += al[j][h1i]*v.y;
        a4.z += al[j][h2]*v.z;
        a4.w += al[j][h3]*v.w;
      }
    }
    __syncthreads();
  }
  if (tid < 195){
    float4 o;
    float v0 = a4.x + b1[c0];   o.x = v0 > 0.f ? v0 : expm1f(v0);
    float v1 = a4.y + b1[c0+1]; o.y = v1 > 0.f ? v1 : expm1f(v1);
    float v2 = a4.z + b1[c0+2]; o.z = v2 > 0.f ? v2 : expm1f(v2);
    float v3 = a4.w + b1[c0+3]; o.w = v3 > 0.f ? v3 : expm1f(v3);
    *reinterpret_cast<float4*>(g1o + (size_t)n*D1 + c0) = o;
  }
}

// ---------------- layer-2 aggregation (float4 gather) -> aggB bf16 [N][G*800] ----------------
template<int G>
__global__ __launch_bounds__(256) void k_aggG(const float* __restrict__ g1, const float* __restrict__ hsd,
                       const int* __restrict__ row_ptr, const int* __restrict__ col_src,
                       short* __restrict__ aggB, int h0){
  __shared__ float m_l[G], s_l[G];
  __shared__ float al[16][G];
  __shared__ int src_l[16];
  int n = blockIdx.x, tid = threadIdx.x;
  int beg = row_ptr[n], end = row_ptr[n+1];
  if (tid < G){
    int h = h0 + tid;
    float hdv = hsd[(size_t)n*20 + 10 + h];
    float m = -1e30f;
    for (int j=beg;j<end;++j) m = fmaxf(m, lrelu(hsd[(size_t)col_src[j]*20 + h] + hdv));
    float s = 0.f;
    for (int j=beg;j<end;++j) s += expf(lrelu(hsd[(size_t)col_src[j]*20 + h] + hdv) - m);
    m_l[tid]=m; s_l[tid]=s;
  }
  __syncthreads();
  float acc[4][G] = {};
  for (int j0=beg; j0<end; j0+=16){
    int cn = min(16, end-j0);
    for (int p=tid; p<cn*G; p+=256){
      int j = p/G, g = p - j*G;
      int h = h0 + g;
      int sidx = col_src[j0+j];
      if (g==0) src_l[j] = sidx;
      float hdv = hsd[(size_t)n*20 + 10 + h];
      al[j][g] = 0.1f * expf(lrelu(hsd[(size_t)sidx*20 + h] + hdv) - m_l[g]) / s_l[g];
    }
    if (G == 1) for (int p=tid; p<cn; p+=256) src_l[p] = col_src[j0+p];
    __syncthreads();
    if (tid < 195){
      for (int j=0;j<cn;++j){
        const float4* gr4 = reinterpret_cast<const float4*>(g1 + (size_t)src_l[j]*D1);
        float4 v = gr4[tid];
        #pragma unroll
        for (int g=0;g<G;++g){
          float a = al[j][g];
          acc[0][g] += a*v.x; acc[1][g] += a*v.y;
          acc[2][g] += a*v.z; acc[3][g] += a*v.w;
        }
      }
    }
    __syncthreads();
  }
  short* og = aggB + (size_t)n*G*800;
  if (tid < 195){
    int c0 = tid*4;
    #pragma unroll
    for (int g=0;g<G;++g){
      ushort4 o;
      o.x = f2bf(acc[0][g]); o.y = f2bf(acc[1][g]);
      o.z = f2bf(acc[2][g]); o.w = f2bf(acc[3][g]);
      *reinterpret_cast<ushort4*>(og + g*800 + c0) = o;
    }
  }
  for (int p=tid; p<G*20; p+=256){ int g=p/20, c2=780+p%20; og[g*800 + c2] = 0; }
}

// ---------------- pooling (col-split) ----------------
__device__ __forceinline__ int lowb(const int* a, int n, int v){
  int lo=0, hi=n;
  while (lo<hi){ int mid=(lo+hi)>>1; if (a[mid]<v) lo=mid+1; else hi=mid; }
  return lo;
}

__global__ void k_pool(const float* __restrict__ out2, const float* __restrict__ b2,
                       const int* __restrict__ batch, int N, float* __restrict__ gfeat){
  int b = blockIdx.x;
  int c = blockIdx.y*256 + threadIdx.x;
  if (c >= D1) return;
  int lo = lowb(batch, N, b), hi = lowb(batch, N, b+1);
  float bb = b2[c];
  float mx = -INFINITY, sm = 0.f;
  for (int n2=lo;n2<hi;++n2){
    float v = fmaxf(out2[(size_t)n2*D1 + c] + bb, 0.f);
    mx = fmaxf(mx, v);
    sm += v;
  }
  int cnt = hi-lo;
  gfeat[(size_t)b*1560 + c] = mx;
  gfeat[(size_t)b*1560 + 780 + c] = sm / fmaxf((float)cnt, 1.f);
}

// ---------------- protein conv: rank-26 factorization ----------------
__global__ void k_wcf(const float* __restrict__ Wc, float* __restrict__ WcF){
  int id = blockIdx.x*256 + threadIdx.x;
  if (id < 256000){
    int i = id >> 8, r = id & 255;
    WcF[id] = Wc[(size_t)(r>>3)*8000 + i*8 + (r&7)];
  }
}

__global__ __launch_bounds__(256) void k_prot(const int* __restrict__ target, const float* __restrict__ WcF,
                       const float* __restrict__ emb, const float* __restrict__ bc,
                       float* __restrict__ convc){
  __shared__ float Q[256*27];
  __shared__ float emb_l[26*128];
  __shared__ int tg_l[1000];
  int b = blockIdx.x, tid = threadIdx.x;
  for (int i=tid;i<26*128;i+=256) emb_l[i]=emb[i];
  for (int i=tid;i<1000;i+=256) tg_l[i]=target[b*1000+i];
  for (int i=tid;i<256*27;i+=256) Q[i]=0.f;
  __syncthreads();
  float* q = Q + tid*27;
  for (int i=0;i<1000;++i){
    float w = WcF[i*256 + tid];
    q[tg_l[i]] += w;
  }
  __syncthreads();
  for (int p=tid; p<32*121; p+=256){
    int o = p/121, t = p%121;
    float acc = bc[o];
    const float* qb = Q + (o*8)*27;
    for (int v=0; v<26; ++v){
      const float* ev = emb_l + v*128 + t;
      #pragma unroll
      for (int k=0;k<8;++k) acc += qb[k*27 + v] * ev[k];
    }
    convc[(size_t)b*3872 + p] = acc;
  }
}

// ---------------- split-K skinny GEMM (M<=64) ----------------
__global__ __launch_bounds__(256) void k_skinny(const float* __restrict__ A, const float* __restrict__ B,
                        float* __restrict__ C, int M, int N, int K, int ldb, int ldc, int kc){
  int col0 = blockIdx.x*64;
  int k0 = blockIdx.y*kc, k1 = min(K, k0+kc);
  int tx = threadIdx.x & 63, ty = threadIdx.x >> 6;
  int col = col0 + tx;
  if (col >= N) return;
  float acc[16] = {};
  for (int k=k0; k<k1; ++k){
    float b = B[(size_t)k*ldb + col];
    const float* Ak = A + (size_t)(ty*16)*K + k;
    #pragma unroll
    for (int i=0;i<16;++i) acc[i] += Ak[(size_t)i*K] * b;
  }
  #pragma unroll
  for (int i=0;i<16;++i){
    int r = ty*16 + i;
    if (r < M) atomicAdd(&C[(size_t)r*ldc + col], acc[i]);
  }
}

__global__ void k_biasact(float* __restrict__ C, const float* __restrict__ bias,
                          int M, int N, int ldc, int act){
  int id = blockIdx.x*256 + threadIdx.x;
  if (id >= M*N) return;
  int r = id / N, c = id % N;
  float v = C[(size_t)r*ldc + c] + bias[c];
  if (act == 1) v = fmaxf(v, 0.f);
  C[(size_t)r*ldc + c] = v;
}

// ---------------- final Wo dot (f2 bias+relu fused) ----------------
__global__ void k_wo(const float* __restrict__ f2, const float* __restrict__ bf2,
                     const float* __restrict__ Wo, const float* __restrict__ bo,
                     float* __restrict__ out, int M){
  __shared__ float red[256];
  int tid = threadIdx.x;
  int r = tid & 63, kg = tid >> 6;
  float p = 0.f;
  for (int k = kg*128; k < kg*128 + 128; ++k)
    p += fmaxf(f2[(size_t)r*512 + k] + bf2[k], 0.f) * Wo[k];
  red[tid] = p;
  __syncthreads();
  if (tid < 64 && tid < M) out[tid] = red[tid] + red[tid+64] + red[tid+128] + red[tid+192] + bo[0];
}

// ---------------- launch ----------------
extern "C" void kernel_launch(void* const* d_in, const int* in_sizes, int n_in,
                              void* d_out, int out_size, void* d_ws, size_t ws_size,
                              hipStream_t stream){
  const float* x   = (const float*)d_in[0];
  const int*   ei    = (const int*)d_in[1];
  const int*   batch = (const int*)d_in[2];
  const int*   target= (const int*)d_in[3];
  const float* W1  = (const float*)d_in[4];
  const float* a1s = (const float*)d_in[5];
  const float* a1d = (const float*)d_in[6];
  const float* b1  = (const float*)d_in[7];
  const float* W2  = (const float*)d_in[8];
  const float* a2s = (const float*)d_in[9];
  const float* a2d = (const float*)d_in[10];
  const float* b2  = (const float*)d_in[11];
  const float* Wg1 = (const float*)d_in[12];
  const float* bg1 = (const float*)d_in[13];
  const float* Wg2 = (const float*)d_in[14];
  const float* bg2 = (const float*)d_in[15];
  const float* emb = (const float*)d_in[16];
  const float* Wc  = (const float*)d_in[17];
  const float* bc  = (const float*)d_in[18];
  const float* Wxt = (const float*)d_in[19];
  const float* bxt = (const float*)d_in[20];
  const float* Wf1 = (const float*)d_in[21];
  const float* bf1 = (const float*)d_in[22];
  const float* Wf2 = (const float*)d_in[23];
  const float* bf2 = (const float*)d_in[24];
  const float* Wo  = (const float*)d_in[25];
  const float* bo  = (const float*)d_in[26];

  int N = in_sizes[0] / 78;
  int Eraw = in_sizes[1] / 2;
  int Bb = in_sizes[3] / 1000;
  int Etot = Eraw + N;

  char* wsp = (char*)d_ws;
  size_t off = 0;
  auto alloc = [&](size_t bytes)->void*{ void* p = wsp + off; off += (bytes + 255) & ~(size_t)255; return p; };
  float* buf1   = (float*)alloc((size_t)N*D1*4);   // h1
  float* buf2   = (float*)alloc((size_t)N*D1*4);   // g1
  float* buf3   = (float*)alloc((size_t)N*D1*4);   // out2
  float* hsd1   = (float*)alloc((size_t)N*20*4);
  float* hsd2   = (float*)alloc((size_t)N*20*4);
  float* WsdT1  = (float*)alloc((size_t)20*D1*4);
  float* WsdT2  = (float*)alloc((size_t)20*D1*4);
  int*   counts = (int*)alloc((size_t)N*4);
  int*   row_ptr= (int*)alloc((size_t)(N+1)*4);
  int*   cursor = (int*)alloc((size_t)N*4);
  int*   col_src= (int*)alloc((size_t)Etot*4);
  float* WcF    = (float*)alloc((size_t)1000*256*4);
  float* convc  = (float*)alloc((size_t)Bb*3872*4);
  float* gfeat  = (float*)alloc((size_t)Bb*1560*4);
  float* fcg1   = (float*)alloc((size_t)Bb*1500*4);
  float* xc     = (float*)alloc((size_t)Bb*256*4);
  float* f1     = (float*)alloc((size_t)Bb*1024*4);
  float* f2     = (float*)alloc((size_t)Bb*512*4);
  short* W2rT   = (short*)alloc((size_t)D1*8000*2);  // [c][h*800+k] bf16
  // choose largest head-group G whose aggB fits
  int G = 10;
  { size_t avail = (ws_size > off + (1u<<20)) ? ws_size - off - (1u<<20) : 0;
    if      (avail >= (size_t)N*10*800*2) G = 10;
    else if (avail >= (size_t)N*5*800*2)  G = 5;
    else if (avail >= (size_t)N*2*800*2)  G = 2;
    else                                   G = 1; }
  short* aggB = (short*)alloc((size_t)N*G*800*2);
  (void)n_in; (void)out_size;

  // ---- CSR by dst (self-loops appended) ----
  hipMemsetAsync(counts, 0, (size_t)N*4, stream);
  int thr=256, blk=(Etot+thr-1)/thr;
  k_count<<<blk,thr,0,stream>>>(ei+Eraw, counts, Eraw, N);
  k_scan<<<1,1024,0,stream>>>(counts, row_ptr, cursor, N);
  k_scatter<<<blk,thr,0,stream>>>(ei, ei+Eraw, cursor, col_src, Eraw, N);

  // ---- zero atomic-target buffers ----
  hipMemsetAsync(fcg1, 0, (size_t)Bb*1500*4, stream);
  hipMemsetAsync(xc,   0, (size_t)Bb*256*4,  stream);
  hipMemsetAsync(f1,   0, (size_t)Bb*1024*4, stream);
  hipMemsetAsync(f2,   0, (size_t)Bb*512*4,  stream);

  // ---- protein branch: rank-26 factorization ----
  k_wcf<<<(256000+255)/256,256,0,stream>>>(Wc, WcF);
  k_prot<<<Bb,256,0,stream>>>(target, WcF, emb, bc, convc);
  { dim3 g((128+63)/64, (3872+127)/128);
    k_skinny<<<g,256,0,stream>>>(convc, Wxt, xc+128, Bb, 128, 3872, 128, 256, 128);
    k_biasact<<<(Bb*128+255)/256,256,0,stream>>>(xc+128, bxt, Bb, 128, 256, 0); }

  // ---- GAT layer 1 ----
  dim3 gW1((D1+127)/128, (N+127)/128);
  k_gemm128<<<gW1,256,0,stream>>>(x, W1, buf1, nullptr, N, D1, 78, 78, D1, D1, 0, 0);
  k_mkwsd1<<<(20*D1+255)/256,256,0,stream>>>(a1s, a1d, WsdT1);
  k_proj20<<<(N+3)/4,256,0,stream>>>(buf1, WsdT1, hsd1, N);
  k_agg1<<<N,256,0,stream>>>(buf1, hsd1, row_ptr, col_src, b1, buf2);

  // ---- GAT layer 2 ----
  k_makews2<<<D1,256,0,stream>>>(W2, a2s, a2d, WsdT2);
  k_proj20<<<(N+3)/4,256,0,stream>>>(buf2, WsdT2, hsd2, N);
  { dim3 g(25, 25, 10); dim3 b(32, 8);
    k_w2t<<<g,b,0,stream>>>(W2, W2rT); }

  float* out2 = buf3;
  int nbx = (D1+127)/128, nby = (N+127)/128;
  int nwg = nbx*nby;
  for (int h0=0; h0<HEADS; h0+=G){
    switch (G){
      case 10: k_aggG<10><<<N,256,0,stream>>>(buf2, hsd2, row_ptr, col_src, aggB, h0); break;
      case 5:  k_aggG<5> <<<N,256,0,stream>>>(buf2, hsd2, row_ptr, col_src, aggB, h0); break;
      case 2:  k_aggG<2> <<<N,256,0,stream>>>(buf2, hsd2, row_ptr, col_src, aggB, h0); break;
      default: k_aggG<1> <<<N,256,0,stream>>>(buf2, hsd2, row_ptr, col_src, aggB, h0); break;
    }
    k_mfma_nt<<<nwg,256,0,stream>>>(aggB, W2rT + h0*800, out2, N, D1, G*800, G*800, 8000, D1, h0?1:0, nbx);
  }

  // ---- pooling (bias+relu fused, col-split) ----
  { dim3 gp(Bb, 4);
    k_pool<<<gp,256,0,stream>>>(out2, b2, batch, N, gfeat); }

  // ---- graph FCs (split-K skinny) ----
  { dim3 g((1500+63)/64, (1560+127)/128);
    k_skinny<<<g,256,0,stream>>>(gfeat, Wg1, fcg1, Bb, 1500, 1560, 1500, 1500, 128);
    k_biasact<<<(Bb*1500+255)/256,256,0,stream>>>(fcg1, bg1, Bb, 1500, 1500, 1); }
  { dim3 g((128+63)/64, (1500+127)/128);
    k_skinny<<<g,256,0,stream>>>(fcg1, Wg2, xc, Bb, 128, 1500, 128, 256, 128);
    k_biasact<<<(Bb*128+255)/256,256,0,stream>>>(xc, bg2, Bb, 128, 256, 1); }

  // ---- fusion MLP ----
  { dim3 g((1024+63)/64, (256+127)/128);
    k_skinny<<<g,256,0,stream>>>(xc, Wf1, f1, Bb, 1024, 256, 1024, 1024, 128);
    k_biasact<<<(Bb*1024+255)/256,256,0,stream>>>(f1, bf1, Bb, 1024, 1024, 1); }
  { dim3 g((512+63)/64, (1024+127)/128);
    k_skinny<<<g,256,0,stream>>>(f1, Wf2, f2, Bb, 512, 1024, 512, 512, 128); }
  k_wo<<<1,256,0,stream>>>(f2, bf2, Wo, bo, (float*)d_out, Bb);
}

// Round 8
// 1305.932 us; speedup vs baseline: 5.1145x; 1.0369x over previous
//
#include <hip/hip_runtime.h>
#include <math.h>

#define HEADS 10
#define D1 780
#define F1 78

typedef __attribute__((ext_vector_type(8))) short bf16x8;
typedef __attribute__((ext_vector_type(4))) float f32x4;

static __device__ __forceinline__ float lrelu(float x){ return x > 0.f ? x : 0.2f*x; }

static __device__ __forceinline__ unsigned short f2bf(float f){
  unsigned int u = __float_as_uint(f);
  u += 0x7fffu + ((u >> 16) & 1u);   // RNE
  return (unsigned short)(u >> 16);
}

// ---------------- CSR build ----------------
__global__ void k_count(const int* __restrict__ dst, int* __restrict__ counts, int Eraw, int N){
  int e = blockIdx.x*blockDim.x + threadIdx.x;
  if (e < Eraw + N){
    int d = (e < Eraw) ? dst[e] : (e - Eraw);
    atomicAdd(&counts[d], 1);
  }
}

__global__ void k_scan(const int* __restrict__ counts, int* __restrict__ row_ptr,
                       int* __restrict__ cursor, int N){
  __shared__ int part[1024];
  int tid = threadIdx.x;
  int chunk = (N + 1023)/1024;
  int beg = tid*chunk, end = min(beg+chunk, N);
  int s = 0;
  for (int i=beg;i<end;++i) s += counts[i];
  part[tid] = s;
  __syncthreads();
  for (int off=1; off<1024; off<<=1){
    int v = (tid >= off) ? part[tid-off] : 0;
    __syncthreads();
    part[tid] += v;
    __syncthreads();
  }
  int excl = (tid>0) ? part[tid-1] : 0;
  for (int i=beg;i<end;++i){ row_ptr[i]=excl; cursor[i]=excl; excl += counts[i]; }
  if (tid == 1023) row_ptr[N] = part[1023];
}

__global__ void k_scatter(const int* __restrict__ src, const int* __restrict__ dst,
                          int* __restrict__ cursor, int* __restrict__ col_src, int Eraw, int N){
  int e = blockIdx.x*blockDim.x + threadIdx.x;
  if (e < Eraw + N){
    int s, d;
    if (e < Eraw){ s = src[e]; d = dst[e]; } else { s = e - Eraw; d = s; }
    int pos = atomicAdd(&cursor[d], 1);
    col_src[pos] = s;
  }
}

// ---------------- one-shot prep: xb, W1T, Wsd1T, xcb, WcF ----------------
__global__ void k_prep(const float* __restrict__ x, const float* __restrict__ W1,
                       const float* __restrict__ a1s, const float* __restrict__ a1d,
                       const float* __restrict__ bg2, const float* __restrict__ bxt,
                       const float* __restrict__ Wc,
                       short* __restrict__ xb, short* __restrict__ W1T,
                       float* __restrict__ WsdT1, float* __restrict__ xcb,
                       float* __restrict__ WcF, int N){
  int id = blockIdx.x*256 + threadIdx.x;
  int r0 = N*96;
  if (id < r0){
    int row = id/96, col = id - row*96;
    xb[id] = (col < 78) ? (short)f2bf(x[row*78 + col]) : (short)0;
    return;
  }
  id -= r0;
  if (id < 780*96){
    int c = id/96, k = id - c*96;
    W1T[id] = (k < 78) ? (short)f2bf(W1[(size_t)k*780 + c]) : (short)0;
    return;
  }
  id -= 780*96;
  if (id < 20*780){
    int j = id / 780, c = id % 780;
    int h = (j < 10) ? j : j - 10;
    float v = 0.f;
    if (c / F1 == h) v = (j < 10) ? a1s[h*F1 + c%F1] : a1d[h*F1 + c%F1];
    WsdT1[id] = v;
    return;
  }
  id -= 20*780;
  if (id < 256){
    xcb[id] = (id < 128) ? bg2[id] : bxt[id-128];
    return;
  }
  id -= 256;
  if (id < 256000){
    int i = id >> 8, r = id & 255;
    WcF[id] = Wc[(size_t)(r>>3)*8000 + i*8 + (r&7)];
  }
}

// ---------------- MFMA bf16 NT GEMM, global_load_lds + both-sides swizzle + XCD chunking ----------------
// C[M,N] (+)= A[M,K] @ BT[N,K]^T. A,BT bf16 (as short), K%32==0, rows 16B-aligned.
__global__ __launch_bounds__(256) void k_mfma_nt(const short* __restrict__ A, const short* __restrict__ BT,
                        float* __restrict__ C, int M, int N, int K,
                        int lda, int ldb, int ldc, int accum, int nbx){
  __shared__ __align__(16) short As[128*32];
  __shared__ __align__(16) short Bs[128*32];
  int tid = threadIdx.x;
  int lane = tid & 63, wave = tid >> 6;
  int wr = (wave >> 1) * 64, wc = (wave & 1) * 64;

  int nwg = gridDim.x;
  int q = nwg >> 3, rr = nwg & 7;
  int xcd = blockIdx.x & 7, rank = blockIdx.x >> 3;
  int l = xcd*q + min(xcd, rr) + rank;
  int row0 = (l / nbx) * 128, col0 = (l % nbx) * 128;

  int kp = ((lane & 3) ^ ((lane >> 3) & 3)) * 8;
  int rA0 = min(row0 + wave*32 + (lane>>2), M-1);
  int rA1 = min(row0 + wave*32 + 16 + (lane>>2), M-1);
  int rB0 = min(col0 + wave*32 + (lane>>2), N-1);
  int rB1 = min(col0 + wave*32 + 16 + (lane>>2), N-1);
  const short* pa0 = A  + (size_t)rA0*lda + kp;
  const short* pa1 = A  + (size_t)rA1*lda + kp;
  const short* pb0 = BT + (size_t)rB0*ldb + kp;
  const short* pb1 = BT + (size_t)rB1*ldb + kp;
  short* la0 = As + (wave*32 + 0)*32;
  short* la1 = As + (wave*32 + 16)*32;
  short* lb0 = Bs + (wave*32 + 0)*32;
  short* lb1 = Bs + (wave*32 + 16)*32;

  int so = ((lane>>4) ^ (((lane&15)>>1)&3)) * 8;

  f32x4 acc[4][4];
  #pragma unroll
  for (int i=0;i<4;++i)
    #pragma unroll
    for (int j=0;j<4;++j) acc[i][j] = (f32x4){0.f,0.f,0.f,0.f};

  for (int k0=0; k0<K; k0+=32){
    __builtin_amdgcn_global_load_lds((const __attribute__((address_space(1))) unsigned int*)pa0,
                                     (__attribute__((address_space(3))) unsigned int*)la0, 16, 0, 0);
    __builtin_amdgcn_global_load_lds((const __attribute__((address_space(1))) unsigned int*)pa1,
                                     (__attribute__((address_space(3))) unsigned int*)la1, 16, 0, 0);
    __builtin_amdgcn_global_load_lds((const __attribute__((address_space(1))) unsigned int*)pb0,
                                     (__attribute__((address_space(3))) unsigned int*)lb0, 16, 0, 0);
    __builtin_amdgcn_global_load_lds((const __attribute__((address_space(1))) unsigned int*)pb1,
                                     (__attribute__((address_space(3))) unsigned int*)lb1, 16, 0, 0);
    pa0 += 32; pa1 += 32; pb0 += 32; pb1 += 32;
    __syncthreads();
    bf16x8 af[4], bf[4];
    #pragma unroll
    for (int rb=0;rb<4;++rb)
      af[rb] = *reinterpret_cast<const bf16x8*>(&As[(wr + rb*16 + (lane&15))*32 + so]);
    #pragma unroll
    for (int cb=0;cb<4;++cb)
      bf[cb] = *reinterpret_cast<const bf16x8*>(&Bs[(wc + cb*16 + (lane&15))*32 + so]);
    #pragma unroll
    for (int rb=0;rb<4;++rb)
      #pragma unroll
      for (int cb=0;cb<4;++cb)
        acc[rb][cb] = __builtin_amdgcn_mfma_f32_16x16x32_bf16(af[rb], bf[cb], acc[rb][cb], 0, 0, 0);
    __syncthreads();
  }
  #pragma unroll
  for (int rb=0;rb<4;++rb){
    #pragma unroll
    for (int cb=0;cb<4;++cb){
      int c = col0 + wc + cb*16 + (lane & 15);
      if (c >= N) continue;
      #pragma unroll
      for (int j=0;j<4;++j){
        int r = row0 + wr + rb*16 + (lane>>4)*4 + j;
        if (r >= M) continue;
        float v = acc[rb][cb][j];
        if (accum) v += C[(size_t)r*ldc + c];
        C[(size_t)r*ldc + c] = v;
      }
    }
  }
}

// ---------------- W2 repack: W2rT[c][h*800+k] = bf16(W2[k][h*780+c]) ----------------
__global__ void k_w2t(const float* __restrict__ W2, short* __restrict__ W2rT){
  __shared__ float s[32][33];
  int k0 = blockIdx.x*32, c0 = blockIdx.y*32, h = blockIdx.z;
  int tx = threadIdx.x, ty = threadIdx.y;
  #pragma unroll
  for (int i=0;i<32;i+=8){
    int k = k0+ty+i, c = c0+tx;
    s[ty+i][tx] = (k < 780 && c < 780) ? W2[(size_t)k*7800 + h*780 + c] : 0.f;
  }
  __syncthreads();
  #pragma unroll
  for (int i=0;i<32;i+=8){
    int c = c0+ty+i, k = k0+tx;
    if (c < 780 && k < 800)
      W2rT[(size_t)c*8000 + h*800 + k] = (short)f2bf(s[tx][ty+i]);
  }
}

// ---------------- layer-2 score projections (wave-per-output, no atomics) ----------------
__global__ __launch_bounds__(256) void k_makews2(const float* __restrict__ W2, const float* __restrict__ a2s,
                          const float* __restrict__ a2d, float* __restrict__ WsdT){
  int c = blockIdx.x;
  int wave = threadIdx.x >> 6, lane = threadIdx.x & 63;
  const float* row = W2 + (size_t)c*7800;
  for (int j = wave; j < 20; j += 4){
    int h = (j < 10) ? j : j - 10;
    const float* av = (j < 10) ? a2s : a2d;
    float s = 0.f;
    for (int e = lane; e < 780; e += 64) s += row[h*780 + e] * av[h*780 + e];
    #pragma unroll
    for (int o=32; o; o>>=1) s += __shfl_xor(s, o);
    if (lane == 0) WsdT[(size_t)j*780 + c] = s;
  }
}

// ---------------- tall-skinny projection: out[n][j] = sum_c A[n][c]*WT[j][c], j<20 ----------------
__global__ __launch_bounds__(256) void k_proj20(const float* __restrict__ A, const float* __restrict__ WT,
                        float* __restrict__ out, int N){
  int n = blockIdx.x*4 + (threadIdx.x >> 6);
  if (n >= N) return;
  int lane = threadIdx.x & 63;
  const float* row = A + (size_t)n*D1;
  float acc[20] = {};
  #pragma unroll
  for (int r=0;r<12;++r){
    int c = lane + r*64;
    float v = row[c];
    #pragma unroll
    for (int j=0;j<20;++j) acc[j] += v * WT[j*780 + c];
  }
  { int c = 768 + lane;
    if (c < D1){
      float v = row[c];
      #pragma unroll
      for (int j=0;j<20;++j) acc[j] += v * WT[j*780 + c];
    } }
  #pragma unroll
  for (int j=0;j<20;++j){
    #pragma unroll
    for (int off=32; off; off>>=1) acc[j] += __shfl_xor(acc[j], off);
  }
  #pragma unroll
  for (int j=0;j<20;++j) if (lane == j) out[(size_t)n*20 + j] = acc[j];
}

// ---------------- GAT layer 1 aggregation (fixed-16 unrolled gather) ----------------
__global__ __launch_bounds__(256) void k_agg1(const float* __restrict__ h1, const float* __restrict__ hsd,
                       const int* __restrict__ row_ptr, const int* __restrict__ col_src,
                       const float* __restrict__ b1, float* __restrict__ g1o){
  __shared__ float m_l[HEADS], s_l[HEADS];
  __shared__ float al[16][HEADS];
  __shared__ int src_l[16];
  int n = blockIdx.x, tid = threadIdx.x;
  int beg = row_ptr[n], end = row_ptr[n+1];
  if (tid < HEADS){
    float hdv = hsd[(size_t)n*20 + 10 + tid];
    float m = -1e30f;
    for (int j=beg;j<end;++j) m = fmaxf(m, lrelu(hsd[(size_t)col_src[j]*20 + tid] + hdv));
    float s = 0.f;
    for (int j=beg;j<end;++j) s += expf(lrelu(hsd[(size_t)col_src[j]*20 + tid] + hdv) - m);
    m_l[tid]=m; s_l[tid]=s;
  }
  __syncthreads();
  float4 a4 = {0.f,0.f,0.f,0.f};
  int c0 = tid*4;
  int h0 = c0/F1, h1i = (c0+1)/F1, h2 = (c0+2)/F1, h3 = (c0+3)/F1;
  for (int j0=beg; j0<end; j0+=16){
    int cn = min(16, end-j0);
    for (int p=tid; p<16*HEADS; p+=256){
      int j = p/HEADS, h = p - j*HEADS;
      int valid = (j < cn);
      int sidx = col_src[j0 + (valid ? j : 0)];
      if (h==0) src_l[j] = sidx;
      float a = 0.f;
      if (valid){
        float sc = lrelu(hsd[(size_t)sidx*20 + h] + hsd[(size_t)n*20 + 10 + h]);
        a = expf(sc - m_l[h]) / s_l[h];
      }
      al[j][h] = a;
    }
    __syncthreads();
    if (tid < 195){
      #pragma unroll
      for (int j=0;j<16;++j){
        const float4* hr4 = reinterpret_cast<const float4*>(h1 + (size_t)src_l[j]*D1);
        float4 v = hr4[tid];
        a4.x += al[j][h0]*v.x;
        a4.y += al[j][h1i]*v.y;
        a4.z += al[j][h2]*v.z;
        a4.w += al[j][h3]*v.w;
      }
    }
    __syncthreads();
  }
  if (tid < 195){
    float4 o;
    float v0 = a4.x + b1[c0];   o.x = v0 > 0.f ? v0 : expm1f(v0);
    float v1 = a4.y + b1[c0+1]; o.y = v1 > 0.f ? v1 : expm1f(v1);
    float v2 = a4.z + b1[c0+2]; o.z = v2 > 0.f ? v2 : expm1f(v2);
    float v3 = a4.w + b1[c0+3]; o.w = v3 > 0.f ? v3 : expm1f(v3);
    *reinterpret_cast<float4*>(g1o + (size_t)n*D1 + c0) = o;
  }
}

// ---------------- layer-2 aggregation (fixed-16 unrolled) -> aggB bf16 [N][G*800] ----------------
template<int G>
__global__ __launch_bounds__(256) void k_aggG(const float* __restrict__ g1, const float* __restrict__ hsd,
                       const int* __restrict__ row_ptr, const int* __restrict__ col_src,
                       short* __restrict__ aggB, int h0){
  __shared__ float m_l[G], s_l[G];
  __shared__ float al[16][G];
  __shared__ int src_l[16];
  int n = blockIdx.x, tid = threadIdx.x;
  int beg = row_ptr[n], end = row_ptr[n+1];
  if (tid < G){
    int h = h0 + tid;
    float hdv = hsd[(size_t)n*20 + 10 + h];
    float m = -1e30f;
    for (int j=beg;j<end;++j) m = fmaxf(m, lrelu(hsd[(size_t)col_src[j]*20 + h] + hdv));
    float s = 0.f;
    for (int j=beg;j<end;++j) s += expf(lrelu(hsd[(size_t)col_src[j]*20 + h] + hdv) - m);
    m_l[tid]=m; s_l[tid]=s;
  }
  __syncthreads();
  float acc[4][G] = {};
  for (int j0=beg; j0<end; j0+=16){
    int cn = min(16, end-j0);
    for (int p=tid; p<16*G; p+=256){
      int j = p/G, g = p - j*G;
      int valid = (j < cn);
      int sidx = col_src[j0 + (valid ? j : 0)];
      if (g==0) src_l[j] = sidx;
      float a = 0.f;
      if (valid){
        int h = h0 + g;
        float hdv = hsd[(size_t)n*20 + 10 + h];
        a = 0.1f * expf(lrelu(hsd[(size_t)sidx*20 + h] + hdv) - m_l[g]) / s_l[g];
      }
      al[j][g] = a;
    }
    __syncthreads();
    if (tid < 195){
      #pragma unroll
      for (int j=0;j<16;++j){
        const float4* gr4 = reinterpret_cast<const float4*>(g1 + (size_t)src_l[j]*D1);
        float4 v = gr4[tid];
        #pragma unroll
        for (int g=0;g<G;++g){
          float a = al[j][g];
          acc[0][g] += a*v.x; acc[1][g] += a*v.y;
          acc[2][g] += a*v.z; acc[3][g] += a*v.w;
        }
      }
    }
    __syncthreads();
  }
  short* og = aggB + (size_t)n*G*800;
  if (tid < 195){
    int c0 = tid*4;
    #pragma unroll
    for (int g=0;g<G;++g){
      ushort4 o;
      o.x = f2bf(acc[0][g]); o.y = f2bf(acc[1][g]);
      o.z = f2bf(acc[2][g]); o.w = f2bf(acc[3][g]);
      *reinterpret_cast<ushort4*>(og + g*800 + c0) = o;
    }
  }
  for (int p=tid; p<G*20; p+=256){ int g=p/20, c2=780+p%20; og[g*800 + c2] = 0; }
}

// ---------------- pooling (col-split) ----------------
__device__ __forceinline__ int lowb(const int* a, int n, int v){
  int lo=0, hi=n;
  while (lo<hi){ int mid=(lo+hi)>>1; if (a[mid]<v) lo=mid+1; else hi=mid; }
  return lo;
}

__global__ void k_pool(const float* __restrict__ out2, const float* __restrict__ b2,
                       const int* __restrict__ batch, int N, float* __restrict__ gfeat){
  int b = blockIdx.x;
  int c = blockIdx.y*256 + threadIdx.x;
  if (c >= D1) return;
  int lo = lowb(batch, N, b), hi = lowb(batch, N, b+1);
  float bb = b2[c];
  float mx = -INFINITY, sm = 0.f;
  for (int n2=lo;n2<hi;++n2){
    float v = fmaxf(out2[(size_t)n2*D1 + c] + bb, 0.f);
    mx = fmaxf(mx, v);
    sm += v;
  }
  int cnt = hi-lo;
  gfeat[(size_t)b*1560 + c] = mx;
  gfeat[(size_t)b*1560 + 780 + c] = sm / fmaxf((float)cnt, 1.f);
}

// ---------------- protein conv: rank-26 factorization ----------------
__global__ __launch_bounds__(256) void k_prot(const int* __restrict__ target, const float* __restrict__ WcF,
                       const float* __restrict__ emb, const float* __restrict__ bc,
                       float* __restrict__ convc){
  __shared__ float Q[256*27];
  __shared__ float emb_l[26*128];
  __shared__ int tg_l[1000];
  int b = blockIdx.x, tid = threadIdx.x;
  for (int i=tid;i<26*128;i+=256) emb_l[i]=emb[i];
  for (int i=tid;i<1000;i+=256) tg_l[i]=target[b*1000+i];
  for (int i=tid;i<256*27;i+=256) Q[i]=0.f;
  __syncthreads();
  float* q = Q + tid*27;
  for (int i=0;i<1000;++i){
    float w = WcF[i*256 + tid];
    q[tg_l[i]] += w;
  }
  __syncthreads();
  for (int p=tid; p<32*121; p+=256){
    int o = p/121, t = p%121;
    float acc = bc[o];
    const float* qb = Q + (o*8)*27;
    for (int v=0; v<26; ++v){
      const float* ev = emb_l + v*128 + t;
      #pragma unroll
      for (int k=0;k<8;++k) acc += qb[k*27 + v] * ev[k];
    }
    convc[(size_t)b*3872 + p] = acc;
  }
}

// ---------------- split-K skinny GEMM (M<=64) with fused A-side bias/act ----------------
// actA: 0=none, 1=relu(A+biasA), 2=relu only for k<128 (xc case)
__global__ __launch_bounds__(256) void k_skinny(const float* __restrict__ A, const float* __restrict__ B,
                        float* __restrict__ C, int M, int N, int K, int ldb, int ldc, int kc,
                        const float* __restrict__ biasA, int actA){
  int col0 = blockIdx.x*64;
  int k0 = blockIdx.y*kc, k1 = min(K, k0+kc);
  int tx = threadIdx.x & 63, ty = threadIdx.x >> 6;
  int col = col0 + tx;
  if (col >= N) return;
  float acc[16] = {};
  for (int k=k0; k<k1; ++k){
    float b = B[(size_t)k*ldb + col];
    float bA = biasA ? biasA[k] : 0.f;
    bool doRelu = (actA == 1) || (actA == 2 && k < 128);
    const float* Ak = A + (size_t)(ty*16)*K + k;
    #pragma unroll
    for (int i=0;i<16;++i){
      float a = Ak[(size_t)i*K] + bA;
      if (doRelu) a = fmaxf(a, 0.f);
      acc[i] += a * b;
    }
  }
  #pragma unroll
  for (int i=0;i<16;++i){
    int r = ty*16 + i;
    if (r < M) atomicAdd(&C[(size_t)r*ldc + col], acc[i]);
  }
}

// ---------------- final Wo dot (f2 bias+relu fused) ----------------
__global__ void k_wo(const float* __restrict__ f2, const float* __restrict__ bf2,
                     const float* __restrict__ Wo, const float* __restrict__ bo,
                     float* __restrict__ out, int M){
  __shared__ float red[256];
  int tid = threadIdx.x;
  int r = tid & 63, kg = tid >> 6;
  float p = 0.f;
  for (int k = kg*128; k < kg*128 + 128; ++k)
    p += fmaxf(f2[(size_t)r*512 + k] + bf2[k], 0.f) * Wo[k];
  red[tid] = p;
  __syncthreads();
  if (tid < 64 && tid < M) out[tid] = red[tid] + red[tid+64] + red[tid+128] + red[tid+192] + bo[0];
}

// ---------------- launch ----------------
extern "C" void kernel_launch(void* const* d_in, const int* in_sizes, int n_in,
                              void* d_out, int out_size, void* d_ws, size_t ws_size,
                              hipStream_t stream){
  const float* x   = (const float*)d_in[0];
  const int*   ei    = (const int*)d_in[1];
  const int*   batch = (const int*)d_in[2];
  const int*   target= (const int*)d_in[3];
  const float* W1  = (const float*)d_in[4];
  const float* a1s = (const float*)d_in[5];
  const float* a1d = (const float*)d_in[6];
  const float* b1  = (const float*)d_in[7];
  const float* W2  = (const float*)d_in[8];
  const float* a2s = (const float*)d_in[9];
  const float* a2d = (const float*)d_in[10];
  const float* b2  = (const float*)d_in[11];
  const float* Wg1 = (const float*)d_in[12];
  const float* bg1 = (const float*)d_in[13];
  const float* Wg2 = (const float*)d_in[14];
  const float* bg2 = (const float*)d_in[15];
  const float* emb = (const float*)d_in[16];
  const float* Wc  = (const float*)d_in[17];
  const float* bc  = (const float*)d_in[18];
  const float* Wxt = (const float*)d_in[19];
  const float* bxt = (const float*)d_in[20];
  const float* Wf1 = (const float*)d_in[21];
  const float* bf1 = (const float*)d_in[22];
  const float* Wf2 = (const float*)d_in[23];
  const float* bf2 = (const float*)d_in[24];
  const float* Wo  = (const float*)d_in[25];
  const float* bo  = (const float*)d_in[26];

  int N = in_sizes[0] / 78;
  int Eraw = in_sizes[1] / 2;
  int Bb = in_sizes[3] / 1000;
  int Etot = Eraw + N;

  char* wsp = (char*)d_ws;
  size_t off = 0;
  auto alloc = [&](size_t bytes)->void*{ void* p = wsp + off; off += (bytes + 255) & ~(size_t)255; return p; };
  float* buf1   = (float*)alloc((size_t)N*D1*4);   // h1
  float* buf2   = (float*)alloc((size_t)N*D1*4);   // g1
  float* buf3   = (float*)alloc((size_t)N*D1*4);   // out2
  float* hsd1   = (float*)alloc((size_t)N*20*4);
  float* hsd2   = (float*)alloc((size_t)N*20*4);
  float* WsdT1  = (float*)alloc((size_t)20*D1*4);
  float* WsdT2  = (float*)alloc((size_t)20*D1*4);
  int*   row_ptr= (int*)alloc((size_t)(N+1)*4);
  int*   cursor = (int*)alloc((size_t)N*4);
  int*   col_src= (int*)alloc((size_t)Etot*4);
  float* WcF    = (float*)alloc((size_t)1000*256*4);
  float* convc  = (float*)alloc((size_t)Bb*3872*4);
  float* gfeat  = (float*)alloc((size_t)Bb*1560*4);
  short* xb     = (short*)alloc((size_t)N*96*2);
  short* W1T    = (short*)alloc((size_t)780*96*2);
  float* xcb    = (float*)alloc((size_t)256*4);
  // ---- contiguous zero region: counts, fcg1, xc, f1, f2 ----
  size_t zbeg = off;
  int*   counts = (int*)alloc((size_t)N*4);
  float* fcg1   = (float*)alloc((size_t)Bb*1500*4);
  float* xc     = (float*)alloc((size_t)Bb*256*4);
  float* f1     = (float*)alloc((size_t)Bb*1024*4);
  float* f2     = (float*)alloc((size_t)Bb*512*4);
  size_t zlen = off - zbeg;
  short* W2rT   = (short*)alloc((size_t)D1*8000*2);  // [c][h*800+k] bf16
  // choose largest head-group G whose aggB fits
  int G = 10;
  { size_t avail = (ws_size > off + (1u<<20)) ? ws_size - off - (1u<<20) : 0;
    if      (avail >= (size_t)N*10*800*2) G = 10;
    else if (avail >= (size_t)N*5*800*2)  G = 5;
    else if (avail >= (size_t)N*2*800*2)  G = 2;
    else                                   G = 1; }
  short* aggB = (short*)alloc((size_t)N*G*800*2);
  (void)n_in; (void)out_size;

  // ---- zero all atomic-target buffers in one memset ----
  hipMemsetAsync(wsp + zbeg, 0, zlen, stream);

  // ---- one-shot prep (xb, W1T, Wsd1T, xcb, WcF) ----
  { int tot = N*96 + 780*96 + 20*780 + 256 + 256000;
    k_prep<<<(tot+255)/256,256,0,stream>>>(x, W1, a1s, a1d, bg2, bxt, Wc,
                                           xb, W1T, WsdT1, xcb, WcF, N); }

  // ---- CSR by dst (self-loops appended) ----
  int thr=256, blk=(Etot+thr-1)/thr;
  k_count<<<blk,thr,0,stream>>>(ei+Eraw, counts, Eraw, N);
  k_scan<<<1,1024,0,stream>>>(counts, row_ptr, cursor, N);
  k_scatter<<<blk,thr,0,stream>>>(ei, ei+Eraw, cursor, col_src, Eraw, N);

  // ---- protein branch: rank-26 factorization ----
  k_prot<<<Bb,256,0,stream>>>(target, WcF, emb, bc, convc);
  { dim3 g((128+63)/64, (3872+127)/128);
    k_skinny<<<g,256,0,stream>>>(convc, Wxt, xc+128, Bb, 128, 3872, 128, 256, 128, nullptr, 0); }

  // ---- GAT layer 1 (MFMA W1 projection) ----
  int nbx = (D1+127)/128, nby = (N+127)/128;
  int nwg = nbx*nby;
  k_mfma_nt<<<nwg,256,0,stream>>>(xb, W1T, buf1, N, D1, 96, 96, 96, D1, 0, nbx);
  k_proj20<<<(N+3)/4,256,0,stream>>>(buf1, WsdT1, hsd1, N);
  k_agg1<<<N,256,0,stream>>>(buf1, hsd1, row_ptr, col_src, b1, buf2);

  // ---- GAT layer 2 ----
  k_makews2<<<D1,256,0,stream>>>(W2, a2s, a2d, WsdT2);
  k_proj20<<<(N+3)/4,256,0,stream>>>(buf2, WsdT2, hsd2, N);
  { dim3 g(25, 25, 10); dim3 b(32, 8);
    k_w2t<<<g,b,0,stream>>>(W2, W2rT); }

  float* out2 = buf3;
  for (int h0=0; h0<HEADS; h0+=G){
    switch (G){
      case 10: k_aggG<10><<<N,256,0,stream>>>(buf2, hsd2, row_ptr, col_src, aggB, h0); break;
      case 5:  k_aggG<5> <<<N,256,0,stream>>>(buf2, hsd2, row_ptr, col_src, aggB, h0); break;
      case 2:  k_aggG<2> <<<N,256,0,stream>>>(buf2, hsd2, row_ptr, col_src, aggB, h0); break;
      default: k_aggG<1> <<<N,256,0,stream>>>(buf2, hsd2, row_ptr, col_src, aggB, h0); break;
    }
    k_mfma_nt<<<nwg,256,0,stream>>>(aggB, W2rT + h0*800, out2, N, D1, G*800, G*800, 8000, D1, h0?1:0, nbx);
  }

  // ---- pooling (bias+relu fused, col-split) ----
  { dim3 gp(Bb, 4);
    k_pool<<<gp,256,0,stream>>>(out2, b2, batch, N, gfeat); }

  // ---- graph FCs (split-K skinny, A-side bias/act fused) ----
  { dim3 g((1500+63)/64, (1560+127)/128);
    k_skinny<<<g,256,0,stream>>>(gfeat, Wg1, fcg1, Bb, 1500, 1560, 1500, 1500, 128, nullptr, 0); }
  { dim3 g((128+63)/64, (1500+127)/128);
    k_skinny<<<g,256,0,stream>>>(fcg1, Wg2, xc, Bb, 128, 1500, 128, 256, 128, bg1, 1); }

  // ---- fusion MLP ----
  { dim3 g((1024+63)/64, (256+127)/128);
    k_skinny<<<g,256,0,stream>>>(xc, Wf1, f1, Bb, 1024, 256, 1024, 1024, 128, xcb, 2); }
  { dim3 g((512+63)/64, (1024+127)/128);
    k_skinny<<<g,256,0,stream>>>(f1, Wf2, f2, Bb, 512, 1024, 512, 512, 128, bf1, 1); }
  k_wo<<<1,256,0,stream>>>(f2, bf2, Wo, bo, (float*)d_out, Bb);
}